// Round 8
// baseline (83.520 us; speedup 1.0000x reference)
//
#include <hip/hip_runtime.h>
#include <hip/hip_bf16.h>
#include <math.h>

#define L_LEN 250
#define D_DIM 128
#define C_DIM 32
#define DIN   160
#define NV    16
#define T_LEN 62400
#define CB    244            // ceil(62400/256)

// ---------------- params v2: grid=16, 512 threads, K-parallel layers --------
// P layout per batch (40 floats): [0]=depth, [1]=coef, [2..17]=mask, [18..33]=pan
__global__ __launch_bounds__(512) void params_kernel2(
        const float* __restrict__ z, const float* __restrict__ cond,
        const float* __restrict__ W1, const float* __restrict__ b1,
        const float* __restrict__ W2, const float* __restrict__ b2,
        const float* __restrict__ W3, const float* __restrict__ b3,
        const float* __restrict__ W4, const float* __restrict__ b4,
        float* __restrict__ P) {
    int b = blockIdx.x;
    int tid = threadIdx.x;
    __shared__ float xb[DIN];
    __shared__ float red[512];
    __shared__ float h1[256];
    __shared__ float h2[128];
    __shared__ float h3[64];
    __shared__ float pr[4];
    __shared__ float4 sm4[16][32];

    {   // z-mean: 32 float4-cols x 16 row-groups
        int c4 = tid & 31, rg = tid >> 5;
        const float4* zp = (const float4*)(z + (size_t)b * L_LEN * D_DIM) + c4;
        float4 acc = make_float4(0.f, 0.f, 0.f, 0.f);
        for (int r = rg; r < L_LEN; r += 16) {
            float4 v = zp[(size_t)r * 32];
            acc.x += v.x; acc.y += v.y; acc.z += v.z; acc.w += v.w;
        }
        sm4[rg][c4] = acc;
    }
    __syncthreads();
    if (tid < 32) {
        float4 acc = sm4[0][tid];
        #pragma unroll
        for (int g = 1; g < 16; ++g) {
            float4 v = sm4[g][tid];
            acc.x += v.x; acc.y += v.y; acc.z += v.z; acc.w += v.w;
        }
        const float inv = 1.0f / (float)L_LEN;
        acc.x *= inv; acc.y *= inv; acc.z *= inv; acc.w *= inv;
        ((float4*)xb)[tid] = acc;
    } else if (tid >= 128 && tid < DIN) {
        xb[tid] = cond[b * C_DIM + (tid - 128)];
    }
    __syncthreads();

    {   // L1: 160 -> 256 ; 256 oc x 2 k-halves of 80
        int oc = tid & 255, half = tid >> 8;
        const float* w = W1 + (size_t)(half * 80) * 256 + oc;
        const float* x = xb + half * 80;
        float a0 = 0.f, a1 = 0.f, a2 = 0.f, a3 = 0.f;
        #pragma unroll 5
        for (int i = 0; i < 80; i += 4) {
            a0 = fmaf(x[i],     w[(size_t)(i)     * 256], a0);
            a1 = fmaf(x[i + 1], w[(size_t)(i + 1) * 256], a1);
            a2 = fmaf(x[i + 2], w[(size_t)(i + 2) * 256], a2);
            a3 = fmaf(x[i + 3], w[(size_t)(i + 3) * 256], a3);
        }
        red[tid] = (a0 + a1) + (a2 + a3);
    }
    __syncthreads();
    if (tid < 256) h1[tid] = fmaxf(red[tid] + red[tid + 256] + b1[tid], 0.f);
    __syncthreads();

    {   // L2: 256 -> 128 ; 128 oc x 4 k-groups of 64
        int oc = tid & 127, qg = tid >> 7;
        const float* w = W2 + (size_t)(qg * 64) * 128 + oc;
        const float* x = h1 + qg * 64;
        float a0 = 0.f, a1 = 0.f, a2 = 0.f, a3 = 0.f;
        #pragma unroll 4
        for (int i = 0; i < 64; i += 4) {
            a0 = fmaf(x[i],     w[(size_t)(i)     * 128], a0);
            a1 = fmaf(x[i + 1], w[(size_t)(i + 1) * 128], a1);
            a2 = fmaf(x[i + 2], w[(size_t)(i + 2) * 128], a2);
            a3 = fmaf(x[i + 3], w[(size_t)(i + 3) * 128], a3);
        }
        red[tid] = (a0 + a1) + (a2 + a3);
    }
    __syncthreads();
    if (tid < 128)
        h2[tid] = fmaxf(red[tid] + red[tid + 128] + red[tid + 256] + red[tid + 384] + b2[tid], 0.f);
    __syncthreads();

    {   // L3: 128 -> 64 ; 64 oc x 8 k-groups of 16
        int oc = tid & 63, qg = tid >> 6;
        const float* w = W3 + (size_t)(qg * 16) * 64 + oc;
        const float* x = h2 + qg * 16;
        float a0 = 0.f, a1 = 0.f;
        #pragma unroll 8
        for (int i = 0; i < 16; i += 2) {
            a0 = fmaf(x[i],     w[(size_t)(i)     * 64], a0);
            a1 = fmaf(x[i + 1], w[(size_t)(i + 1) * 64], a1);
        }
        red[tid] = a0 + a1;
    }
    __syncthreads();
    if (tid < 64) {
        float s = b3[tid];
        #pragma unroll
        for (int g = 0; g < 8; ++g) s += red[g * 64 + tid];
        h3[tid] = fmaxf(s, 0.f);
    }
    __syncthreads();

    if (tid < 256) {   // L4: 64 -> 4 ; fully parallel products
        int oc = tid & 3, k = tid >> 2;
        red[tid] = h3[k] * W4[k * 4 + oc];
    }
    __syncthreads();
    if (tid < 4) {
        float s = b4[tid];
        for (int k = 0; k < 64; ++k) s += red[k * 4 + tid];
        pr[tid] = s;
    }
    __syncthreads();
    if (tid == 0) {
        float num_voices = 1.0f + 14.0f / (1.0f + __expf(-pr[0]));
        float spread     = 1.0f / (1.0f + __expf(-pr[2]));
        float depth      = 0.5f / (1.0f + __expf(-pr[3]));
        float* Pb = P + b * 40;
        float msum = 0.f;
        for (int v = 0; v < NV; ++v) {
            float m = 1.0f / (1.0f + __expf(-(num_voices - (float)v) * 2.0f));
            msum += m;
            Pb[2 + v] = m;
            float pos = ((float)v - 7.5f) * (1.0f / 16.0f);
            Pb[2 + NV + v] = 1.0f - fabsf(pos) * spread * 0.5f;
        }
        float norm = sqrtf(msum + 1e-6f);
        Pb[0] = depth;
        Pb[1] = 1.0f / (norm + 1e-6f);
    }
}

// ---------------- conv1 weight-stationary (standalone): grid = 512 ---------
// block = (ic-split s, oc-quarter q, batch b, l-half). Thread = 1 oc x 16 l.
__global__ __launch_bounds__(256) void conv1_ws_kernel(
        const float* __restrict__ z, const float* __restrict__ cond,
        const float* __restrict__ K1, float* __restrict__ parts1) {
    int tid = threadIdx.x;
    __shared__ float kw[7 * 40 * 32];     // 35.8KB
    __shared__ float smc[40][136];        // 21.8KB; [ic][pl], p = l0-3+pl

    int blk = blockIdx.x;
    int s  = blk >> 7;            // ic split 0..3 (40 ic)
    int q  = (blk >> 5) & 3;      // oc quarter 0..3 (32 oc)
    int b  = (blk >> 1) & 15;
    int lh = blk & 1;
    int l0 = lh * 125;

    for (int idx = tid; idx < 7 * 40 * 32; idx += 256) {
        int tap = idx / (40 * 32);
        int rem = idx - tap * (40 * 32);
        int ic  = rem >> 5;
        int oc  = rem & 31;
        kw[(ic * 7 + tap) * 32 + oc] =
            K1[((size_t)tap * DIN + s * 40 + ic) * 128 + q * 32 + oc];
    }
    for (int idx = tid; idx < 134 * 40; idx += 256) {
        int pl = idx / 40;
        int il = idx - pl * 40;
        int p  = l0 - 3 + pl;
        int gi = s * 40 + il;
        float v = 0.f;
        if (p >= 0 && p < L_LEN)
            v = (gi < D_DIM) ? z[((size_t)b * L_LEN + p) * D_DIM + gi]
                             : cond[b * C_DIM + (gi - D_DIM)];
        smc[il][pl] = v;
    }
    __syncthreads();

    int oc = tid & 31;
    int lb = (tid >> 5) << 4;     // 0,16,...,112
    float acc[16];
    #pragma unroll
    for (int j = 0; j < 16; ++j) acc[j] = 0.f;
    #pragma unroll 2
    for (int ic = 0; ic < 40; ++ic) {
        float zr[22];
        #pragma unroll
        for (int qq = 0; qq < 20; qq += 4)
            *(float4*)&zr[qq] = *(const float4*)&smc[ic][lb + qq];
        *(float2*)&zr[20] = *(const float2*)&smc[ic][lb + 20];
        const float* kwp = &kw[ic * 7 * 32 + oc];
        #pragma unroll
        for (int tap = 0; tap < 7; ++tap) {
            float w = kwp[tap * 32];
            #pragma unroll
            for (int j = 0; j < 16; ++j)
                acc[j] = fmaf(zr[tap + j], w, acc[j]);
        }
    }
    float* po = parts1 + (size_t)s * (16 * L_LEN * 128)
              + ((size_t)b * L_LEN) * 128 + q * 32 + oc;
    #pragma unroll
    for (int j = 0; j < 16; ++j) {
        int ll = lb + j;
        int l  = l0 + ll;
        if (ll < 125 && l < L_LEN) po[(size_t)l * 128] = acc[j];
    }
}

// -------- conv2 weight-stationary: 2s x 2q x 16b x 8lt = 512 blocks ---------
__global__ __launch_bounds__(256) void conv2_split_kernel(
        const float* __restrict__ parts1, const float* __restrict__ cb1,
        const float* __restrict__ K2, float* __restrict__ parts2) {
    int s  = blockIdx.x >> 8;        // ic half 0..1 (64 ic)
    int q  = (blockIdx.x >> 7) & 1;  // oc half 0..1 (32 oc)
    int b  = (blockIdx.x >> 3) & 15;
    int lt = blockIdx.x & 7;
    int l0 = lt * 32;
    int tid = threadIdx.x;
    const int PSTR = 16 * L_LEN * 128;
    __shared__ float kw[5 * 64 * 32];   // 40KB
    __shared__ float smr[64][40];       // [ic][pl], p = l0-2+pl, pl 0..35
    for (int idx = tid; idx < 5 * 64 * 32; idx += 256) {
        int tap = idx / (64 * 32);
        int rem = idx - tap * (64 * 32);
        int ic  = rem >> 5;
        int oc  = rem & 31;
        kw[(ic * 5 + tap) * 32 + oc] =
            K2[((size_t)tap * 128 + s * 64 + ic) * 64 + q * 32 + oc];
    }
    for (int idx = tid; idx < 36 * 64; idx += 256) {
        int pl = idx >> 6;
        int il = idx & 63;
        int p  = l0 - 2 + pl;
        int gi = s * 64 + il;
        float v = 0.f;
        if (p >= 0 && p < L_LEN) {
            size_t o = ((size_t)b * L_LEN + p) * 128 + gi;
            v = cb1[gi] + parts1[o] + parts1[o + PSTR] + parts1[o + 2 * PSTR] + parts1[o + 3 * PSTR];
            v = fmaxf(v, 0.f);
        }
        smr[il][pl] = v;
    }
    __syncthreads();
    int oc = tid & 31;
    int lb = (tid >> 5) << 2;   // 0..28
    float acc[4];
    #pragma unroll
    for (int j = 0; j < 4; ++j) acc[j] = 0.f;
    #pragma unroll 4
    for (int ic = 0; ic < 64; ++ic) {
        float zr[8];
        *(float4*)&zr[0] = *(const float4*)&smr[ic][lb];
        *(float4*)&zr[4] = *(const float4*)&smr[ic][lb + 4];
        const float* kwp = &kw[ic * 5 * 32 + oc];
        #pragma unroll
        for (int tap = 0; tap < 5; ++tap) {
            float w = kwp[tap * 32];
            #pragma unroll
            for (int j = 0; j < 4; ++j)
                acc[j] = fmaf(zr[tap + j], w, acc[j]);
        }
    }
    float* po = parts2 + (size_t)s * (16 * L_LEN * 64)
              + ((size_t)b * L_LEN) * 64 + q * 32 + oc;
    #pragma unroll
    for (int j = 0; j < 4; ++j) {
        int l = l0 + lb + j;
        if (l < L_LEN) po[(size_t)l * 64] = acc[j];
    }
}

// ------- kernel 3: fused conv3 + upsample + softplus + unison mix ----------
__global__ __launch_bounds__(256) void conv3_main_kernel(
        const float* __restrict__ base, const float* __restrict__ parts2,
        const float* __restrict__ cb2,
        const float* __restrict__ K3, const float* __restrict__ cb3,
        const float* __restrict__ P, float* __restrict__ out) {
    int b = blockIdx.x / CB;
    int c = blockIdx.x % CB;
    int t0 = c * 256;
    int tid = threadIdx.x;
    const int PSTR2 = 16 * L_LEN * 64;
    const float scale = 250.0f / 62400.0f;

    __shared__ float k3t[16][196];   // [v][tap*64+ic]
    __shared__ float sA[6][68];      // g2 rows p = L0-1+pl, 0 if OOB
    __shared__ float g3loc[4][17];   // g3 rows L0..L0+3
    __shared__ float Pb[34];

    float src0 = ((float)t0 + 0.5f) * scale - 0.5f;
    src0 = fminf(fmaxf(src0, 0.0f), 249.0f);
    int L0 = (int)floorf(src0);

    if (tid < 34) Pb[tid] = P[b * 40 + tid];
    for (int idx = tid; idx < 3 * 64 * 16; idx += 256) {
        int v  = idx & 15;
        int ti = idx >> 4;
        k3t[v][ti] = K3[ti * 16 + v];
    }
    for (int idx = tid; idx < 6 * 64; idx += 256) {
        int pl = idx >> 6;
        int i  = idx & 63;
        int p  = L0 - 1 + pl;
        float v = 0.f;
        if (p >= 0 && p < L_LEN) {
            size_t o = ((size_t)b * L_LEN + p) * 64 + i;
            v = fmaxf(cb2[i] + parts2[o] + parts2[o + PSTR2], 0.f);
        }
        sA[pl][i] = v;
    }
    __syncthreads();

    {   // conv3: 4 rows x 16 v x 4 ic-segments; quad shuffle-reduce
        int seg = tid & 3;
        int v   = (tid >> 2) & 15;
        int r   = tid >> 6;
        float acc = 0.f;
        #pragma unroll
        for (int tap = 0; tap < 3; ++tap) {
            const float* gr = &sA[r + tap][seg * 16];
            const float* kr = &k3t[v][tap * 64 + seg * 16];
            #pragma unroll
            for (int j = 0; j < 4; ++j) {
                float4 g = *(const float4*)&gr[j * 4];
                float4 k = *(const float4*)&kr[j * 4];
                acc = fmaf(g.x, k.x, acc);
                acc = fmaf(g.y, k.y, acc);
                acc = fmaf(g.z, k.z, acc);
                acc = fmaf(g.w, k.w, acc);
            }
        }
        acc += __shfl_xor(acc, 1);
        acc += __shfl_xor(acc, 2);
        if (seg == 0) g3loc[r][v] = acc + cb3[v];
    }
    __syncthreads();

    int t = t0 + tid;
    if (t >= T_LEN) return;
    float depth = Pb[0];
    float coef  = Pb[1];
    float src = ((float)t + 0.5f) * scale - 0.5f;
    src = fminf(fmaxf(src, 0.0f), 249.0f);
    float fi0 = floorf(src);
    int i0 = (int)fi0;
    int i1 = min(i0 + 1, L_LEN - 1);
    float frac = src - fi0;
    int r0 = i0 - L0;
    int r1 = i1 - L0;
    float vg[16];
    #pragma unroll
    for (int v = 0; v < NV; ++v) {
        float a = g3loc[r0][v];
        float d = g3loc[r1][v];
        vg[v] = fmaf(d - a, frac, a);
    }
    float tsec = (float)t * (1.0f / 48000.0f);
    const float* bs = base + (size_t)b * T_LEN;
    const int shifts[NV] = {-9,-8,-6,-5,-4,-3,-1,0,0,1,3,4,5,6,8,9};
    float gain_sum = 0.f, uni = 0.f;
    #pragma unroll
    for (int v = 0; v < NV; ++v) {
        float x = vg[v];
        float sp = fmaxf(x, 0.f) + __logf(1.0f + __expf(-fabsf(x)));   // softplus
        float fv = 3.0f + 0.3f * (float)v;
        float ph = fv * tsec;
        ph -= floorf(ph);                       // revolutions in [0,1)
        float lfo = __builtin_amdgcn_sinf(ph);  // v_sin_f32: sin(2*pi*ph)
        int tb = t - shifts[v];
        if (tb < 0) tb += T_LEN; else if (tb >= T_LEN) tb -= T_LEN;
        float mod = bs[tb] * fmaf(0.2f * depth, lfo, 1.0f);
        gain_sum = fmaf(sp, Pb[2 + v], gain_sum);
        uni      = fmaf(mod * sp, Pb[2 + NV + v], uni);
    }
    out[(size_t)b * T_LEN + t] = gain_sum * coef * uni;
}

// ================= fallback (round-1 monolithic) kernels ====================
__global__ void params_kernel(const float* __restrict__ z, const float* __restrict__ cond,
                              const float* __restrict__ W1, const float* __restrict__ b1,
                              const float* __restrict__ W2, const float* __restrict__ b2,
                              const float* __restrict__ W3, const float* __restrict__ b3,
                              const float* __restrict__ W4, const float* __restrict__ b4,
                              float* __restrict__ P) {
    int b = blockIdx.x;
    int tid = threadIdx.x;
    __shared__ float xb[DIN];
    __shared__ float zp2[128];
    __shared__ float h1[256];
    __shared__ float h2[128];
    __shared__ float h3[64];
    __shared__ float pr[4];
    {
        int i = tid & 127, half = tid >> 7;
        const float* zp = z + (size_t)b * L_LEN * D_DIM + i;
        float s = 0.f;
        for (int l = half; l < L_LEN; l += 2) s += zp[(size_t)l * D_DIM];
        if (half) zp2[i] = s;
        __syncthreads();
        if (!half) xb[i] = (s + zp2[i]) * (1.0f / (float)L_LEN);
        if (tid >= 128 && tid < DIN) xb[tid] = cond[b * C_DIM + (tid - 128)];
    }
    __syncthreads();
    {
        float acc = b1[tid];
        for (int i = 0; i < DIN; ++i) acc = fmaf(xb[i], W1[i * 256 + tid], acc);
        h1[tid] = fmaxf(acc, 0.f);
    }
    __syncthreads();
    if (tid < 128) {
        float acc = b2[tid];
        for (int i = 0; i < 256; ++i) acc = fmaf(h1[i], W2[i * 128 + tid], acc);
        h2[tid] = fmaxf(acc, 0.f);
    }
    __syncthreads();
    if (tid < 64) {
        float acc = b3[tid];
        for (int i = 0; i < 128; ++i) acc = fmaf(h2[i], W3[i * 64 + tid], acc);
        h3[tid] = fmaxf(acc, 0.f);
    }
    __syncthreads();
    if (tid < 4) {
        float acc = b4[tid];
        for (int i = 0; i < 64; ++i) acc = fmaf(h3[i], W4[i * 4 + tid], acc);
        pr[tid] = acc;
    }
    __syncthreads();
    if (tid == 0) {
        float num_voices = 1.0f + 14.0f / (1.0f + __expf(-pr[0]));
        float spread     = 1.0f / (1.0f + __expf(-pr[2]));
        float depth      = 0.5f / (1.0f + __expf(-pr[3]));
        float* Pb = P + b * 40;
        float msum = 0.f;
        for (int v = 0; v < NV; ++v) {
            float m = 1.0f / (1.0f + __expf(-(num_voices - (float)v) * 2.0f));
            msum += m;
            Pb[2 + v] = m;
            float pos = ((float)v - 7.5f) * (1.0f / 16.0f);
            Pb[2 + NV + v] = 1.0f - fabsf(pos) * spread * 0.5f;
        }
        float norm = sqrtf(msum + 1e-6f);
        Pb[0] = depth;
        Pb[1] = 1.0f / (norm + 1e-6f);
    }
}

__global__ void conv1_mono_kernel(const float* __restrict__ z, const float* __restrict__ cond,
                                  const float* __restrict__ K1, const float* __restrict__ cb1,
                                  float* __restrict__ g1) {
    int b  = blockIdx.x >> 4;
    int lt = blockIdx.x & 15;
    int l0 = lt * 16;
    int tid = threadIdx.x;
    __shared__ float sm[DIN][22];
    for (int idx = tid; idx < 22 * DIN; idx += 256) {
        int pl = idx / DIN;
        int i  = idx - pl * DIN;
        int p  = l0 - 3 + pl;
        float v = 0.f;
        if (p >= 0 && p < L_LEN)
            v = (i < D_DIM) ? z[((size_t)b * L_LEN + p) * D_DIM + i]
                            : cond[b * C_DIM + (i - D_DIM)];
        sm[i][pl] = v;
    }
    __syncthreads();
    int oc = tid & 127;
    int lb = (tid >> 7) * 8;
    float bias = cb1[oc];
    float acc[8];
    #pragma unroll
    for (int j = 0; j < 8; ++j) acc[j] = bias;
    for (int i = 0; i < DIN; ++i) {
        float zr[14];
        #pragma unroll
        for (int q = 0; q < 14; ++q) zr[q] = sm[i][lb + q];
        #pragma unroll
        for (int tap = 0; tap < 7; ++tap) {
            float k = K1[(size_t)(tap * DIN + i) * 128 + oc];
            #pragma unroll
            for (int j = 0; j < 8; ++j) acc[j] = fmaf(zr[tap + j], k, acc[j]);
        }
    }
    #pragma unroll
    for (int j = 0; j < 8; ++j) {
        int l = l0 + lb + j;
        if (l < L_LEN) g1[((size_t)b * L_LEN + l) * 128 + oc] = fmaxf(acc[j], 0.f);
    }
}

__global__ void conv2_mono_kernel(const float* __restrict__ g1,
                                  const float* __restrict__ K2, const float* __restrict__ cb2,
                                  float* __restrict__ g2) {
    int b  = blockIdx.x >> 4;
    int lt = blockIdx.x & 15;
    int l0 = lt * 16;
    int tid = threadIdx.x;
    __shared__ float sm[128][20];
    for (int idx = tid; idx < 20 * 128; idx += 256) {
        int pl = idx >> 7;
        int i  = idx & 127;
        int p  = l0 - 2 + pl;
        float v = (p >= 0 && p < L_LEN) ? g1[((size_t)b * L_LEN + p) * 128 + i] : 0.f;
        sm[i][pl] = v;
    }
    __syncthreads();
    int oc = tid & 63;
    int lb = (tid >> 6) * 4;
    float bias = cb2[oc];
    float acc[4];
    #pragma unroll
    for (int j = 0; j < 4; ++j) acc[j] = bias;
    for (int i = 0; i < 128; ++i) {
        float zr[8];
        #pragma unroll
        for (int q = 0; q < 8; ++q) zr[q] = sm[i][lb + q];
        #pragma unroll
        for (int tap = 0; tap < 5; ++tap) {
            float k = K2[(size_t)(tap * 128 + i) * 64 + oc];
            #pragma unroll
            for (int j = 0; j < 4; ++j) acc[j] = fmaf(zr[tap + j], k, acc[j]);
        }
    }
    #pragma unroll
    for (int j = 0; j < 4; ++j) {
        int l = l0 + lb + j;
        if (l < L_LEN) g2[((size_t)b * L_LEN + l) * 64 + oc] = fmaxf(acc[j], 0.f);
    }
}

__global__ void conv3_mono_kernel(const float* __restrict__ g2,
                                  const float* __restrict__ K3, const float* __restrict__ cb3,
                                  float* __restrict__ g3) {
    int b  = blockIdx.x >> 4;
    int lt = blockIdx.x & 15;
    int l0 = lt * 16;
    int tid = threadIdx.x;
    int v  = tid & 15;
    int ll = tid >> 4;
    int l  = l0 + ll;
    if (l >= L_LEN) return;
    float acc = cb3[v];
    #pragma unroll
    for (int tap = 0; tap < 3; ++tap) {
        int p = l + tap - 1;
        if (p < 0 || p >= L_LEN) continue;
        const float* gp = g2 + ((size_t)b * L_LEN + p) * 64;
        #pragma unroll
        for (int i = 0; i < 64; ++i) acc = fmaf(gp[i], K3[(size_t)(tap * 64 + i) * 16 + v], acc);
    }
    g3[((size_t)b * L_LEN + l) * 16 + v] = acc;
}

__global__ __launch_bounds__(256) void main_mono_kernel(
        const float* __restrict__ base, const float* __restrict__ g3,
        const float* __restrict__ P, float* __restrict__ out) {
    int b = blockIdx.x / CB;
    int c = blockIdx.x % CB;
    int t = c * 256 + threadIdx.x;
    __shared__ float Pb[34];
    if (threadIdx.x < 34) Pb[threadIdx.x] = P[b * 40 + threadIdx.x];
    __syncthreads();
    if (t >= T_LEN) return;
    float depth = Pb[0];
    float coef  = Pb[1];
    const float scale = 250.0f / 62400.0f;
    float src = ((float)t + 0.5f) * scale - 0.5f;
    src = fminf(fmaxf(src, 0.0f), 249.0f);
    float fi0 = floorf(src);
    int i0 = (int)fi0;
    int i1 = min(i0 + 1, L_LEN - 1);
    float frac = src - fi0;
    const float4* r0 = (const float4*)(g3 + ((size_t)b * L_LEN + i0) * NV);
    const float4* r1 = (const float4*)(g3 + ((size_t)b * L_LEN + i1) * NV);
    float vg[16];
    #pragma unroll
    for (int q = 0; q < 4; ++q) {
        float4 a = r0[q];
        float4 d = r1[q];
        vg[q * 4 + 0] = fmaf(d.x - a.x, frac, a.x);
        vg[q * 4 + 1] = fmaf(d.y - a.y, frac, a.y);
        vg[q * 4 + 2] = fmaf(d.z - a.z, frac, a.z);
        vg[q * 4 + 3] = fmaf(d.w - a.w, frac, a.w);
    }
    float tsec = (float)t * (1.0f / 48000.0f);
    const float* bs = base + (size_t)b * T_LEN;
    const int shifts[NV] = {-9,-8,-6,-5,-4,-3,-1,0,0,1,3,4,5,6,8,9};
    float gain_sum = 0.f, uni = 0.f;
    #pragma unroll
    for (int v = 0; v < NV; ++v) {
        float x = vg[v];
        float sp = fmaxf(x, 0.f) + __logf(1.0f + __expf(-fabsf(x)));
        float fv = 3.0f + 0.3f * (float)v;
        float ph = fv * tsec;
        ph -= floorf(ph);
        float lfo = __builtin_amdgcn_sinf(ph);
        int tb = t - shifts[v];
        if (tb < 0) tb += T_LEN; else if (tb >= T_LEN) tb -= T_LEN;
        float mod = bs[tb] * fmaf(0.2f * depth, lfo, 1.0f);
        gain_sum = fmaf(sp, Pb[2 + v], gain_sum);
        uni      = fmaf(mod * sp, Pb[2 + NV + v], uni);
    }
    out[(size_t)b * T_LEN + t] = gain_sum * coef * uni;
}

extern "C" void kernel_launch(void* const* d_in, const int* in_sizes, int n_in,
                              void* d_out, int out_size, void* d_ws, size_t ws_size,
                              hipStream_t stream) {
    const float* base = (const float*)d_in[0];
    const float* z    = (const float*)d_in[1];
    const float* cond = (const float*)d_in[2];
    const float* W1 = (const float*)d_in[4];  const float* b1 = (const float*)d_in[5];
    const float* W2 = (const float*)d_in[6];  const float* b2 = (const float*)d_in[7];
    const float* W3 = (const float*)d_in[8];  const float* b3 = (const float*)d_in[9];
    const float* W4 = (const float*)d_in[10]; const float* b4 = (const float*)d_in[11];
    const float* K1 = (const float*)d_in[12]; const float* cb1 = (const float*)d_in[13];
    const float* K2 = (const float*)d_in[14]; const float* cb2 = (const float*)d_in[15];
    const float* K3 = (const float*)d_in[16]; const float* cb3 = (const float*)d_in[17];
    float* out = (float*)d_out;

    int B = in_sizes[0] / T_LEN;   // 16

    float* ws = (float*)d_ws;
    const size_t P1 = (size_t)16 * L_LEN * 128;    // per conv1 split
    const size_t P2 = (size_t)16 * L_LEN * 64;     // per conv2 split
    size_t need = (1024 + 4 * P1 + 2 * P2) * sizeof(float);

    float* P = ws;
    if (ws_size >= need) {
        float* parts1 = ws + 1024;
        float* parts2 = parts1 + 4 * P1;
        params_kernel2<<<B, 512, 0, stream>>>(z, cond, W1, b1, W2, b2, W3, b3, W4, b4, P);
        conv1_ws_kernel<<<512, 256, 0, stream>>>(z, cond, K1, parts1);
        conv2_split_kernel<<<512, 256, 0, stream>>>(parts1, cb1, K2, parts2);
        conv3_main_kernel<<<B * CB, 256, 0, stream>>>(base, parts2, cb2, K3, cb3, P, out);
    } else {
        float* g1 = ws + 1024;
        float* g2 = g1 + (size_t)B * L_LEN * 128;
        float* g3 = g2 + (size_t)B * L_LEN * 64;
        params_kernel<<<B, 256, 0, stream>>>(z, cond, W1, b1, W2, b2, W3, b3, W4, b4, P);
        conv1_mono_kernel<<<B * 16, 256, 0, stream>>>(z, cond, K1, cb1, g1);
        conv2_mono_kernel<<<B * 16, 256, 0, stream>>>(g1, K2, cb2, g2);
        conv3_mono_kernel<<<B * 16, 256, 0, stream>>>(g2, K3, cb3, g3);
        main_mono_kernel<<<B * CB, 256, 0, stream>>>(base, g3, P, out);
    }
}

// Round 9
// 76.062 us; speedup vs baseline: 1.0981x; 1.0981x over previous
//
#include <hip/hip_runtime.h>
#include <hip/hip_bf16.h>
#include <math.h>

#define L_LEN 250
#define D_DIM 128
#define C_DIM 32
#define DIN   160
#define NV    16
#define T_LEN 62400
#define CB    244            // ceil(62400/256)
#define ICB1  10             // conv1 ic per block (16 splits)

// ---------------- params v2: grid=16, 512 threads, K-parallel layers --------
// P layout per batch (40 floats): [0]=depth, [1]=coef, [2..17]=mask, [18..33]=pan
__global__ __launch_bounds__(512) void params_kernel2(
        const float* __restrict__ z, const float* __restrict__ cond,
        const float* __restrict__ W1, const float* __restrict__ b1,
        const float* __restrict__ W2, const float* __restrict__ b2,
        const float* __restrict__ W3, const float* __restrict__ b3,
        const float* __restrict__ W4, const float* __restrict__ b4,
        float* __restrict__ P) {
    int b = blockIdx.x;
    int tid = threadIdx.x;
    __shared__ float xb[DIN];
    __shared__ float red[512];
    __shared__ float h1[256];
    __shared__ float h2[128];
    __shared__ float h3[64];
    __shared__ float pr[4];
    __shared__ float4 sm4[16][32];

    {   // z-mean: 32 float4-cols x 16 row-groups
        int c4 = tid & 31, rg = tid >> 5;
        const float4* zp = (const float4*)(z + (size_t)b * L_LEN * D_DIM) + c4;
        float4 acc = make_float4(0.f, 0.f, 0.f, 0.f);
        for (int r = rg; r < L_LEN; r += 16) {
            float4 v = zp[(size_t)r * 32];
            acc.x += v.x; acc.y += v.y; acc.z += v.z; acc.w += v.w;
        }
        sm4[rg][c4] = acc;
    }
    __syncthreads();
    if (tid < 32) {
        float4 acc = sm4[0][tid];
        #pragma unroll
        for (int g = 1; g < 16; ++g) {
            float4 v = sm4[g][tid];
            acc.x += v.x; acc.y += v.y; acc.z += v.z; acc.w += v.w;
        }
        const float inv = 1.0f / (float)L_LEN;
        acc.x *= inv; acc.y *= inv; acc.z *= inv; acc.w *= inv;
        ((float4*)xb)[tid] = acc;
    } else if (tid >= 128 && tid < DIN) {
        xb[tid] = cond[b * C_DIM + (tid - 128)];
    }
    __syncthreads();

    {   // L1: 160 -> 256 ; 256 oc x 2 k-halves of 80
        int oc = tid & 255, half = tid >> 8;
        const float* w = W1 + (size_t)(half * 80) * 256 + oc;
        const float* x = xb + half * 80;
        float a0 = 0.f, a1 = 0.f, a2 = 0.f, a3 = 0.f;
        #pragma unroll 5
        for (int i = 0; i < 80; i += 4) {
            a0 = fmaf(x[i],     w[(size_t)(i)     * 256], a0);
            a1 = fmaf(x[i + 1], w[(size_t)(i + 1) * 256], a1);
            a2 = fmaf(x[i + 2], w[(size_t)(i + 2) * 256], a2);
            a3 = fmaf(x[i + 3], w[(size_t)(i + 3) * 256], a3);
        }
        red[tid] = (a0 + a1) + (a2 + a3);
    }
    __syncthreads();
    if (tid < 256) h1[tid] = fmaxf(red[tid] + red[tid + 256] + b1[tid], 0.f);
    __syncthreads();

    {   // L2: 256 -> 128 ; 128 oc x 4 k-groups of 64
        int oc = tid & 127, qg = tid >> 7;
        const float* w = W2 + (size_t)(qg * 64) * 128 + oc;
        const float* x = h1 + qg * 64;
        float a0 = 0.f, a1 = 0.f, a2 = 0.f, a3 = 0.f;
        #pragma unroll 4
        for (int i = 0; i < 64; i += 4) {
            a0 = fmaf(x[i],     w[(size_t)(i)     * 128], a0);
            a1 = fmaf(x[i + 1], w[(size_t)(i + 1) * 128], a1);
            a2 = fmaf(x[i + 2], w[(size_t)(i + 2) * 128], a2);
            a3 = fmaf(x[i + 3], w[(size_t)(i + 3) * 128], a3);
        }
        red[tid] = (a0 + a1) + (a2 + a3);
    }
    __syncthreads();
    if (tid < 128)
        h2[tid] = fmaxf(red[tid] + red[tid + 128] + red[tid + 256] + red[tid + 384] + b2[tid], 0.f);
    __syncthreads();

    {   // L3: 128 -> 64 ; 64 oc x 8 k-groups of 16
        int oc = tid & 63, qg = tid >> 6;
        const float* w = W3 + (size_t)(qg * 16) * 64 + oc;
        const float* x = h2 + qg * 16;
        float a0 = 0.f, a1 = 0.f;
        #pragma unroll 8
        for (int i = 0; i < 16; i += 2) {
            a0 = fmaf(x[i],     w[(size_t)(i)     * 64], a0);
            a1 = fmaf(x[i + 1], w[(size_t)(i + 1) * 64], a1);
        }
        red[tid] = a0 + a1;
    }
    __syncthreads();
    if (tid < 64) {
        float s = b3[tid];
        #pragma unroll
        for (int g = 0; g < 8; ++g) s += red[g * 64 + tid];
        h3[tid] = fmaxf(s, 0.f);
    }
    __syncthreads();

    if (tid < 256) {   // L4: 64 -> 4 ; fully parallel products
        int oc = tid & 3, k = tid >> 2;
        red[tid] = h3[k] * W4[k * 4 + oc];
    }
    __syncthreads();
    if (tid < 4) {
        float s = b4[tid];
        for (int k = 0; k < 64; ++k) s += red[k * 4 + tid];
        pr[tid] = s;
    }
    __syncthreads();
    if (tid == 0) {
        float num_voices = 1.0f + 14.0f / (1.0f + __expf(-pr[0]));
        float spread     = 1.0f / (1.0f + __expf(-pr[2]));
        float depth      = 0.5f / (1.0f + __expf(-pr[3]));
        float* Pb = P + b * 40;
        float msum = 0.f;
        for (int v = 0; v < NV; ++v) {
            float m = 1.0f / (1.0f + __expf(-(num_voices - (float)v) * 2.0f));
            msum += m;
            Pb[2 + v] = m;
            float pos = ((float)v - 7.5f) * (1.0f / 16.0f);
            Pb[2 + NV + v] = 1.0f - fabsf(pos) * spread * 0.5f;
        }
        float norm = sqrtf(msum + 1e-6f);
        Pb[0] = depth;
        Pb[1] = 1.0f / (norm + 1e-6f);
    }
}

// ---------------- conv1: 16 ic-splits x 16 b x 2 lh = 512 blocks ------------
// Thread = 4 oc x 16 l (64 acc). Weights [10 ic][7 tap][128 oc] in LDS (b128
// reads); window [10][136]. VALU-bound by construction.
__global__ __launch_bounds__(256) void conv1_ws_kernel(
        const float* __restrict__ z, const float* __restrict__ cond,
        const float* __restrict__ K1, float* __restrict__ parts1) {
    int tid = threadIdx.x;
    __shared__ float kw[ICB1 * 7 * 128];    // 35840 B
    __shared__ float smc[ICB1][136];        // 5440 B
    int blk = blockIdx.x;
    int s  = blk >> 5;            // 0..15
    int b  = (blk >> 1) & 15;
    int lh = blk & 1;
    int l0 = lh * 122;            // covers 0..127 / 122..249 (overlap benign)

    for (int idx = tid; idx < ICB1 * 7 * 128; idx += 256) {
        int oc = idx & 127;
        int r  = idx >> 7;            // r = ic*7+tap
        int tap = r % 7, ic = r / 7;
        kw[idx] = K1[((size_t)tap * DIN + s * ICB1 + ic) * 128 + oc];
    }
    for (int idx = tid; idx < 134 * ICB1; idx += 256) {
        int ic = idx % ICB1;
        int pl = idx / ICB1;
        int p  = l0 - 3 + pl;
        int gi = s * ICB1 + ic;
        float v = 0.f;
        if (p >= 0 && p < L_LEN)
            v = (gi < D_DIM) ? z[((size_t)b * L_LEN + p) * D_DIM + gi]
                             : cond[b * C_DIM + (gi - D_DIM)];
        smc[ic][pl] = v;
    }
    __syncthreads();

    int oc0 = (tid & 31) << 2;    // 0,4,...,124
    int lb  = (tid >> 5) << 4;    // 0,16,...,112
    float acc[4][16];
    #pragma unroll
    for (int o = 0; o < 4; ++o)
        #pragma unroll
        for (int j = 0; j < 16; ++j) acc[o][j] = 0.f;

    #pragma unroll 2
    for (int ic = 0; ic < ICB1; ++ic) {
        float zr[22];
        *(float4*)&zr[0]  = *(const float4*)&smc[ic][lb];
        *(float4*)&zr[4]  = *(const float4*)&smc[ic][lb + 4];
        *(float4*)&zr[8]  = *(const float4*)&smc[ic][lb + 8];
        *(float4*)&zr[12] = *(const float4*)&smc[ic][lb + 12];
        *(float4*)&zr[16] = *(const float4*)&smc[ic][lb + 16];
        *(float2*)&zr[20] = *(const float2*)&smc[ic][lb + 20];
        const float* kwp = &kw[ic * 7 * 128 + oc0];
        #pragma unroll
        for (int tap = 0; tap < 7; ++tap) {
            float4 w = *(const float4*)(kwp + tap * 128);
            #pragma unroll
            for (int j = 0; j < 16; ++j) {
                acc[0][j] = fmaf(zr[tap + j], w.x, acc[0][j]);
                acc[1][j] = fmaf(zr[tap + j], w.y, acc[1][j]);
                acc[2][j] = fmaf(zr[tap + j], w.z, acc[2][j]);
                acc[3][j] = fmaf(zr[tap + j], w.w, acc[3][j]);
            }
        }
    }
    float* po = parts1 + (size_t)s * (16 * L_LEN * 128)
              + (size_t)b * L_LEN * 128 + oc0;
    #pragma unroll
    for (int j = 0; j < 16; ++j) {
        int l = l0 + lb + j;
        if (l < L_LEN)
            *(float4*)(po + (size_t)l * 128) =
                make_float4(acc[0][j], acc[1][j], acc[2][j], acc[3][j]);
    }
}

// ---------------- conv2: 4 ic-splits x 16 b x 4 lt(64 l) = 256 blocks -------
// Thread = 2 oc x 8 l. Input = relu(cb1 + sum of 16 parts1 slices).
__global__ __launch_bounds__(256) void conv2_ws_kernel(
        const float* __restrict__ parts1, const float* __restrict__ cb1,
        const float* __restrict__ K2, float* __restrict__ parts2) {
    int tid = threadIdx.x;
    __shared__ float kw[32 * 5 * 64];     // 40960 B
    __shared__ float smr[32][72];         // 9216 B
    int s  = blockIdx.x >> 6;     // 0..3 (32 ch each)
    int b  = (blockIdx.x >> 2) & 15;
    int lt = blockIdx.x & 3;
    int l0 = lt * 62;             // 0,62,124,186 (64-l tiles, overlap benign)
    const int PSTR = 16 * L_LEN * 128;

    for (int idx = tid; idx < 32 * 5 * 64; idx += 256) {
        int oc = idx & 63;
        int r  = idx >> 6;            // r = ic*5+tap
        int tap = r % 5, ic = r / 5;
        kw[idx] = K2[((size_t)tap * 128 + s * 32 + ic) * 64 + oc];
    }
    for (int idx = tid; idx < 70 * 32; idx += 256) {
        int ch = idx & 31;
        int pl = idx >> 5;
        int p  = l0 - 2 + pl;
        int gi = s * 32 + ch;
        float v = 0.f;
        if (p >= 0 && p < L_LEN) {
            size_t o = ((size_t)b * L_LEN + p) * 128 + gi;
            float a = cb1[gi];
            #pragma unroll
            for (int k = 0; k < 16; ++k) a += parts1[o + (size_t)k * PSTR];
            v = fmaxf(a, 0.f);
        }
        smr[ch][pl] = v;
    }
    __syncthreads();

    int oc0 = (tid & 31) << 1;    // 0,2,...,62
    int lb  = (tid >> 5) << 3;    // 0,8,...,56
    float acc[2][8];
    #pragma unroll
    for (int j = 0; j < 8; ++j) { acc[0][j] = 0.f; acc[1][j] = 0.f; }

    #pragma unroll 2
    for (int ic = 0; ic < 32; ++ic) {
        float zr[12];
        *(float4*)&zr[0] = *(const float4*)&smr[ic][lb];
        *(float4*)&zr[4] = *(const float4*)&smr[ic][lb + 4];
        *(float4*)&zr[8] = *(const float4*)&smr[ic][lb + 8];
        const float* kwp = &kw[ic * 5 * 64 + oc0];
        #pragma unroll
        for (int tap = 0; tap < 5; ++tap) {
            float2 w = *(const float2*)(kwp + tap * 64);
            #pragma unroll
            for (int j = 0; j < 8; ++j) {
                acc[0][j] = fmaf(zr[tap + j], w.x, acc[0][j]);
                acc[1][j] = fmaf(zr[tap + j], w.y, acc[1][j]);
            }
        }
    }
    float* po = parts2 + (size_t)s * (16 * L_LEN * 64)
              + (size_t)b * L_LEN * 64 + oc0;
    #pragma unroll
    for (int j = 0; j < 8; ++j) {
        int l = l0 + lb + j;
        if (l < L_LEN)
            *(float2*)(po + (size_t)l * 64) = make_float2(acc[0][j], acc[1][j]);
    }
}

// ------- kernel 3: fused conv3 + upsample + softplus + unison mix ----------
__global__ __launch_bounds__(256) void conv3_main_kernel(
        const float* __restrict__ base, const float* __restrict__ parts2,
        const float* __restrict__ cb2,
        const float* __restrict__ K3, const float* __restrict__ cb3,
        const float* __restrict__ P, float* __restrict__ out) {
    int b = blockIdx.x / CB;
    int c = blockIdx.x % CB;
    int t0 = c * 256;
    int tid = threadIdx.x;
    const int PSTR2 = 16 * L_LEN * 64;
    const float scale = 250.0f / 62400.0f;

    __shared__ float k3t[16][196];   // [v][tap*64+ic]
    __shared__ float sA[6][68];      // g2 rows p = L0-1+pl, 0 if OOB
    __shared__ float g3loc[4][17];   // g3 rows L0..L0+3
    __shared__ float Pb[34];

    float src0 = ((float)t0 + 0.5f) * scale - 0.5f;
    src0 = fminf(fmaxf(src0, 0.0f), 249.0f);
    int L0 = (int)floorf(src0);

    if (tid < 34) Pb[tid] = P[b * 40 + tid];
    for (int idx = tid; idx < 3 * 64 * 16; idx += 256) {
        int v  = idx & 15;
        int ti = idx >> 4;
        k3t[v][ti] = K3[ti * 16 + v];
    }
    for (int idx = tid; idx < 6 * 64; idx += 256) {
        int pl = idx >> 6;
        int i  = idx & 63;
        int p  = L0 - 1 + pl;
        float v = 0.f;
        if (p >= 0 && p < L_LEN) {
            size_t o = ((size_t)b * L_LEN + p) * 64 + i;
            float a = cb2[i];
            #pragma unroll
            for (int k = 0; k < 4; ++k) a += parts2[o + (size_t)k * PSTR2];
            v = fmaxf(a, 0.f);
        }
        sA[pl][i] = v;
    }
    __syncthreads();

    {   // conv3: 4 rows x 16 v x 4 ic-segments; quad shuffle-reduce
        int seg = tid & 3;
        int v   = (tid >> 2) & 15;
        int r   = tid >> 6;
        float acc = 0.f;
        #pragma unroll
        for (int tap = 0; tap < 3; ++tap) {
            const float* gr = &sA[r + tap][seg * 16];
            const float* kr = &k3t[v][tap * 64 + seg * 16];
            #pragma unroll
            for (int j = 0; j < 4; ++j) {
                float4 g = *(const float4*)&gr[j * 4];
                float4 k = *(const float4*)&kr[j * 4];
                acc = fmaf(g.x, k.x, acc);
                acc = fmaf(g.y, k.y, acc);
                acc = fmaf(g.z, k.z, acc);
                acc = fmaf(g.w, k.w, acc);
            }
        }
        acc += __shfl_xor(acc, 1);
        acc += __shfl_xor(acc, 2);
        if (seg == 0) g3loc[r][v] = acc + cb3[v];
    }
    __syncthreads();

    int t = t0 + tid;
    if (t >= T_LEN) return;
    float depth = Pb[0];
    float coef  = Pb[1];
    float src = ((float)t + 0.5f) * scale - 0.5f;
    src = fminf(fmaxf(src, 0.0f), 249.0f);
    float fi0 = floorf(src);
    int i0 = (int)fi0;
    int i1 = min(i0 + 1, L_LEN - 1);
    float frac = src - fi0;
    int r0 = i0 - L0;
    int r1 = i1 - L0;
    float vg[16];
    #pragma unroll
    for (int v = 0; v < NV; ++v) {
        float a = g3loc[r0][v];
        float d = g3loc[r1][v];
        vg[v] = fmaf(d - a, frac, a);
    }
    float tsec = (float)t * (1.0f / 48000.0f);
    const float* bs = base + (size_t)b * T_LEN;
    const int shifts[NV] = {-9,-8,-6,-5,-4,-3,-1,0,0,1,3,4,5,6,8,9};
    float gain_sum = 0.f, uni = 0.f;
    #pragma unroll
    for (int v = 0; v < NV; ++v) {
        float x = vg[v];
        float sp = fmaxf(x, 0.f) + __logf(1.0f + __expf(-fabsf(x)));   // softplus
        float fv = 3.0f + 0.3f * (float)v;
        float ph = fv * tsec;
        ph -= floorf(ph);                       // revolutions in [0,1)
        float lfo = __builtin_amdgcn_sinf(ph);  // v_sin_f32: sin(2*pi*ph)
        int tb = t - shifts[v];
        if (tb < 0) tb += T_LEN; else if (tb >= T_LEN) tb -= T_LEN;
        float mod = bs[tb] * fmaf(0.2f * depth, lfo, 1.0f);
        gain_sum = fmaf(sp, Pb[2 + v], gain_sum);
        uni      = fmaf(mod * sp, Pb[2 + NV + v], uni);
    }
    out[(size_t)b * T_LEN + t] = gain_sum * coef * uni;
}

// ================= fallback (round-1 monolithic) kernels ====================
__global__ void params_kernel(const float* __restrict__ z, const float* __restrict__ cond,
                              const float* __restrict__ W1, const float* __restrict__ b1,
                              const float* __restrict__ W2, const float* __restrict__ b2,
                              const float* __restrict__ W3, const float* __restrict__ b3,
                              const float* __restrict__ W4, const float* __restrict__ b4,
                              float* __restrict__ P) {
    int b = blockIdx.x;
    int tid = threadIdx.x;
    __shared__ float xb[DIN];
    __shared__ float zp2[128];
    __shared__ float h1[256];
    __shared__ float h2[128];
    __shared__ float h3[64];
    __shared__ float pr[4];
    {
        int i = tid & 127, half = tid >> 7;
        const float* zp = z + (size_t)b * L_LEN * D_DIM + i;
        float s = 0.f;
        for (int l = half; l < L_LEN; l += 2) s += zp[(size_t)l * D_DIM];
        if (half) zp2[i] = s;
        __syncthreads();
        if (!half) xb[i] = (s + zp2[i]) * (1.0f / (float)L_LEN);
        if (tid >= 128 && tid < DIN) xb[tid] = cond[b * C_DIM + (tid - 128)];
    }
    __syncthreads();
    {
        float acc = b1[tid];
        for (int i = 0; i < DIN; ++i) acc = fmaf(xb[i], W1[i * 256 + tid], acc);
        h1[tid] = fmaxf(acc, 0.f);
    }
    __syncthreads();
    if (tid < 128) {
        float acc = b2[tid];
        for (int i = 0; i < 256; ++i) acc = fmaf(h1[i], W2[i * 128 + tid], acc);
        h2[tid] = fmaxf(acc, 0.f);
    }
    __syncthreads();
    if (tid < 64) {
        float acc = b3[tid];
        for (int i = 0; i < 128; ++i) acc = fmaf(h2[i], W3[i * 64 + tid], acc);
        h3[tid] = fmaxf(acc, 0.f);
    }
    __syncthreads();
    if (tid < 4) {
        float acc = b4[tid];
        for (int i = 0; i < 64; ++i) acc = fmaf(h3[i], W4[i * 4 + tid], acc);
        pr[tid] = acc;
    }
    __syncthreads();
    if (tid == 0) {
        float num_voices = 1.0f + 14.0f / (1.0f + __expf(-pr[0]));
        float spread     = 1.0f / (1.0f + __expf(-pr[2]));
        float depth      = 0.5f / (1.0f + __expf(-pr[3]));
        float* Pb = P + b * 40;
        float msum = 0.f;
        for (int v = 0; v < NV; ++v) {
            float m = 1.0f / (1.0f + __expf(-(num_voices - (float)v) * 2.0f));
            msum += m;
            Pb[2 + v] = m;
            float pos = ((float)v - 7.5f) * (1.0f / 16.0f);
            Pb[2 + NV + v] = 1.0f - fabsf(pos) * spread * 0.5f;
        }
        float norm = sqrtf(msum + 1e-6f);
        Pb[0] = depth;
        Pb[1] = 1.0f / (norm + 1e-6f);
    }
}

__global__ void conv1_mono_kernel(const float* __restrict__ z, const float* __restrict__ cond,
                                  const float* __restrict__ K1, const float* __restrict__ cb1,
                                  float* __restrict__ g1) {
    int b  = blockIdx.x >> 4;
    int lt = blockIdx.x & 15;
    int l0 = lt * 16;
    int tid = threadIdx.x;
    __shared__ float sm[DIN][22];
    for (int idx = tid; idx < 22 * DIN; idx += 256) {
        int pl = idx / DIN;
        int i  = idx - pl * DIN;
        int p  = l0 - 3 + pl;
        float v = 0.f;
        if (p >= 0 && p < L_LEN)
            v = (i < D_DIM) ? z[((size_t)b * L_LEN + p) * D_DIM + i]
                            : cond[b * C_DIM + (i - D_DIM)];
        sm[i][pl] = v;
    }
    __syncthreads();
    int oc = tid & 127;
    int lb = (tid >> 7) * 8;
    float bias = cb1[oc];
    float acc[8];
    #pragma unroll
    for (int j = 0; j < 8; ++j) acc[j] = bias;
    for (int i = 0; i < DIN; ++i) {
        float zr[14];
        #pragma unroll
        for (int q = 0; q < 14; ++q) zr[q] = sm[i][lb + q];
        #pragma unroll
        for (int tap = 0; tap < 7; ++tap) {
            float k = K1[(size_t)(tap * DIN + i) * 128 + oc];
            #pragma unroll
            for (int j = 0; j < 8; ++j) acc[j] = fmaf(zr[tap + j], k, acc[j]);
        }
    }
    #pragma unroll
    for (int j = 0; j < 8; ++j) {
        int l = l0 + lb + j;
        if (l < L_LEN) g1[((size_t)b * L_LEN + l) * 128 + oc] = fmaxf(acc[j], 0.f);
    }
}

__global__ void conv2_mono_kernel(const float* __restrict__ g1,
                                  const float* __restrict__ K2, const float* __restrict__ cb2,
                                  float* __restrict__ g2) {
    int b  = blockIdx.x >> 4;
    int lt = blockIdx.x & 15;
    int l0 = lt * 16;
    int tid = threadIdx.x;
    __shared__ float sm[128][20];
    for (int idx = tid; idx < 20 * 128; idx += 256) {
        int pl = idx >> 7;
        int i  = idx & 127;
        int p  = l0 - 2 + pl;
        float v = (p >= 0 && p < L_LEN) ? g1[((size_t)b * L_LEN + p) * 128 + i] : 0.f;
        sm[i][pl] = v;
    }
    __syncthreads();
    int oc = tid & 63;
    int lb = (tid >> 6) * 4;
    float bias = cb2[oc];
    float acc[4];
    #pragma unroll
    for (int j = 0; j < 4; ++j) acc[j] = bias;
    for (int i = 0; i < 128; ++i) {
        float zr[8];
        #pragma unroll
        for (int q = 0; q < 8; ++q) zr[q] = sm[i][lb + q];
        #pragma unroll
        for (int tap = 0; tap < 5; ++tap) {
            float k = K2[(size_t)(tap * 128 + i) * 64 + oc];
            #pragma unroll
            for (int j = 0; j < 4; ++j) acc[j] = fmaf(zr[tap + j], k, acc[j]);
        }
    }
    #pragma unroll
    for (int j = 0; j < 4; ++j) {
        int l = l0 + lb + j;
        if (l < L_LEN) g2[((size_t)b * L_LEN + l) * 64 + oc] = fmaxf(acc[j], 0.f);
    }
}

__global__ void conv3_mono_kernel(const float* __restrict__ g2,
                                  const float* __restrict__ K3, const float* __restrict__ cb3,
                                  float* __restrict__ g3) {
    int b  = blockIdx.x >> 4;
    int lt = blockIdx.x & 15;
    int l0 = lt * 16;
    int tid = threadIdx.x;
    int v  = tid & 15;
    int ll = tid >> 4;
    int l  = l0 + ll;
    if (l >= L_LEN) return;
    float acc = cb3[v];
    #pragma unroll
    for (int tap = 0; tap < 3; ++tap) {
        int p = l + tap - 1;
        if (p < 0 || p >= L_LEN) continue;
        const float* gp = g2 + ((size_t)b * L_LEN + p) * 64;
        #pragma unroll
        for (int i = 0; i < 64; ++i) acc = fmaf(gp[i], K3[(size_t)(tap * 64 + i) * 16 + v], acc);
    }
    g3[((size_t)b * L_LEN + l) * 16 + v] = acc;
}

__global__ __launch_bounds__(256) void main_mono_kernel(
        const float* __restrict__ base, const float* __restrict__ g3,
        const float* __restrict__ P, float* __restrict__ out) {
    int b = blockIdx.x / CB;
    int c = blockIdx.x % CB;
    int t = c * 256 + threadIdx.x;
    __shared__ float Pb[34];
    if (threadIdx.x < 34) Pb[threadIdx.x] = P[b * 40 + threadIdx.x];
    __syncthreads();
    if (t >= T_LEN) return;
    float depth = Pb[0];
    float coef  = Pb[1];
    const float scale = 250.0f / 62400.0f;
    float src = ((float)t + 0.5f) * scale - 0.5f;
    src = fminf(fmaxf(src, 0.0f), 249.0f);
    float fi0 = floorf(src);
    int i0 = (int)fi0;
    int i1 = min(i0 + 1, L_LEN - 1);
    float frac = src - fi0;
    const float4* r0 = (const float4*)(g3 + ((size_t)b * L_LEN + i0) * NV);
    const float4* r1 = (const float4*)(g3 + ((size_t)b * L_LEN + i1) * NV);
    float vg[16];
    #pragma unroll
    for (int q = 0; q < 4; ++q) {
        float4 a = r0[q];
        float4 d = r1[q];
        vg[q * 4 + 0] = fmaf(d.x - a.x, frac, a.x);
        vg[q * 4 + 1] = fmaf(d.y - a.y, frac, a.y);
        vg[q * 4 + 2] = fmaf(d.z - a.z, frac, a.z);
        vg[q * 4 + 3] = fmaf(d.w - a.w, frac, a.w);
    }
    float tsec = (float)t * (1.0f / 48000.0f);
    const float* bs = base + (size_t)b * T_LEN;
    const int shifts[NV] = {-9,-8,-6,-5,-4,-3,-1,0,0,1,3,4,5,6,8,9};
    float gain_sum = 0.f, uni = 0.f;
    #pragma unroll
    for (int v = 0; v < NV; ++v) {
        float x = vg[v];
        float sp = fmaxf(x, 0.f) + __logf(1.0f + __expf(-fabsf(x)));
        float fv = 3.0f + 0.3f * (float)v;
        float ph = fv * tsec;
        ph -= floorf(ph);
        float lfo = __builtin_amdgcn_sinf(ph);
        int tb = t - shifts[v];
        if (tb < 0) tb += T_LEN; else if (tb >= T_LEN) tb -= T_LEN;
        float mod = bs[tb] * fmaf(0.2f * depth, lfo, 1.0f);
        gain_sum = fmaf(sp, Pb[2 + v], gain_sum);
        uni      = fmaf(mod * sp, Pb[2 + NV + v], uni);
    }
    out[(size_t)b * T_LEN + t] = gain_sum * coef * uni;
}

extern "C" void kernel_launch(void* const* d_in, const int* in_sizes, int n_in,
                              void* d_out, int out_size, void* d_ws, size_t ws_size,
                              hipStream_t stream) {
    const float* base = (const float*)d_in[0];
    const float* z    = (const float*)d_in[1];
    const float* cond = (const float*)d_in[2];
    const float* W1 = (const float*)d_in[4];  const float* b1 = (const float*)d_in[5];
    const float* W2 = (const float*)d_in[6];  const float* b2 = (const float*)d_in[7];
    const float* W3 = (const float*)d_in[8];  const float* b3 = (const float*)d_in[9];
    const float* W4 = (const float*)d_in[10]; const float* b4 = (const float*)d_in[11];
    const float* K1 = (const float*)d_in[12]; const float* cb1 = (const float*)d_in[13];
    const float* K2 = (const float*)d_in[14]; const float* cb2 = (const float*)d_in[15];
    const float* K3 = (const float*)d_in[16]; const float* cb3 = (const float*)d_in[17];
    float* out = (float*)d_out;

    int B = in_sizes[0] / T_LEN;   // 16

    float* ws = (float*)d_ws;
    const size_t P1 = (size_t)16 * L_LEN * 128;    // per conv1 split (512000)
    const size_t P2 = (size_t)16 * L_LEN * 64;     // per conv2 split (256000)
    size_t need = (1024 + 16 * P1 + 4 * P2) * sizeof(float);   // ~36.9 MB

    float* P = ws;
    if (ws_size >= need) {
        float* parts1 = ws + 1024;
        float* parts2 = parts1 + 16 * P1;
        params_kernel2<<<B, 512, 0, stream>>>(z, cond, W1, b1, W2, b2, W3, b3, W4, b4, P);
        conv1_ws_kernel<<<512, 256, 0, stream>>>(z, cond, K1, parts1);
        conv2_ws_kernel<<<256, 256, 0, stream>>>(parts1, cb1, K2, parts2);
        conv3_main_kernel<<<B * CB, 256, 0, stream>>>(base, parts2, cb2, K3, cb3, P, out);
    } else {
        float* g1 = ws + 1024;
        float* g2 = g1 + (size_t)B * L_LEN * 128;
        float* g3 = g2 + (size_t)B * L_LEN * 64;
        params_kernel<<<B, 256, 0, stream>>>(z, cond, W1, b1, W2, b2, W3, b3, W4, b4, P);
        conv1_mono_kernel<<<B * 16, 256, 0, stream>>>(z, cond, K1, cb1, g1);
        conv2_mono_kernel<<<B * 16, 256, 0, stream>>>(g1, K2, cb2, g2);
        conv3_mono_kernel<<<B * 16, 256, 0, stream>>>(g2, K3, cb3, g3);
        main_mono_kernel<<<B * CB, 256, 0, stream>>>(base, g3, P, out);
    }
}

// Round 10
// 70.686 us; speedup vs baseline: 1.1816x; 1.0761x over previous
//
#include <hip/hip_runtime.h>
#include <hip/hip_bf16.h>
#include <math.h>

#define L_LEN 250
#define D_DIM 128
#define C_DIM 32
#define DIN   160
#define NV    16
#define T_LEN 62400
#define CB    244            // ceil(62400/256)
#define ICB1  10             // conv1 ic per block (16 splits)

// ------- kernel A: blocks 0..15 = K-parallel MLP ; 16..527 = conv1_ws -------
// P layout per batch (40 floats): [0]=depth, [1]=coef, [2..17]=mask, [18..33]=pan
__global__ __launch_bounds__(256) void conv1_mlp_kernel(
        const float* __restrict__ z, const float* __restrict__ cond,
        const float* __restrict__ K1, float* __restrict__ parts1,
        const float* __restrict__ W1, const float* __restrict__ b1,
        const float* __restrict__ W2, const float* __restrict__ b2,
        const float* __restrict__ W3, const float* __restrict__ b3,
        const float* __restrict__ W4, const float* __restrict__ b4,
        float* __restrict__ P) {
    int tid = threadIdx.x;
    __shared__ float kw[ICB1 * 7 * 128];    // 35840 B; MLP aliases into this
    __shared__ float smc[ICB1][136];        // 5440 B

    if (blockIdx.x < 16) {
        // ---------- K-parallel MLP (dispatched first, hides under conv1) ----
        int b = blockIdx.x;
        float* xb = kw;                     // 160
        float* h1 = kw + 160;               // 256
        float* h2 = kw + 416;               // 128
        float* h3 = kw + 544;               // 64
        float* pr = kw + 608;               // 4
        float* red = kw + 640;              // 512
        float4* sm4 = (float4*)(kw + 1152); // 256 float4
        {   // z-mean: 32 float4-cols x 8 row-groups, coalesced, batched loads
            int c4 = tid & 31, rg = tid >> 5;
            const float4* zp = (const float4*)(z + (size_t)b * L_LEN * D_DIM) + c4;
            float4 acc = make_float4(0.f, 0.f, 0.f, 0.f);
            for (int r = rg; r < L_LEN; r += 8) {
                float4 v = zp[(size_t)r * 32];
                acc.x += v.x; acc.y += v.y; acc.z += v.z; acc.w += v.w;
            }
            sm4[rg * 32 + c4] = acc;
        }
        __syncthreads();
        if (tid < 32) {
            float4 acc = sm4[tid];
            #pragma unroll
            for (int g = 1; g < 8; ++g) {
                float4 v = sm4[g * 32 + tid];
                acc.x += v.x; acc.y += v.y; acc.z += v.z; acc.w += v.w;
            }
            const float inv = 1.0f / (float)L_LEN;
            acc.x *= inv; acc.y *= inv; acc.z *= inv; acc.w *= inv;
            ((float4*)xb)[tid] = acc;
        } else if (tid >= 128 && tid < DIN) {
            xb[tid] = cond[b * C_DIM + (tid - 128)];
        }
        __syncthreads();
        {   // L1: 160 -> 256, one oc per thread, independent batched loads
            const float* w = W1 + tid;
            float a0 = b1[tid], a1 = 0.f, a2 = 0.f, a3 = 0.f;
            #pragma unroll 4
            for (int i = 0; i < DIN; i += 4) {
                a0 = fmaf(xb[i],     w[(size_t)(i)     * 256], a0);
                a1 = fmaf(xb[i + 1], w[(size_t)(i + 1) * 256], a1);
                a2 = fmaf(xb[i + 2], w[(size_t)(i + 2) * 256], a2);
                a3 = fmaf(xb[i + 3], w[(size_t)(i + 3) * 256], a3);
            }
            h1[tid] = fmaxf((a0 + a1) + (a2 + a3), 0.f);
        }
        __syncthreads();
        {   // L2: 256 -> 128 ; 128 oc x 2 k-halves of 128
            int oc = tid & 127, hh = tid >> 7;
            const float* w = W2 + (size_t)(hh * 128) * 128 + oc;
            const float* x = h1 + hh * 128;
            float a0 = 0.f, a1 = 0.f, a2 = 0.f, a3 = 0.f;
            #pragma unroll 4
            for (int i = 0; i < 128; i += 4) {
                a0 = fmaf(x[i],     w[(size_t)(i)     * 128], a0);
                a1 = fmaf(x[i + 1], w[(size_t)(i + 1) * 128], a1);
                a2 = fmaf(x[i + 2], w[(size_t)(i + 2) * 128], a2);
                a3 = fmaf(x[i + 3], w[(size_t)(i + 3) * 128], a3);
            }
            red[tid] = (a0 + a1) + (a2 + a3);
        }
        __syncthreads();
        if (tid < 128) h2[tid] = fmaxf(red[tid] + red[tid + 128] + b2[tid], 0.f);
        __syncthreads();
        {   // L3: 128 -> 64 ; 64 oc x 4 k-groups of 32
            int oc = tid & 63, qg = tid >> 6;
            const float* w = W3 + (size_t)(qg * 32) * 64 + oc;
            const float* x = h2 + qg * 32;
            float a0 = 0.f, a1 = 0.f;
            #pragma unroll 4
            for (int i = 0; i < 32; i += 2) {
                a0 = fmaf(x[i],     w[(size_t)(i)     * 64], a0);
                a1 = fmaf(x[i + 1], w[(size_t)(i + 1) * 64], a1);
            }
            red[tid] = a0 + a1;
        }
        __syncthreads();
        if (tid < 64)
            h3[tid] = fmaxf(red[tid] + red[tid + 64] + red[tid + 128] + red[tid + 192] + b3[tid], 0.f);
        __syncthreads();
        red[tid] = h3[tid >> 2] * W4[(tid >> 2) * 4 + (tid & 3)];   // L4 products
        __syncthreads();
        if (tid < 4) {
            float s = b4[tid];
            for (int k = 0; k < 64; ++k) s += red[k * 4 + tid];
            pr[tid] = s;
        }
        __syncthreads();
        if (tid == 0) {
            float num_voices = 1.0f + 14.0f / (1.0f + __expf(-pr[0]));
            float spread     = 1.0f / (1.0f + __expf(-pr[2]));
            float depth      = 0.5f / (1.0f + __expf(-pr[3]));
            float* Pb = P + b * 40;
            float msum = 0.f;
            for (int v = 0; v < NV; ++v) {
                float m = 1.0f / (1.0f + __expf(-(num_voices - (float)v) * 2.0f));
                msum += m;
                Pb[2 + v] = m;
                float pos = ((float)v - 7.5f) * (1.0f / 16.0f);
                Pb[2 + NV + v] = 1.0f - fabsf(pos) * spread * 0.5f;
            }
            float norm = sqrtf(msum + 1e-6f);
            Pb[0] = depth;
            Pb[1] = 1.0f / (norm + 1e-6f);
        }
        return;
    }
    // ---------------- conv1_ws: 16 ic-splits x 16 b x 2 lh ------------------
    // Thread = 4 oc x 16 l. VALU-bound by construction (round-9 body).
    int blk = blockIdx.x - 16;
    int s  = blk >> 5;            // 0..15
    int b  = (blk >> 1) & 15;
    int lh = blk & 1;
    int l0 = lh * 122;            // 0..127 / 122..249 (overlap benign)

    for (int idx = tid; idx < ICB1 * 7 * 128; idx += 256) {
        int oc = idx & 127;
        int r  = idx >> 7;            // r = ic*7+tap
        int tap = r % 7, ic = r / 7;
        kw[idx] = K1[((size_t)tap * DIN + s * ICB1 + ic) * 128 + oc];
    }
    for (int idx = tid; idx < 134 * ICB1; idx += 256) {
        int ic = idx % ICB1;
        int pl = idx / ICB1;
        int p  = l0 - 3 + pl;
        int gi = s * ICB1 + ic;
        float v = 0.f;
        if (p >= 0 && p < L_LEN)
            v = (gi < D_DIM) ? z[((size_t)b * L_LEN + p) * D_DIM + gi]
                             : cond[b * C_DIM + (gi - D_DIM)];
        smc[ic][pl] = v;
    }
    __syncthreads();

    int oc0 = (tid & 31) << 2;    // 0,4,...,124
    int lb  = (tid >> 5) << 4;    // 0,16,...,112
    float acc[4][16];
    #pragma unroll
    for (int o = 0; o < 4; ++o)
        #pragma unroll
        for (int j = 0; j < 16; ++j) acc[o][j] = 0.f;

    #pragma unroll 2
    for (int ic = 0; ic < ICB1; ++ic) {
        float zr[22];
        *(float4*)&zr[0]  = *(const float4*)&smc[ic][lb];
        *(float4*)&zr[4]  = *(const float4*)&smc[ic][lb + 4];
        *(float4*)&zr[8]  = *(const float4*)&smc[ic][lb + 8];
        *(float4*)&zr[12] = *(const float4*)&smc[ic][lb + 12];
        *(float4*)&zr[16] = *(const float4*)&smc[ic][lb + 16];
        *(float2*)&zr[20] = *(const float2*)&smc[ic][lb + 20];
        const float* kwp = &kw[ic * 7 * 128 + oc0];
        #pragma unroll
        for (int tap = 0; tap < 7; ++tap) {
            float4 w = *(const float4*)(kwp + tap * 128);
            #pragma unroll
            for (int j = 0; j < 16; ++j) {
                acc[0][j] = fmaf(zr[tap + j], w.x, acc[0][j]);
                acc[1][j] = fmaf(zr[tap + j], w.y, acc[1][j]);
                acc[2][j] = fmaf(zr[tap + j], w.z, acc[2][j]);
                acc[3][j] = fmaf(zr[tap + j], w.w, acc[3][j]);
            }
        }
    }
    float* po = parts1 + (size_t)s * (16 * L_LEN * 128)
              + (size_t)b * L_LEN * 128 + oc0;
    #pragma unroll
    for (int j = 0; j < 16; ++j) {
        int l = l0 + lb + j;
        if (l < L_LEN)
            *(float4*)(po + (size_t)l * 128) =
                make_float4(acc[0][j], acc[1][j], acc[2][j], acc[3][j]);
    }
}

// -------- conv2: 8 ic-splits(16) x 16 b x 4 lt(64 l) = 512 blocks -----------
// Thread = 2 oc x 8 l. Input = relu(cb1 + sum of 16 parts1 slices).
__global__ __launch_bounds__(256) void conv2_ws_kernel(
        const float* __restrict__ parts1, const float* __restrict__ cb1,
        const float* __restrict__ K2, float* __restrict__ parts2) {
    int tid = threadIdx.x;
    __shared__ float kw[16 * 5 * 64];     // 20480 B
    __shared__ float smr[16][72];         // 4608 B
    int s  = blockIdx.x >> 6;     // 0..7 (16 ch each)
    int b  = (blockIdx.x >> 2) & 15;
    int lt = blockIdx.x & 3;
    int l0 = lt * 62;             // 0,62,124,186 (64-l tiles, overlap benign)
    const int PSTR = 16 * L_LEN * 128;

    for (int idx = tid; idx < 16 * 5 * 64; idx += 256) {
        int oc = idx & 63;
        int r  = idx >> 6;            // r = ic*5+tap
        int tap = r % 5, ic = r / 5;
        kw[idx] = K2[((size_t)tap * 128 + s * 16 + ic) * 64 + oc];
    }
    for (int idx = tid; idx < 68 * 16; idx += 256) {
        int ch = idx & 15;
        int pl = idx >> 4;
        int p  = l0 - 2 + pl;
        int gi = s * 16 + ch;
        float v = 0.f;
        if (p >= 0 && p < L_LEN) {
            size_t o = ((size_t)b * L_LEN + p) * 128 + gi;
            float a = cb1[gi];
            #pragma unroll
            for (int k = 0; k < 16; ++k) a += parts1[o + (size_t)k * PSTR];
            v = fmaxf(a, 0.f);
        }
        smr[ch][pl] = v;
    }
    __syncthreads();

    int oc0 = (tid & 31) << 1;    // 0,2,...,62
    int lb  = (tid >> 5) << 3;    // 0,8,...,56
    float acc[2][8];
    #pragma unroll
    for (int j = 0; j < 8; ++j) { acc[0][j] = 0.f; acc[1][j] = 0.f; }

    #pragma unroll 2
    for (int ic = 0; ic < 16; ++ic) {
        float zr[12];
        *(float4*)&zr[0] = *(const float4*)&smr[ic][lb];
        *(float4*)&zr[4] = *(const float4*)&smr[ic][lb + 4];
        *(float4*)&zr[8] = *(const float4*)&smr[ic][lb + 8];
        const float* kwp = &kw[ic * 5 * 64 + oc0];
        #pragma unroll
        for (int tap = 0; tap < 5; ++tap) {
            float2 w = *(const float2*)(kwp + tap * 64);
            #pragma unroll
            for (int j = 0; j < 8; ++j) {
                acc[0][j] = fmaf(zr[tap + j], w.x, acc[0][j]);
                acc[1][j] = fmaf(zr[tap + j], w.y, acc[1][j]);
            }
        }
    }
    float* po = parts2 + (size_t)s * (16 * L_LEN * 64)
              + (size_t)b * L_LEN * 64 + oc0;
    #pragma unroll
    for (int j = 0; j < 8; ++j) {
        int l = l0 + lb + j;
        if (l < L_LEN)
            *(float2*)(po + (size_t)l * 64) = make_float2(acc[0][j], acc[1][j]);
    }
}

// ------- kernel C: fused conv3 + upsample + softplus + unison mix ----------
__global__ __launch_bounds__(256) void conv3_main_kernel(
        const float* __restrict__ base, const float* __restrict__ parts2,
        const float* __restrict__ cb2,
        const float* __restrict__ K3, const float* __restrict__ cb3,
        const float* __restrict__ P, float* __restrict__ out) {
    int b = blockIdx.x / CB;
    int c = blockIdx.x % CB;
    int t0 = c * 256;
    int tid = threadIdx.x;
    const int PSTR2 = 16 * L_LEN * 64;
    const float scale = 250.0f / 62400.0f;

    __shared__ float k3t[16][196];   // [v][tap*64+ic]
    __shared__ float sA[6][68];      // g2 rows p = L0-1+pl, 0 if OOB
    __shared__ float g3loc[4][17];   // g3 rows L0..L0+3
    __shared__ float Pb[34];

    float src0 = ((float)t0 + 0.5f) * scale - 0.5f;
    src0 = fminf(fmaxf(src0, 0.0f), 249.0f);
    int L0 = (int)floorf(src0);

    if (tid < 34) Pb[tid] = P[b * 40 + tid];
    for (int idx = tid; idx < 3 * 64 * 16; idx += 256) {
        int v  = idx & 15;
        int ti = idx >> 4;
        k3t[v][ti] = K3[ti * 16 + v];
    }
    for (int idx = tid; idx < 6 * 64; idx += 256) {
        int pl = idx >> 6;
        int i  = idx & 63;
        int p  = L0 - 1 + pl;
        float v = 0.f;
        if (p >= 0 && p < L_LEN) {
            size_t o = ((size_t)b * L_LEN + p) * 64 + i;
            float a = cb2[i];
            #pragma unroll
            for (int k = 0; k < 8; ++k) a += parts2[o + (size_t)k * PSTR2];
            v = fmaxf(a, 0.f);
        }
        sA[pl][i] = v;
    }
    __syncthreads();

    {   // conv3: 4 rows x 16 v x 4 ic-segments; quad shuffle-reduce
        int seg = tid & 3;
        int v   = (tid >> 2) & 15;
        int r   = tid >> 6;
        float acc = 0.f;
        #pragma unroll
        for (int tap = 0; tap < 3; ++tap) {
            const float* gr = &sA[r + tap][seg * 16];
            const float* kr = &k3t[v][tap * 64 + seg * 16];
            #pragma unroll
            for (int j = 0; j < 4; ++j) {
                float4 g = *(const float4*)&gr[j * 4];
                float4 k = *(const float4*)&kr[j * 4];
                acc = fmaf(g.x, k.x, acc);
                acc = fmaf(g.y, k.y, acc);
                acc = fmaf(g.z, k.z, acc);
                acc = fmaf(g.w, k.w, acc);
            }
        }
        acc += __shfl_xor(acc, 1);
        acc += __shfl_xor(acc, 2);
        if (seg == 0) g3loc[r][v] = acc + cb3[v];
    }
    __syncthreads();

    int t = t0 + tid;
    if (t >= T_LEN) return;
    float depth = Pb[0];
    float coef  = Pb[1];
    float src = ((float)t + 0.5f) * scale - 0.5f;
    src = fminf(fmaxf(src, 0.0f), 249.0f);
    float fi0 = floorf(src);
    int i0 = (int)fi0;
    int i1 = min(i0 + 1, L_LEN - 1);
    float frac = src - fi0;
    int r0 = i0 - L0;
    int r1 = i1 - L0;
    float vg[16];
    #pragma unroll
    for (int v = 0; v < NV; ++v) {
        float a = g3loc[r0][v];
        float d = g3loc[r1][v];
        vg[v] = fmaf(d - a, frac, a);
    }
    float tsec = (float)t * (1.0f / 48000.0f);
    const float* bs = base + (size_t)b * T_LEN;
    const int shifts[NV] = {-9,-8,-6,-5,-4,-3,-1,0,0,1,3,4,5,6,8,9};
    float gain_sum = 0.f, uni = 0.f;
    #pragma unroll
    for (int v = 0; v < NV; ++v) {
        float x = vg[v];
        float sp = fmaxf(x, 0.f) + __logf(1.0f + __expf(-fabsf(x)));   // softplus
        float fv = 3.0f + 0.3f * (float)v;
        float ph = fv * tsec;
        ph -= floorf(ph);                       // revolutions in [0,1)
        float lfo = __builtin_amdgcn_sinf(ph);  // v_sin_f32: sin(2*pi*ph)
        int tb = t - shifts[v];
        if (tb < 0) tb += T_LEN; else if (tb >= T_LEN) tb -= T_LEN;
        float mod = bs[tb] * fmaf(0.2f * depth, lfo, 1.0f);
        gain_sum = fmaf(sp, Pb[2 + v], gain_sum);
        uni      = fmaf(mod * sp, Pb[2 + NV + v], uni);
    }
    out[(size_t)b * T_LEN + t] = gain_sum * coef * uni;
}

// ================= fallback (round-1 monolithic) kernels ====================
__global__ void params_kernel(const float* __restrict__ z, const float* __restrict__ cond,
                              const float* __restrict__ W1, const float* __restrict__ b1,
                              const float* __restrict__ W2, const float* __restrict__ b2,
                              const float* __restrict__ W3, const float* __restrict__ b3,
                              const float* __restrict__ W4, const float* __restrict__ b4,
                              float* __restrict__ P) {
    int b = blockIdx.x;
    int tid = threadIdx.x;
    __shared__ float xb[DIN];
    __shared__ float zp2[128];
    __shared__ float h1[256];
    __shared__ float h2[128];
    __shared__ float h3[64];
    __shared__ float pr[4];
    {
        int i = tid & 127, half = tid >> 7;
        const float* zp = z + (size_t)b * L_LEN * D_DIM + i;
        float s = 0.f;
        for (int l = half; l < L_LEN; l += 2) s += zp[(size_t)l * D_DIM];
        if (half) zp2[i] = s;
        __syncthreads();
        if (!half) xb[i] = (s + zp2[i]) * (1.0f / (float)L_LEN);
        if (tid >= 128 && tid < DIN) xb[tid] = cond[b * C_DIM + (tid - 128)];
    }
    __syncthreads();
    {
        float acc = b1[tid];
        for (int i = 0; i < DIN; ++i) acc = fmaf(xb[i], W1[i * 256 + tid], acc);
        h1[tid] = fmaxf(acc, 0.f);
    }
    __syncthreads();
    if (tid < 128) {
        float acc = b2[tid];
        for (int i = 0; i < 256; ++i) acc = fmaf(h1[i], W2[i * 128 + tid], acc);
        h2[tid] = fmaxf(acc, 0.f);
    }
    __syncthreads();
    if (tid < 64) {
        float acc = b3[tid];
        for (int i = 0; i < 128; ++i) acc = fmaf(h2[i], W3[i * 64 + tid], acc);
        h3[tid] = fmaxf(acc, 0.f);
    }
    __syncthreads();
    if (tid < 4) {
        float acc = b4[tid];
        for (int i = 0; i < 64; ++i) acc = fmaf(h3[i], W4[i * 4 + tid], acc);
        pr[tid] = acc;
    }
    __syncthreads();
    if (tid == 0) {
        float num_voices = 1.0f + 14.0f / (1.0f + __expf(-pr[0]));
        float spread     = 1.0f / (1.0f + __expf(-pr[2]));
        float depth      = 0.5f / (1.0f + __expf(-pr[3]));
        float* Pb = P + b * 40;
        float msum = 0.f;
        for (int v = 0; v < NV; ++v) {
            float m = 1.0f / (1.0f + __expf(-(num_voices - (float)v) * 2.0f));
            msum += m;
            Pb[2 + v] = m;
            float pos = ((float)v - 7.5f) * (1.0f / 16.0f);
            Pb[2 + NV + v] = 1.0f - fabsf(pos) * spread * 0.5f;
        }
        float norm = sqrtf(msum + 1e-6f);
        Pb[0] = depth;
        Pb[1] = 1.0f / (norm + 1e-6f);
    }
}

__global__ void conv1_mono_kernel(const float* __restrict__ z, const float* __restrict__ cond,
                                  const float* __restrict__ K1, const float* __restrict__ cb1,
                                  float* __restrict__ g1) {
    int b  = blockIdx.x >> 4;
    int lt = blockIdx.x & 15;
    int l0 = lt * 16;
    int tid = threadIdx.x;
    __shared__ float sm[DIN][22];
    for (int idx = tid; idx < 22 * DIN; idx += 256) {
        int pl = idx / DIN;
        int i  = idx - pl * DIN;
        int p  = l0 - 3 + pl;
        float v = 0.f;
        if (p >= 0 && p < L_LEN)
            v = (i < D_DIM) ? z[((size_t)b * L_LEN + p) * D_DIM + i]
                            : cond[b * C_DIM + (i - D_DIM)];
        sm[i][pl] = v;
    }
    __syncthreads();
    int oc = tid & 127;
    int lb = (tid >> 7) * 8;
    float bias = cb1[oc];
    float acc[8];
    #pragma unroll
    for (int j = 0; j < 8; ++j) acc[j] = bias;
    for (int i = 0; i < DIN; ++i) {
        float zr[14];
        #pragma unroll
        for (int q = 0; q < 14; ++q) zr[q] = sm[i][lb + q];
        #pragma unroll
        for (int tap = 0; tap < 7; ++tap) {
            float k = K1[(size_t)(tap * DIN + i) * 128 + oc];
            #pragma unroll
            for (int j = 0; j < 8; ++j) acc[j] = fmaf(zr[tap + j], k, acc[j]);
        }
    }
    #pragma unroll
    for (int j = 0; j < 8; ++j) {
        int l = l0 + lb + j;
        if (l < L_LEN) g1[((size_t)b * L_LEN + l) * 128 + oc] = fmaxf(acc[j], 0.f);
    }
}

__global__ void conv2_mono_kernel(const float* __restrict__ g1,
                                  const float* __restrict__ K2, const float* __restrict__ cb2,
                                  float* __restrict__ g2) {
    int b  = blockIdx.x >> 4;
    int lt = blockIdx.x & 15;
    int l0 = lt * 16;
    int tid = threadIdx.x;
    __shared__ float sm[128][20];
    for (int idx = tid; idx < 20 * 128; idx += 256) {
        int pl = idx >> 7;
        int i  = idx & 127;
        int p  = l0 - 2 + pl;
        float v = (p >= 0 && p < L_LEN) ? g1[((size_t)b * L_LEN + p) * 128 + i] : 0.f;
        sm[i][pl] = v;
    }
    __syncthreads();
    int oc = tid & 63;
    int lb = (tid >> 6) * 4;
    float bias = cb2[oc];
    float acc[4];
    #pragma unroll
    for (int j = 0; j < 4; ++j) acc[j] = bias;
    for (int i = 0; i < 128; ++i) {
        float zr[8];
        #pragma unroll
        for (int q = 0; q < 8; ++q) zr[q] = sm[i][lb + q];
        #pragma unroll
        for (int tap = 0; tap < 5; ++tap) {
            float k = K2[(size_t)(tap * 128 + i) * 64 + oc];
            #pragma unroll
            for (int j = 0; j < 4; ++j) acc[j] = fmaf(zr[tap + j], k, acc[j]);
        }
    }
    #pragma unroll
    for (int j = 0; j < 4; ++j) {
        int l = l0 + lb + j;
        if (l < L_LEN) g2[((size_t)b * L_LEN + l) * 64 + oc] = fmaxf(acc[j], 0.f);
    }
}

__global__ void conv3_mono_kernel(const float* __restrict__ g2,
                                  const float* __restrict__ K3, const float* __restrict__ cb3,
                                  float* __restrict__ g3) {
    int b  = blockIdx.x >> 4;
    int lt = blockIdx.x & 15;
    int l0 = lt * 16;
    int tid = threadIdx.x;
    int v  = tid & 15;
    int ll = tid >> 4;
    int l  = l0 + ll;
    if (l >= L_LEN) return;
    float acc = cb3[v];
    #pragma unroll
    for (int tap = 0; tap < 3; ++tap) {
        int p = l + tap - 1;
        if (p < 0 || p >= L_LEN) continue;
        const float* gp = g2 + ((size_t)b * L_LEN + p) * 64;
        #pragma unroll
        for (int i = 0; i < 64; ++i) acc = fmaf(gp[i], K3[(size_t)(tap * 64 + i) * 16 + v], acc);
    }
    g3[((size_t)b * L_LEN + l) * 16 + v] = acc;
}

__global__ __launch_bounds__(256) void main_mono_kernel(
        const float* __restrict__ base, const float* __restrict__ g3,
        const float* __restrict__ P, float* __restrict__ out) {
    int b = blockIdx.x / CB;
    int c = blockIdx.x % CB;
    int t = c * 256 + threadIdx.x;
    __shared__ float Pb[34];
    if (threadIdx.x < 34) Pb[threadIdx.x] = P[b * 40 + threadIdx.x];
    __syncthreads();
    if (t >= T_LEN) return;
    float depth = Pb[0];
    float coef  = Pb[1];
    const float scale = 250.0f / 62400.0f;
    float src = ((float)t + 0.5f) * scale - 0.5f;
    src = fminf(fmaxf(src, 0.0f), 249.0f);
    float fi0 = floorf(src);
    int i0 = (int)fi0;
    int i1 = min(i0 + 1, L_LEN - 1);
    float frac = src - fi0;
    const float4* r0 = (const float4*)(g3 + ((size_t)b * L_LEN + i0) * NV);
    const float4* r1 = (const float4*)(g3 + ((size_t)b * L_LEN + i1) * NV);
    float vg[16];
    #pragma unroll
    for (int q = 0; q < 4; ++q) {
        float4 a = r0[q];
        float4 d = r1[q];
        vg[q * 4 + 0] = fmaf(d.x - a.x, frac, a.x);
        vg[q * 4 + 1] = fmaf(d.y - a.y, frac, a.y);
        vg[q * 4 + 2] = fmaf(d.z - a.z, frac, a.z);
        vg[q * 4 + 3] = fmaf(d.w - a.w, frac, a.w);
    }
    float tsec = (float)t * (1.0f / 48000.0f);
    const float* bs = base + (size_t)b * T_LEN;
    const int shifts[NV] = {-9,-8,-6,-5,-4,-3,-1,0,0,1,3,4,5,6,8,9};
    float gain_sum = 0.f, uni = 0.f;
    #pragma unroll
    for (int v = 0; v < NV; ++v) {
        float x = vg[v];
        float sp = fmaxf(x, 0.f) + __logf(1.0f + __expf(-fabsf(x)));
        float fv = 3.0f + 0.3f * (float)v;
        float ph = fv * tsec;
        ph -= floorf(ph);
        float lfo = __builtin_amdgcn_sinf(ph);
        int tb = t - shifts[v];
        if (tb < 0) tb += T_LEN; else if (tb >= T_LEN) tb -= T_LEN;
        float mod = bs[tb] * fmaf(0.2f * depth, lfo, 1.0f);
        gain_sum = fmaf(sp, Pb[2 + v], gain_sum);
        uni      = fmaf(mod * sp, Pb[2 + NV + v], uni);
    }
    out[(size_t)b * T_LEN + t] = gain_sum * coef * uni;
}

extern "C" void kernel_launch(void* const* d_in, const int* in_sizes, int n_in,
                              void* d_out, int out_size, void* d_ws, size_t ws_size,
                              hipStream_t stream) {
    const float* base = (const float*)d_in[0];
    const float* z    = (const float*)d_in[1];
    const float* cond = (const float*)d_in[2];
    const float* W1 = (const float*)d_in[4];  const float* b1 = (const float*)d_in[5];
    const float* W2 = (const float*)d_in[6];  const float* b2 = (const float*)d_in[7];
    const float* W3 = (const float*)d_in[8];  const float* b3 = (const float*)d_in[9];
    const float* W4 = (const float*)d_in[10]; const float* b4 = (const float*)d_in[11];
    const float* K1 = (const float*)d_in[12]; const float* cb1 = (const float*)d_in[13];
    const float* K2 = (const float*)d_in[14]; const float* cb2 = (const float*)d_in[15];
    const float* K3 = (const float*)d_in[16]; const float* cb3 = (const float*)d_in[17];
    float* out = (float*)d_out;

    int B = in_sizes[0] / T_LEN;   // 16

    float* ws = (float*)d_ws;
    const size_t P1 = (size_t)16 * L_LEN * 128;    // per conv1 split (512000)
    const size_t P2 = (size_t)16 * L_LEN * 64;     // per conv2 split (256000)
    size_t need = (1024 + 16 * P1 + 8 * P2) * sizeof(float);   // ~41 MB

    float* P = ws;
    if (ws_size >= need) {
        float* parts1 = ws + 1024;
        float* parts2 = parts1 + 16 * P1;
        conv1_mlp_kernel<<<16 + 512, 256, 0, stream>>>(
            z, cond, K1, parts1, W1, b1, W2, b2, W3, b3, W4, b4, P);
        conv2_ws_kernel<<<512, 256, 0, stream>>>(parts1, cb1, K2, parts2);
        conv3_main_kernel<<<B * CB, 256, 0, stream>>>(base, parts2, cb2, K3, cb3, P, out);
    } else {
        float* g1 = ws + 1024;
        float* g2 = g1 + (size_t)B * L_LEN * 128;
        float* g3 = g2 + (size_t)B * L_LEN * 64;
        params_kernel<<<B, 256, 0, stream>>>(z, cond, W1, b1, W2, b2, W3, b3, W4, b4, P);
        conv1_mono_kernel<<<B * 16, 256, 0, stream>>>(z, cond, K1, cb1, g1);
        conv2_mono_kernel<<<B * 16, 256, 0, stream>>>(g1, K2, cb2, g2);
        conv3_mono_kernel<<<B * 16, 256, 0, stream>>>(g2, K3, cb3, g3);
        main_mono_kernel<<<B * CB, 256, 0, stream>>>(base, g3, P, out);
    }
}

// Round 11
// 68.757 us; speedup vs baseline: 1.2147x; 1.0280x over previous
//
#include <hip/hip_runtime.h>
#include <hip/hip_bf16.h>
#include <math.h>

#define L_LEN 250
#define D_DIM 128
#define C_DIM 32
#define DIN   160
#define NV    16
#define T_LEN 62400
#define CB    244              // ceil(62400/256)
#define XROWS 272              // padded rows: r = l+3, l in [-3, 268]
#define NXB   (16 * XROWS * 160)   // Xb elements (bf16)
#define NK1   (128 * 1120)         // K1t elements (bf16)

typedef short short8 __attribute__((ext_vector_type(8)));
typedef float f32x4  __attribute__((ext_vector_type(4)));

// ---------------- kernel 0: build bf16 padded input + transposed weights ----
// Xb[b][r][ic] = (r-3 in [0,250)) ? concat(z,cond)[b][r-3][ic] : 0   (bf16)
// K1t[oc][tap*160+ic] = K1[tap][ic][oc]                              (bf16)
__global__ __launch_bounds__(256) void prep_kernel(
        const float* __restrict__ z, const float* __restrict__ cond,
        const float* __restrict__ K1,
        __hip_bfloat16* __restrict__ Xb, __hip_bfloat16* __restrict__ K1t) {
    int idx = blockIdx.x * 256 + threadIdx.x;
    if (idx < NXB) {
        int b   = idx / (XROWS * 160);
        int rem = idx - b * (XROWS * 160);
        int r   = rem / 160;
        int ic  = rem - r * 160;
        int l   = r - 3;
        float v = 0.f;
        if (l >= 0 && l < L_LEN)
            v = (ic < D_DIM) ? z[((size_t)b * L_LEN + l) * D_DIM + ic]
                             : cond[b * C_DIM + (ic - D_DIM)];
        Xb[idx] = __float2bfloat16(v);
    } else if (idx < NXB + NK1) {
        int j  = idx - NXB;
        int oc = j / 1120;
        int k  = j - oc * 1120;
        K1t[j] = __float2bfloat16(K1[(size_t)k * 128 + oc]);
    }
}

// ------- kernel A: blocks 0..15 = K-parallel MLP ; 16..271 = conv1 MFMA -----
// conv1: block=(b, lt). 4 waves; wave w computes C[16 l][32 oc] at oc0=w*32
// via mfma_f32_16x16x32_bf16 over K=1120 (7 taps x 5 k-slices). No split-K:
// writes g1 (single slice, no bias/relu — applied at conv2 staging).
// P layout per batch (40): [0]=depth, [1]=coef, [2..17]=mask, [18..33]=pan
__global__ __launch_bounds__(256) void conv1_mfma_mlp_kernel(
        const short* __restrict__ Xb, const short* __restrict__ K1t,
        float* __restrict__ g1,
        const float* __restrict__ z, const float* __restrict__ cond,
        const float* __restrict__ W1, const float* __restrict__ b1,
        const float* __restrict__ W2, const float* __restrict__ b2,
        const float* __restrict__ W3, const float* __restrict__ b3,
        const float* __restrict__ W4, const float* __restrict__ b4,
        float* __restrict__ P) {
    int tid = threadIdx.x;
    if (blockIdx.x < 16) {
        // ---------- K-parallel MLP (hides under conv1) ----------
        int b = blockIdx.x;
        __shared__ float buf[2176];
        float* xb = buf;                     // 160
        float* h1 = buf + 160;               // 256
        float* h2 = buf + 416;               // 128
        float* h3 = buf + 544;               // 64
        float* pr = buf + 608;               // 4
        float* red = buf + 640;              // 512
        float4* sm4 = (float4*)(buf + 1152); // 256 float4
        {
            int c4 = tid & 31, rg = tid >> 5;
            const float4* zp = (const float4*)(z + (size_t)b * L_LEN * D_DIM) + c4;
            float4 acc = make_float4(0.f, 0.f, 0.f, 0.f);
            for (int r = rg; r < L_LEN; r += 8) {
                float4 v = zp[(size_t)r * 32];
                acc.x += v.x; acc.y += v.y; acc.z += v.z; acc.w += v.w;
            }
            sm4[rg * 32 + c4] = acc;
        }
        __syncthreads();
        if (tid < 32) {
            float4 acc = sm4[tid];
            #pragma unroll
            for (int g = 1; g < 8; ++g) {
                float4 v = sm4[g * 32 + tid];
                acc.x += v.x; acc.y += v.y; acc.z += v.z; acc.w += v.w;
            }
            const float inv = 1.0f / (float)L_LEN;
            acc.x *= inv; acc.y *= inv; acc.z *= inv; acc.w *= inv;
            ((float4*)xb)[tid] = acc;
        } else if (tid >= 128 && tid < DIN) {
            xb[tid] = cond[b * C_DIM + (tid - 128)];
        }
        __syncthreads();
        {   // L1: 160 -> 256
            const float* w = W1 + tid;
            float a0 = b1[tid], a1 = 0.f, a2 = 0.f, a3 = 0.f;
            #pragma unroll 4
            for (int i = 0; i < DIN; i += 4) {
                a0 = fmaf(xb[i],     w[(size_t)(i)     * 256], a0);
                a1 = fmaf(xb[i + 1], w[(size_t)(i + 1) * 256], a1);
                a2 = fmaf(xb[i + 2], w[(size_t)(i + 2) * 256], a2);
                a3 = fmaf(xb[i + 3], w[(size_t)(i + 3) * 256], a3);
            }
            h1[tid] = fmaxf((a0 + a1) + (a2 + a3), 0.f);
        }
        __syncthreads();
        {   // L2: 256 -> 128 ; 2 k-halves
            int oc = tid & 127, hh = tid >> 7;
            const float* w = W2 + (size_t)(hh * 128) * 128 + oc;
            const float* x = h1 + hh * 128;
            float a0 = 0.f, a1 = 0.f, a2 = 0.f, a3 = 0.f;
            #pragma unroll 4
            for (int i = 0; i < 128; i += 4) {
                a0 = fmaf(x[i],     w[(size_t)(i)     * 128], a0);
                a1 = fmaf(x[i + 1], w[(size_t)(i + 1) * 128], a1);
                a2 = fmaf(x[i + 2], w[(size_t)(i + 2) * 128], a2);
                a3 = fmaf(x[i + 3], w[(size_t)(i + 3) * 128], a3);
            }
            red[tid] = (a0 + a1) + (a2 + a3);
        }
        __syncthreads();
        if (tid < 128) h2[tid] = fmaxf(red[tid] + red[tid + 128] + b2[tid], 0.f);
        __syncthreads();
        {   // L3: 128 -> 64 ; 4 k-groups
            int oc = tid & 63, qg = tid >> 6;
            const float* w = W3 + (size_t)(qg * 32) * 64 + oc;
            const float* x = h2 + qg * 32;
            float a0 = 0.f, a1 = 0.f;
            #pragma unroll 4
            for (int i = 0; i < 32; i += 2) {
                a0 = fmaf(x[i],     w[(size_t)(i)     * 64], a0);
                a1 = fmaf(x[i + 1], w[(size_t)(i + 1) * 64], a1);
            }
            red[tid] = a0 + a1;
        }
        __syncthreads();
        if (tid < 64)
            h3[tid] = fmaxf(red[tid] + red[tid + 64] + red[tid + 128] + red[tid + 192] + b3[tid], 0.f);
        __syncthreads();
        red[tid] = h3[tid >> 2] * W4[(tid >> 2) * 4 + (tid & 3)];
        __syncthreads();
        if (tid < 4) {
            float s = b4[tid];
            for (int k = 0; k < 64; ++k) s += red[k * 4 + tid];
            pr[tid] = s;
        }
        __syncthreads();
        if (tid == 0) {
            float num_voices = 1.0f + 14.0f / (1.0f + __expf(-pr[0]));
            float spread     = 1.0f / (1.0f + __expf(-pr[2]));
            float depth      = 0.5f / (1.0f + __expf(-pr[3]));
            float* Pb = P + b * 40;
            float msum = 0.f;
            for (int v = 0; v < NV; ++v) {
                float m = 1.0f / (1.0f + __expf(-(num_voices - (float)v) * 2.0f));
                msum += m;
                Pb[2 + v] = m;
                float pos = ((float)v - 7.5f) * (1.0f / 16.0f);
                Pb[2 + NV + v] = 1.0f - fabsf(pos) * spread * 0.5f;
            }
            float norm = sqrtf(msum + 1e-6f);
            Pb[0] = depth;
            Pb[1] = 1.0f / (norm + 1e-6f);
        }
        return;
    }
    // ---------------- conv1 MFMA path ----------------
    int blk = blockIdx.x - 16;
    int b   = blk >> 4;
    int lt  = blk & 15;
    int l0  = lt * 16;
    int lane = tid & 63;
    int oc0g = (tid >> 6) * 32;       // wave -> 32-oc stripe
    int m  = lane & 15;               // A row (M=l) / B,C col (N=oc)
    int kg = lane >> 4;               // k-octet group 0..3

    // A: Xb[b][l0+m+tap][kg*8 + ks*32 + j]   (16B contiguous along K)
    // B: K1t[oc0g+m(+16)][tap*160 + ks*32 + kg*8 + j]
    const short* Ab = Xb + ((size_t)(b * XROWS + l0 + m) * 160 + kg * 8);
    const short* Bb = K1t + ((size_t)(oc0g + m) * 1120 + kg * 8);

    f32x4 acc0 = {0.f, 0.f, 0.f, 0.f};
    f32x4 acc1 = {0.f, 0.f, 0.f, 0.f};
    #pragma unroll 1
    for (int tap = 0; tap < 7; ++tap) {
        const short* ap = Ab + tap * 160;
        const short* bp = Bb + tap * 160;
        #pragma unroll
        for (int ks = 0; ks < 5; ++ks) {
            short8 av  = *(const short8*)(ap + ks * 32);
            short8 bv0 = *(const short8*)(bp + ks * 32);
            short8 bv1 = *(const short8*)(bp + 16 * 1120 + ks * 32);
            acc0 = __builtin_amdgcn_mfma_f32_16x16x32_bf16(av, bv0, acc0, 0, 0, 0);
            acc1 = __builtin_amdgcn_mfma_f32_16x16x32_bf16(av, bv1, acc1, 0, 0, 0);
        }
    }
    // C/D: col = lane&15 (oc), row = kg*4 + reg (l)
    int rbase = l0 + kg * 4;
    #pragma unroll
    for (int j = 0; j < 4; ++j) {
        int lr = rbase + j;
        if (lr < L_LEN) {
            float* gp = g1 + ((size_t)b * L_LEN + lr) * 128 + oc0g + m;
            gp[0]  = acc0[j];
            gp[16] = acc1[j];
        }
    }
}

// -------- conv2: 8 ic-splits(16) x 16 b x 4 lt(64 l) = 512 blocks -----------
// Thread = 2 oc x 8 l. Input = relu(g1 + cb1)  (single slice now).
__global__ __launch_bounds__(256) void conv2_ws_kernel(
        const float* __restrict__ g1, const float* __restrict__ cb1,
        const float* __restrict__ K2, float* __restrict__ parts2) {
    int tid = threadIdx.x;
    __shared__ float kw[16 * 5 * 64];     // 20480 B
    __shared__ float smr[16][72];         // 4608 B
    int s  = blockIdx.x >> 6;     // 0..7 (16 ch each)
    int b  = (blockIdx.x >> 2) & 15;
    int lt = blockIdx.x & 3;
    int l0 = lt * 62;             // 0,62,124,186 (64-l tiles, overlap benign)

    for (int idx = tid; idx < 16 * 5 * 64; idx += 256) {
        int oc = idx & 63;
        int r  = idx >> 6;            // r = ic*5+tap
        int tap = r % 5, ic = r / 5;
        kw[idx] = K2[((size_t)tap * 128 + s * 16 + ic) * 64 + oc];
    }
    for (int idx = tid; idx < 68 * 16; idx += 256) {
        int ch = idx & 15;
        int pl = idx >> 4;
        int p  = l0 - 2 + pl;
        int gi = s * 16 + ch;
        float v = 0.f;
        if (p >= 0 && p < L_LEN)
            v = fmaxf(g1[((size_t)b * L_LEN + p) * 128 + gi] + cb1[gi], 0.f);
        smr[ch][pl] = v;
    }
    __syncthreads();

    int oc0 = (tid & 31) << 1;    // 0,2,...,62
    int lb  = (tid >> 5) << 3;    // 0,8,...,56
    float acc[2][8];
    #pragma unroll
    for (int j = 0; j < 8; ++j) { acc[0][j] = 0.f; acc[1][j] = 0.f; }

    #pragma unroll 2
    for (int ic = 0; ic < 16; ++ic) {
        float zr[12];
        *(float4*)&zr[0] = *(const float4*)&smr[ic][lb];
        *(float4*)&zr[4] = *(const float4*)&smr[ic][lb + 4];
        *(float4*)&zr[8] = *(const float4*)&smr[ic][lb + 8];
        const float* kwp = &kw[ic * 5 * 64 + oc0];
        #pragma unroll
        for (int tap = 0; tap < 5; ++tap) {
            float2 w = *(const float2*)(kwp + tap * 64);
            #pragma unroll
            for (int j = 0; j < 8; ++j) {
                acc[0][j] = fmaf(zr[tap + j], w.x, acc[0][j]);
                acc[1][j] = fmaf(zr[tap + j], w.y, acc[1][j]);
            }
        }
    }
    float* po = parts2 + (size_t)s * (16 * L_LEN * 64)
              + (size_t)b * L_LEN * 64 + oc0;
    #pragma unroll
    for (int j = 0; j < 8; ++j) {
        int l = l0 + lb + j;
        if (l < L_LEN)
            *(float2*)(po + (size_t)l * 64) = make_float2(acc[0][j], acc[1][j]);
    }
}

// ------- kernel C: fused conv3 + upsample + softplus + unison mix ----------
__global__ __launch_bounds__(256) void conv3_main_kernel(
        const float* __restrict__ base, const float* __restrict__ parts2,
        const float* __restrict__ cb2,
        const float* __restrict__ K3, const float* __restrict__ cb3,
        const float* __restrict__ P, float* __restrict__ out) {
    int b = blockIdx.x / CB;
    int c = blockIdx.x % CB;
    int t0 = c * 256;
    int tid = threadIdx.x;
    const int PSTR2 = 16 * L_LEN * 64;
    const float scale = 250.0f / 62400.0f;

    __shared__ float k3t[16][196];
    __shared__ float sA[6][68];
    __shared__ float g3loc[4][17];
    __shared__ float Pb[34];

    float src0 = ((float)t0 + 0.5f) * scale - 0.5f;
    src0 = fminf(fmaxf(src0, 0.0f), 249.0f);
    int L0 = (int)floorf(src0);

    if (tid < 34) Pb[tid] = P[b * 40 + tid];
    for (int idx = tid; idx < 3 * 64 * 16; idx += 256) {
        int v  = idx & 15;
        int ti = idx >> 4;
        k3t[v][ti] = K3[ti * 16 + v];
    }
    for (int idx = tid; idx < 6 * 64; idx += 256) {
        int pl = idx >> 6;
        int i  = idx & 63;
        int p  = L0 - 1 + pl;
        float v = 0.f;
        if (p >= 0 && p < L_LEN) {
            size_t o = ((size_t)b * L_LEN + p) * 64 + i;
            float a = cb2[i];
            #pragma unroll
            for (int k = 0; k < 8; ++k) a += parts2[o + (size_t)k * PSTR2];
            v = fmaxf(a, 0.f);
        }
        sA[pl][i] = v;
    }
    __syncthreads();

    {
        int seg = tid & 3;
        int v   = (tid >> 2) & 15;
        int r   = tid >> 6;
        float acc = 0.f;
        #pragma unroll
        for (int tap = 0; tap < 3; ++tap) {
            const float* gr = &sA[r + tap][seg * 16];
            const float* kr = &k3t[v][tap * 64 + seg * 16];
            #pragma unroll
            for (int j = 0; j < 4; ++j) {
                float4 g = *(const float4*)&gr[j * 4];
                float4 k = *(const float4*)&kr[j * 4];
                acc = fmaf(g.x, k.x, acc);
                acc = fmaf(g.y, k.y, acc);
                acc = fmaf(g.z, k.z, acc);
                acc = fmaf(g.w, k.w, acc);
            }
        }
        acc += __shfl_xor(acc, 1);
        acc += __shfl_xor(acc, 2);
        if (seg == 0) g3loc[r][v] = acc + cb3[v];
    }
    __syncthreads();

    int t = t0 + tid;
    if (t >= T_LEN) return;
    float depth = Pb[0];
    float coef  = Pb[1];
    float src = ((float)t + 0.5f) * scale - 0.5f;
    src = fminf(fmaxf(src, 0.0f), 249.0f);
    float fi0 = floorf(src);
    int i0 = (int)fi0;
    int i1 = min(i0 + 1, L_LEN - 1);
    float frac = src - fi0;
    int r0 = i0 - L0;
    int r1 = i1 - L0;
    float vg[16];
    #pragma unroll
    for (int v = 0; v < NV; ++v) {
        float a = g3loc[r0][v];
        float d = g3loc[r1][v];
        vg[v] = fmaf(d - a, frac, a);
    }
    float tsec = (float)t * (1.0f / 48000.0f);
    const float* bs = base + (size_t)b * T_LEN;
    const int shifts[NV] = {-9,-8,-6,-5,-4,-3,-1,0,0,1,3,4,5,6,8,9};
    float gain_sum = 0.f, uni = 0.f;
    #pragma unroll
    for (int v = 0; v < NV; ++v) {
        float x = vg[v];
        float sp = fmaxf(x, 0.f) + __logf(1.0f + __expf(-fabsf(x)));   // softplus
        float fv = 3.0f + 0.3f * (float)v;
        float ph = fv * tsec;
        ph -= floorf(ph);
        float lfo = __builtin_amdgcn_sinf(ph);  // v_sin_f32: revolutions
        int tb = t - shifts[v];
        if (tb < 0) tb += T_LEN; else if (tb >= T_LEN) tb -= T_LEN;
        float mod = bs[tb] * fmaf(0.2f * depth, lfo, 1.0f);
        gain_sum = fmaf(sp, Pb[2 + v], gain_sum);
        uni      = fmaf(mod * sp, Pb[2 + NV + v], uni);
    }
    out[(size_t)b * T_LEN + t] = gain_sum * coef * uni;
}

// ================= fallback (round-1 monolithic) kernels ====================
__global__ void params_kernel(const float* __restrict__ z, const float* __restrict__ cond,
                              const float* __restrict__ W1, const float* __restrict__ b1,
                              const float* __restrict__ W2, const float* __restrict__ b2,
                              const float* __restrict__ W3, const float* __restrict__ b3,
                              const float* __restrict__ W4, const float* __restrict__ b4,
                              float* __restrict__ P) {
    int b = blockIdx.x;
    int tid = threadIdx.x;
    __shared__ float xb[DIN];
    __shared__ float zp2[128];
    __shared__ float h1[256];
    __shared__ float h2[128];
    __shared__ float h3[64];
    __shared__ float pr[4];
    {
        int i = tid & 127, half = tid >> 7;
        const float* zp = z + (size_t)b * L_LEN * D_DIM + i;
        float s = 0.f;
        for (int l = half; l < L_LEN; l += 2) s += zp[(size_t)l * D_DIM];
        if (half) zp2[i] = s;
        __syncthreads();
        if (!half) xb[i] = (s + zp2[i]) * (1.0f / (float)L_LEN);
        if (tid >= 128 && tid < DIN) xb[tid] = cond[b * C_DIM + (tid - 128)];
    }
    __syncthreads();
    {
        float acc = b1[tid];
        for (int i = 0; i < DIN; ++i) acc = fmaf(xb[i], W1[i * 256 + tid], acc);
        h1[tid] = fmaxf(acc, 0.f);
    }
    __syncthreads();
    if (tid < 128) {
        float acc = b2[tid];
        for (int i = 0; i < 256; ++i) acc = fmaf(h1[i], W2[i * 128 + tid], acc);
        h2[tid] = fmaxf(acc, 0.f);
    }
    __syncthreads();
    if (tid < 64) {
        float acc = b3[tid];
        for (int i = 0; i < 128; ++i) acc = fmaf(h2[i], W3[i * 64 + tid], acc);
        h3[tid] = fmaxf(acc, 0.f);
    }
    __syncthreads();
    if (tid < 4) {
        float acc = b4[tid];
        for (int i = 0; i < 64; ++i) acc = fmaf(h3[i], W4[i * 4 + tid], acc);
        pr[tid] = acc;
    }
    __syncthreads();
    if (tid == 0) {
        float num_voices = 1.0f + 14.0f / (1.0f + __expf(-pr[0]));
        float spread     = 1.0f / (1.0f + __expf(-pr[2]));
        float depth      = 0.5f / (1.0f + __expf(-pr[3]));
        float* Pb = P + b * 40;
        float msum = 0.f;
        for (int v = 0; v < NV; ++v) {
            float m = 1.0f / (1.0f + __expf(-(num_voices - (float)v) * 2.0f));
            msum += m;
            Pb[2 + v] = m;
            float pos = ((float)v - 7.5f) * (1.0f / 16.0f);
            Pb[2 + NV + v] = 1.0f - fabsf(pos) * spread * 0.5f;
        }
        float norm = sqrtf(msum + 1e-6f);
        Pb[0] = depth;
        Pb[1] = 1.0f / (norm + 1e-6f);
    }
}

__global__ void conv1_mono_kernel(const float* __restrict__ z, const float* __restrict__ cond,
                                  const float* __restrict__ K1, const float* __restrict__ cb1,
                                  float* __restrict__ g1) {
    int b  = blockIdx.x >> 4;
    int lt = blockIdx.x & 15;
    int l0 = lt * 16;
    int tid = threadIdx.x;
    __shared__ float sm[DIN][22];
    for (int idx = tid; idx < 22 * DIN; idx += 256) {
        int pl = idx / DIN;
        int i  = idx - pl * DIN;
        int p  = l0 - 3 + pl;
        float v = 0.f;
        if (p >= 0 && p < L_LEN)
            v = (i < D_DIM) ? z[((size_t)b * L_LEN + p) * D_DIM + i]
                            : cond[b * C_DIM + (i - D_DIM)];
        sm[i][pl] = v;
    }
    __syncthreads();
    int oc = tid & 127;
    int lb = (tid >> 7) * 8;
    float bias = cb1[oc];
    float acc[8];
    #pragma unroll
    for (int j = 0; j < 8; ++j) acc[j] = bias;
    for (int i = 0; i < DIN; ++i) {
        float zr[14];
        #pragma unroll
        for (int q = 0; q < 14; ++q) zr[q] = sm[i][lb + q];
        #pragma unroll
        for (int tap = 0; tap < 7; ++tap) {
            float k = K1[(size_t)(tap * DIN + i) * 128 + oc];
            #pragma unroll
            for (int j = 0; j < 8; ++j) acc[j] = fmaf(zr[tap + j], k, acc[j]);
        }
    }
    #pragma unroll
    for (int j = 0; j < 8; ++j) {
        int l = l0 + lb + j;
        if (l < L_LEN) g1[((size_t)b * L_LEN + l) * 128 + oc] = fmaxf(acc[j], 0.f);
    }
}

__global__ void conv2_mono_kernel(const float* __restrict__ g1,
                                  const float* __restrict__ K2, const float* __restrict__ cb2,
                                  float* __restrict__ g2) {
    int b  = blockIdx.x >> 4;
    int lt = blockIdx.x & 15;
    int l0 = lt * 16;
    int tid = threadIdx.x;
    __shared__ float sm[128][20];
    for (int idx = tid; idx < 20 * 128; idx += 256) {
        int pl = idx >> 7;
        int i  = idx & 127;
        int p  = l0 - 2 + pl;
        float v = (p >= 0 && p < L_LEN) ? g1[((size_t)b * L_LEN + p) * 128 + i] : 0.f;
        sm[i][pl] = v;
    }
    __syncthreads();
    int oc = tid & 63;
    int lb = (tid >> 6) * 4;
    float bias = cb2[oc];
    float acc[4];
    #pragma unroll
    for (int j = 0; j < 4; ++j) acc[j] = bias;
    for (int i = 0; i < 128; ++i) {
        float zr[8];
        #pragma unroll
        for (int q = 0; q < 8; ++q) zr[q] = sm[i][lb + q];
        #pragma unroll
        for (int tap = 0; tap < 5; ++tap) {
            float k = K2[(size_t)(tap * 128 + i) * 64 + oc];
            #pragma unroll
            for (int j = 0; j < 4; ++j) acc[j] = fmaf(zr[tap + j], k, acc[j]);
        }
    }
    #pragma unroll
    for (int j = 0; j < 4; ++j) {
        int l = l0 + lb + j;
        if (l < L_LEN) g2[((size_t)b * L_LEN + l) * 64 + oc] = fmaxf(acc[j], 0.f);
    }
}

__global__ void conv3_mono_kernel(const float* __restrict__ g2,
                                  const float* __restrict__ K3, const float* __restrict__ cb3,
                                  float* __restrict__ g3) {
    int b  = blockIdx.x >> 4;
    int lt = blockIdx.x & 15;
    int l0 = lt * 16;
    int tid = threadIdx.x;
    int v  = tid & 15;
    int ll = tid >> 4;
    int l  = l0 + ll;
    if (l >= L_LEN) return;
    float acc = cb3[v];
    #pragma unroll
    for (int tap = 0; tap < 3; ++tap) {
        int p = l + tap - 1;
        if (p < 0 || p >= L_LEN) continue;
        const float* gp = g2 + ((size_t)b * L_LEN + p) * 64;
        #pragma unroll
        for (int i = 0; i < 64; ++i) acc = fmaf(gp[i], K3[(size_t)(tap * 64 + i) * 16 + v], acc);
    }
    g3[((size_t)b * L_LEN + l) * 16 + v] = acc;
}

__global__ __launch_bounds__(256) void main_mono_kernel(
        const float* __restrict__ base, const float* __restrict__ g3,
        const float* __restrict__ P, float* __restrict__ out) {
    int b = blockIdx.x / CB;
    int c = blockIdx.x % CB;
    int t = c * 256 + threadIdx.x;
    __shared__ float Pb[34];
    if (threadIdx.x < 34) Pb[threadIdx.x] = P[b * 40 + threadIdx.x];
    __syncthreads();
    if (t >= T_LEN) return;
    float depth = Pb[0];
    float coef  = Pb[1];
    const float scale = 250.0f / 62400.0f;
    float src = ((float)t + 0.5f) * scale - 0.5f;
    src = fminf(fmaxf(src, 0.0f), 249.0f);
    float fi0 = floorf(src);
    int i0 = (int)fi0;
    int i1 = min(i0 + 1, L_LEN - 1);
    float frac = src - fi0;
    const float4* r0 = (const float4*)(g3 + ((size_t)b * L_LEN + i0) * NV);
    const float4* r1 = (const float4*)(g3 + ((size_t)b * L_LEN + i1) * NV);
    float vg[16];
    #pragma unroll
    for (int q = 0; q < 4; ++q) {
        float4 a = r0[q];
        float4 d = r1[q];
        vg[q * 4 + 0] = fmaf(d.x - a.x, frac, a.x);
        vg[q * 4 + 1] = fmaf(d.y - a.y, frac, a.y);
        vg[q * 4 + 2] = fmaf(d.z - a.z, frac, a.z);
        vg[q * 4 + 3] = fmaf(d.w - a.w, frac, a.w);
    }
    float tsec = (float)t * (1.0f / 48000.0f);
    const float* bs = base + (size_t)b * T_LEN;
    const int shifts[NV] = {-9,-8,-6,-5,-4,-3,-1,0,0,1,3,4,5,6,8,9};
    float gain_sum = 0.f, uni = 0.f;
    #pragma unroll
    for (int v = 0; v < NV; ++v) {
        float x = vg[v];
        float sp = fmaxf(x, 0.f) + __logf(1.0f + __expf(-fabsf(x)));
        float fv = 3.0f + 0.3f * (float)v;
        float ph = fv * tsec;
        ph -= floorf(ph);
        float lfo = __builtin_amdgcn_sinf(ph);
        int tb = t - shifts[v];
        if (tb < 0) tb += T_LEN; else if (tb >= T_LEN) tb -= T_LEN;
        float mod = bs[tb] * fmaf(0.2f * depth, lfo, 1.0f);
        gain_sum = fmaf(sp, Pb[2 + v], gain_sum);
        uni      = fmaf(mod * sp, Pb[2 + NV + v], uni);
    }
    out[(size_t)b * T_LEN + t] = gain_sum * coef * uni;
}

extern "C" void kernel_launch(void* const* d_in, const int* in_sizes, int n_in,
                              void* d_out, int out_size, void* d_ws, size_t ws_size,
                              hipStream_t stream) {
    const float* base = (const float*)d_in[0];
    const float* z    = (const float*)d_in[1];
    const float* cond = (const float*)d_in[2];
    const float* W1 = (const float*)d_in[4];  const float* b1 = (const float*)d_in[5];
    const float* W2 = (const float*)d_in[6];  const float* b2 = (const float*)d_in[7];
    const float* W3 = (const float*)d_in[8];  const float* b3 = (const float*)d_in[9];
    const float* W4 = (const float*)d_in[10]; const float* b4 = (const float*)d_in[11];
    const float* K1 = (const float*)d_in[12]; const float* cb1 = (const float*)d_in[13];
    const float* K2 = (const float*)d_in[14]; const float* cb2 = (const float*)d_in[15];
    const float* K3 = (const float*)d_in[16]; const float* cb3 = (const float*)d_in[17];
    float* out = (float*)d_out;

    int B = in_sizes[0] / T_LEN;   // 16

    float* ws = (float*)d_ws;
    const size_t XBF = NXB / 2;            // Xb size in floats (348160)
    const size_t K1F = NK1 / 2;            // K1t size in floats (71680)
    const size_t G1  = (size_t)16 * L_LEN * 128;   // 512000
    const size_t P2  = (size_t)16 * L_LEN * 64;    // per conv2 slice (256000)
    size_t need = (1024 + XBF + K1F + G1 + 8 * P2) * sizeof(float);   // ~11.9 MB

    float* P = ws;
    if (ws_size >= need) {
        __hip_bfloat16* Xb  = (__hip_bfloat16*)(ws + 1024);
        __hip_bfloat16* K1t = (__hip_bfloat16*)(ws + 1024 + XBF);
        float* g1     = ws + 1024 + XBF + K1F;
        float* parts2 = g1 + G1;

        int prep_blocks = (NXB + NK1 + 255) / 256;   // 3280
        prep_kernel<<<prep_blocks, 256, 0, stream>>>(z, cond, K1, Xb, K1t);
        conv1_mfma_mlp_kernel<<<16 + 256, 256, 0, stream>>>(
            (const short*)Xb, (const short*)K1t, g1, z, cond,
            W1, b1, W2, b2, W3, b3, W4, b4, P);
        conv2_ws_kernel<<<512, 256, 0, stream>>>(g1, cb1, K2, parts2);
        conv3_main_kernel<<<B * CB, 256, 0, stream>>>(base, parts2, cb2, K3, cb3, P, out);
    } else {
        float* g1 = ws + 1024;
        float* g2 = g1 + (size_t)B * L_LEN * 128;
        float* g3 = g2 + (size_t)B * L_LEN * 64;
        params_kernel<<<B, 256, 0, stream>>>(z, cond, W1, b1, W2, b2, W3, b3, W4, b4, P);
        conv1_mono_kernel<<<B * 16, 256, 0, stream>>>(z, cond, K1, cb1, g1);
        conv2_mono_kernel<<<B * 16, 256, 0, stream>>>(g1, K2, cb2, g2);
        conv3_mono_kernel<<<B * 16, 256, 0, stream>>>(g2, K3, cb3, g3);
        main_mono_kernel<<<B * CB, 256, 0, stream>>>(base, g3, P, out);
    }
}

// Round 12
// 58.870 us; speedup vs baseline: 1.4187x; 1.1679x over previous
//
#include <hip/hip_runtime.h>
#include <hip/hip_bf16.h>
#include <math.h>

#define L_LEN 250
#define D_DIM 128
#define C_DIM 32
#define DIN   160
#define NV    16
#define T_LEN 62400
#define CB    244              // ceil(62400/256)
#define XROWS 272              // conv1 input pad rows: r = l+3
#define XR2   256              // g1b pad rows: r = l+2, l in [-2,253]
#define NXB   (16 * XROWS * 160)   // Xb elements (bf16)
#define NK1   (128 * 1120)         // K1t elements (bf16)
#define NK2   (64 * 640)           // K2t elements (bf16)
#define NPAD  (16 * 6 * 128)       // g1b pad-row elements to zero

typedef short short8 __attribute__((ext_vector_type(8)));
typedef float f32x4  __attribute__((ext_vector_type(4)));

// ------- kernel 0: bf16 padded input + transposed weights + g1b pad-zero ----
__global__ __launch_bounds__(256) void prep_kernel(
        const float* __restrict__ z, const float* __restrict__ cond,
        const float* __restrict__ K1, const float* __restrict__ K2,
        __hip_bfloat16* __restrict__ Xb, __hip_bfloat16* __restrict__ K1t,
        __hip_bfloat16* __restrict__ K2t, __hip_bfloat16* __restrict__ g1b) {
    int idx = blockIdx.x * 256 + threadIdx.x;
    if (idx < NXB) {
        int b   = idx / (XROWS * 160);
        int rem = idx - b * (XROWS * 160);
        int r   = rem / 160;
        int ic  = rem - r * 160;
        int l   = r - 3;
        float v = 0.f;
        if (l >= 0 && l < L_LEN)
            v = (ic < D_DIM) ? z[((size_t)b * L_LEN + l) * D_DIM + ic]
                             : cond[b * C_DIM + (ic - D_DIM)];
        Xb[idx] = __float2bfloat16(v);
    } else if (idx < NXB + NK1) {
        int j  = idx - NXB;
        int oc = j / 1120;
        int k  = j - oc * 1120;
        K1t[j] = __float2bfloat16(K1[(size_t)k * 128 + oc]);
    } else if (idx < NXB + NK1 + NK2) {
        int j  = idx - NXB - NK1;
        int oc = j / 640;
        int k  = j - oc * 640;
        K2t[j] = __float2bfloat16(K2[(size_t)k * 64 + oc]);
    } else if (idx < NXB + NK1 + NK2 + NPAD) {
        int j  = idx - NXB - NK1 - NK2;
        int b  = j / (6 * 128);
        int rem = j - b * (6 * 128);
        int rr = rem >> 7;
        int ic = rem & 127;
        int r  = (rr < 2) ? rr : 250 + rr;   // rows 0,1,252,253,254,255
        g1b[((size_t)b * XR2 + r) * 128 + ic] = __float2bfloat16(0.f);
    }
}

// ------- kernel A: blocks 0..15 = K-parallel MLP ; 16..271 = conv1 MFMA -----
// conv1 wave: C[16 l][32 oc], K=1120. Epilogue: g1b = bf16(relu(acc+cb1)),
// padded rows r=l+2. P layout (40): [0]=depth,[1]=coef,[2..17]=mask,[18..33]=pan
__global__ __launch_bounds__(256) void conv1_mfma_mlp_kernel(
        const short* __restrict__ Xb, const short* __restrict__ K1t,
        const float* __restrict__ cb1, __hip_bfloat16* __restrict__ g1b,
        const float* __restrict__ z, const float* __restrict__ cond,
        const float* __restrict__ W1, const float* __restrict__ b1,
        const float* __restrict__ W2, const float* __restrict__ b2,
        const float* __restrict__ W3, const float* __restrict__ b3,
        const float* __restrict__ W4, const float* __restrict__ b4,
        float* __restrict__ P) {
    int tid = threadIdx.x;
    if (blockIdx.x < 16) {
        // ---------- K-parallel MLP (hides under conv1) ----------
        int b = blockIdx.x;
        __shared__ float buf[2176];
        float* xb = buf;
        float* h1 = buf + 160;
        float* h2 = buf + 416;
        float* h3 = buf + 544;
        float* pr = buf + 608;
        float* red = buf + 640;
        float4* sm4 = (float4*)(buf + 1152);
        {
            int c4 = tid & 31, rg = tid >> 5;
            const float4* zp = (const float4*)(z + (size_t)b * L_LEN * D_DIM) + c4;
            float4 acc = make_float4(0.f, 0.f, 0.f, 0.f);
            for (int r = rg; r < L_LEN; r += 8) {
                float4 v = zp[(size_t)r * 32];
                acc.x += v.x; acc.y += v.y; acc.z += v.z; acc.w += v.w;
            }
            sm4[rg * 32 + c4] = acc;
        }
        __syncthreads();
        if (tid < 32) {
            float4 acc = sm4[tid];
            #pragma unroll
            for (int g = 1; g < 8; ++g) {
                float4 v = sm4[g * 32 + tid];
                acc.x += v.x; acc.y += v.y; acc.z += v.z; acc.w += v.w;
            }
            const float inv = 1.0f / (float)L_LEN;
            acc.x *= inv; acc.y *= inv; acc.z *= inv; acc.w *= inv;
            ((float4*)xb)[tid] = acc;
        } else if (tid >= 128 && tid < DIN) {
            xb[tid] = cond[b * C_DIM + (tid - 128)];
        }
        __syncthreads();
        {   // L1: 160 -> 256
            const float* w = W1 + tid;
            float a0 = b1[tid], a1 = 0.f, a2 = 0.f, a3 = 0.f;
            #pragma unroll 4
            for (int i = 0; i < DIN; i += 4) {
                a0 = fmaf(xb[i],     w[(size_t)(i)     * 256], a0);
                a1 = fmaf(xb[i + 1], w[(size_t)(i + 1) * 256], a1);
                a2 = fmaf(xb[i + 2], w[(size_t)(i + 2) * 256], a2);
                a3 = fmaf(xb[i + 3], w[(size_t)(i + 3) * 256], a3);
            }
            h1[tid] = fmaxf((a0 + a1) + (a2 + a3), 0.f);
        }
        __syncthreads();
        {   // L2: 256 -> 128 ; 2 k-halves
            int oc = tid & 127, hh = tid >> 7;
            const float* w = W2 + (size_t)(hh * 128) * 128 + oc;
            const float* x = h1 + hh * 128;
            float a0 = 0.f, a1 = 0.f, a2 = 0.f, a3 = 0.f;
            #pragma unroll 4
            for (int i = 0; i < 128; i += 4) {
                a0 = fmaf(x[i],     w[(size_t)(i)     * 128], a0);
                a1 = fmaf(x[i + 1], w[(size_t)(i + 1) * 128], a1);
                a2 = fmaf(x[i + 2], w[(size_t)(i + 2) * 128], a2);
                a3 = fmaf(x[i + 3], w[(size_t)(i + 3) * 128], a3);
            }
            red[tid] = (a0 + a1) + (a2 + a3);
        }
        __syncthreads();
        if (tid < 128) h2[tid] = fmaxf(red[tid] + red[tid + 128] + b2[tid], 0.f);
        __syncthreads();
        {   // L3: 128 -> 64 ; 4 k-groups
            int oc = tid & 63, qg = tid >> 6;
            const float* w = W3 + (size_t)(qg * 32) * 64 + oc;
            const float* x = h2 + qg * 32;
            float a0 = 0.f, a1 = 0.f;
            #pragma unroll 4
            for (int i = 0; i < 32; i += 2) {
                a0 = fmaf(x[i],     w[(size_t)(i)     * 64], a0);
                a1 = fmaf(x[i + 1], w[(size_t)(i + 1) * 64], a1);
            }
            red[tid] = a0 + a1;
        }
        __syncthreads();
        if (tid < 64)
            h3[tid] = fmaxf(red[tid] + red[tid + 64] + red[tid + 128] + red[tid + 192] + b3[tid], 0.f);
        __syncthreads();
        red[tid] = h3[tid >> 2] * W4[(tid >> 2) * 4 + (tid & 3)];
        __syncthreads();
        if (tid < 4) {
            float s = b4[tid];
            for (int k = 0; k < 64; ++k) s += red[k * 4 + tid];
            pr[tid] = s;
        }
        __syncthreads();
        if (tid == 0) {
            float num_voices = 1.0f + 14.0f / (1.0f + __expf(-pr[0]));
            float spread     = 1.0f / (1.0f + __expf(-pr[2]));
            float depth      = 0.5f / (1.0f + __expf(-pr[3]));
            float* Pb = P + b * 40;
            float msum = 0.f;
            for (int v = 0; v < NV; ++v) {
                float m = 1.0f / (1.0f + __expf(-(num_voices - (float)v) * 2.0f));
                msum += m;
                Pb[2 + v] = m;
                float pos = ((float)v - 7.5f) * (1.0f / 16.0f);
                Pb[2 + NV + v] = 1.0f - fabsf(pos) * spread * 0.5f;
            }
            float norm = sqrtf(msum + 1e-6f);
            Pb[0] = depth;
            Pb[1] = 1.0f / (norm + 1e-6f);
        }
        return;
    }
    // ---------------- conv1 MFMA path (verified layout, R11) ----------------
    int blk = blockIdx.x - 16;
    int b   = blk >> 4;
    int lt  = blk & 15;
    int l0  = lt * 16;
    int lane = tid & 63;
    int oc0g = (tid >> 6) * 32;
    int m  = lane & 15;
    int kg = lane >> 4;

    const short* Ab = Xb + ((size_t)(b * XROWS + l0 + m) * 160 + kg * 8);
    const short* Bb = K1t + ((size_t)(oc0g + m) * 1120 + kg * 8);

    f32x4 acc0 = {0.f, 0.f, 0.f, 0.f};
    f32x4 acc1 = {0.f, 0.f, 0.f, 0.f};
    #pragma unroll 1
    for (int tap = 0; tap < 7; ++tap) {
        const short* ap = Ab + tap * 160;
        const short* bp = Bb + tap * 160;
        #pragma unroll
        for (int ks = 0; ks < 5; ++ks) {
            short8 av  = *(const short8*)(ap + ks * 32);
            short8 bv0 = *(const short8*)(bp + ks * 32);
            short8 bv1 = *(const short8*)(bp + 16 * 1120 + ks * 32);
            acc0 = __builtin_amdgcn_mfma_f32_16x16x32_bf16(av, bv0, acc0, 0, 0, 0);
            acc1 = __builtin_amdgcn_mfma_f32_16x16x32_bf16(av, bv1, acc1, 0, 0, 0);
        }
    }
    // C/D: col = lane&15 (oc), row = kg*4+reg (l). Fold bias+relu, write bf16.
    float bias0 = cb1[oc0g + m];
    float bias1 = cb1[oc0g + m + 16];
    int rbase = l0 + kg * 4;
    #pragma unroll
    for (int j = 0; j < 4; ++j) {
        int lr = rbase + j;
        if (lr < L_LEN) {
            __hip_bfloat16* gp = g1b + ((size_t)(b * XR2) + lr + 2) * 128 + oc0g + m;
            gp[0]  = __float2bfloat16(fmaxf(acc0[j] + bias0, 0.f));
            gp[16] = __float2bfloat16(fmaxf(acc1[j] + bias1, 0.f));
        }
    }
}

// ------- kernel B: conv2 MFMA. 16b x 16lt = 256 blocks; wave = 16l x 16oc ---
// A = g1b padded (r=l+tap works out exactly), B = K2t, K=640 (5 taps x 4 ks).
__global__ __launch_bounds__(256) void conv2_mfma_kernel(
        const short* __restrict__ g1b, const short* __restrict__ K2t,
        float* __restrict__ g2) {
    int tid = threadIdx.x;
    int b   = blockIdx.x >> 4;
    int lt  = blockIdx.x & 15;
    int l0  = lt * 16;
    int lane = tid & 63;
    int oc0w = (tid >> 6) * 16;
    int m  = lane & 15;
    int kg = lane >> 4;

    // A row for (l, tap): padded r = l + tap  (since r = l' + 2, l' = l-2+tap)
    const short* Ab = g1b + ((size_t)(b * XR2 + l0 + m) * 128 + kg * 8);
    const short* Bb = K2t + ((size_t)(oc0w + m) * 640 + kg * 8);

    f32x4 acc = {0.f, 0.f, 0.f, 0.f};
    #pragma unroll 1
    for (int tap = 0; tap < 5; ++tap) {
        const short* ap = Ab + tap * 128;
        const short* bp = Bb + tap * 128;
        #pragma unroll
        for (int ks = 0; ks < 4; ++ks) {
            short8 av = *(const short8*)(ap + ks * 32);
            short8 bv = *(const short8*)(bp + ks * 32);
            acc = __builtin_amdgcn_mfma_f32_16x16x32_bf16(av, bv, acc, 0, 0, 0);
        }
    }
    int rbase = l0 + kg * 4;
    #pragma unroll
    for (int j = 0; j < 4; ++j) {
        int l = rbase + j;
        if (l < L_LEN)
            g2[((size_t)b * L_LEN + l) * 64 + oc0w + m] = acc[j];
    }
}

// ------- kernel C: fused conv3 + upsample + softplus + unison mix ----------
__global__ __launch_bounds__(256) void conv3_main_kernel(
        const float* __restrict__ base, const float* __restrict__ g2,
        const float* __restrict__ cb2,
        const float* __restrict__ K3, const float* __restrict__ cb3,
        const float* __restrict__ P, float* __restrict__ out) {
    int b = blockIdx.x / CB;
    int c = blockIdx.x % CB;
    int t0 = c * 256;
    int tid = threadIdx.x;
    const float scale = 250.0f / 62400.0f;

    __shared__ float k3t[16][196];
    __shared__ float sA[6][68];
    __shared__ float g3loc[4][17];
    __shared__ float Pb[34];

    float src0 = ((float)t0 + 0.5f) * scale - 0.5f;
    src0 = fminf(fmaxf(src0, 0.0f), 249.0f);
    int L0 = (int)floorf(src0);

    if (tid < 34) Pb[tid] = P[b * 40 + tid];
    for (int idx = tid; idx < 3 * 64 * 16; idx += 256) {
        int v  = idx & 15;
        int ti = idx >> 4;
        k3t[v][ti] = K3[ti * 16 + v];
    }
    for (int idx = tid; idx < 6 * 64; idx += 256) {
        int pl = idx >> 6;
        int i  = idx & 63;
        int p  = L0 - 1 + pl;
        float v = 0.f;
        if (p >= 0 && p < L_LEN)
            v = fmaxf(cb2[i] + g2[((size_t)b * L_LEN + p) * 64 + i], 0.f);
        sA[pl][i] = v;
    }
    __syncthreads();

    {   // conv3: 4 rows x 16 v x 4 ic-segments; quad shuffle-reduce
        int seg = tid & 3;
        int v   = (tid >> 2) & 15;
        int r   = tid >> 6;
        float acc = 0.f;
        #pragma unroll
        for (int tap = 0; tap < 3; ++tap) {
            const float* gr = &sA[r + tap][seg * 16];
            const float* kr = &k3t[v][tap * 64 + seg * 16];
            #pragma unroll
            for (int j = 0; j < 4; ++j) {
                float4 g = *(const float4*)&gr[j * 4];
                float4 k = *(const float4*)&kr[j * 4];
                acc = fmaf(g.x, k.x, acc);
                acc = fmaf(g.y, k.y, acc);
                acc = fmaf(g.z, k.z, acc);
                acc = fmaf(g.w, k.w, acc);
            }
        }
        acc += __shfl_xor(acc, 1);
        acc += __shfl_xor(acc, 2);
        if (seg == 0) g3loc[r][v] = acc + cb3[v];
    }
    __syncthreads();

    int t = t0 + tid;
    if (t >= T_LEN) return;
    float depth = Pb[0];
    float coef  = Pb[1];
    float src = ((float)t + 0.5f) * scale - 0.5f;
    src = fminf(fmaxf(src, 0.0f), 249.0f);
    float fi0 = floorf(src);
    int i0 = (int)fi0;
    int i1 = min(i0 + 1, L_LEN - 1);
    float frac = src - fi0;
    int r0 = i0 - L0;
    int r1 = i1 - L0;
    float vg[16];
    #pragma unroll
    for (int v = 0; v < NV; ++v) {
        float a = g3loc[r0][v];
        float d = g3loc[r1][v];
        vg[v] = fmaf(d - a, frac, a);
    }
    float tsec = (float)t * (1.0f / 48000.0f);
    const float* bs = base + (size_t)b * T_LEN;
    const int shifts[NV] = {-9,-8,-6,-5,-4,-3,-1,0,0,1,3,4,5,6,8,9};
    float gain_sum = 0.f, uni = 0.f;
    #pragma unroll
    for (int v = 0; v < NV; ++v) {
        float x = vg[v];
        float sp = fmaxf(x, 0.f) + __logf(1.0f + __expf(-fabsf(x)));   // softplus
        float fv = 3.0f + 0.3f * (float)v;
        float ph = fv * tsec;
        ph -= floorf(ph);
        float lfo = __builtin_amdgcn_sinf(ph);  // v_sin_f32: revolutions
        int tb = t - shifts[v];
        if (tb < 0) tb += T_LEN; else if (tb >= T_LEN) tb -= T_LEN;
        float mod = bs[tb] * fmaf(0.2f * depth, lfo, 1.0f);
        gain_sum = fmaf(sp, Pb[2 + v], gain_sum);
        uni      = fmaf(mod * sp, Pb[2 + NV + v], uni);
    }
    out[(size_t)b * T_LEN + t] = gain_sum * coef * uni;
}

// ================= fallback (round-1 monolithic) kernels ====================
__global__ void params_kernel(const float* __restrict__ z, const float* __restrict__ cond,
                              const float* __restrict__ W1, const float* __restrict__ b1,
                              const float* __restrict__ W2, const float* __restrict__ b2,
                              const float* __restrict__ W3, const float* __restrict__ b3,
                              const float* __restrict__ W4, const float* __restrict__ b4,
                              float* __restrict__ P) {
    int b = blockIdx.x;
    int tid = threadIdx.x;
    __shared__ float xb[DIN];
    __shared__ float zp2[128];
    __shared__ float h1[256];
    __shared__ float h2[128];
    __shared__ float h3[64];
    __shared__ float pr[4];
    {
        int i = tid & 127, half = tid >> 7;
        const float* zp = z + (size_t)b * L_LEN * D_DIM + i;
        float s = 0.f;
        for (int l = half; l < L_LEN; l += 2) s += zp[(size_t)l * D_DIM];
        if (half) zp2[i] = s;
        __syncthreads();
        if (!half) xb[i] = (s + zp2[i]) * (1.0f / (float)L_LEN);
        if (tid >= 128 && tid < DIN) xb[tid] = cond[b * C_DIM + (tid - 128)];
    }
    __syncthreads();
    {
        float acc = b1[tid];
        for (int i = 0; i < DIN; ++i) acc = fmaf(xb[i], W1[i * 256 + tid], acc);
        h1[tid] = fmaxf(acc, 0.f);
    }
    __syncthreads();
    if (tid < 128) {
        float acc = b2[tid];
        for (int i = 0; i < 256; ++i) acc = fmaf(h1[i], W2[i * 128 + tid], acc);
        h2[tid] = fmaxf(acc, 0.f);
    }
    __syncthreads();
    if (tid < 64) {
        float acc = b3[tid];
        for (int i = 0; i < 128; ++i) acc = fmaf(h2[i], W3[i * 64 + tid], acc);
        h3[tid] = fmaxf(acc, 0.f);
    }
    __syncthreads();
    if (tid < 4) {
        float acc = b4[tid];
        for (int i = 0; i < 64; ++i) acc = fmaf(h3[i], W4[i * 4 + tid], acc);
        pr[tid] = acc;
    }
    __syncthreads();
    if (tid == 0) {
        float num_voices = 1.0f + 14.0f / (1.0f + __expf(-pr[0]));
        float spread     = 1.0f / (1.0f + __expf(-pr[2]));
        float depth      = 0.5f / (1.0f + __expf(-pr[3]));
        float* Pb = P + b * 40;
        float msum = 0.f;
        for (int v = 0; v < NV; ++v) {
            float m = 1.0f / (1.0f + __expf(-(num_voices - (float)v) * 2.0f));
            msum += m;
            Pb[2 + v] = m;
            float pos = ((float)v - 7.5f) * (1.0f / 16.0f);
            Pb[2 + NV + v] = 1.0f - fabsf(pos) * spread * 0.5f;
        }
        float norm = sqrtf(msum + 1e-6f);
        Pb[0] = depth;
        Pb[1] = 1.0f / (norm + 1e-6f);
    }
}

__global__ void conv1_mono_kernel(const float* __restrict__ z, const float* __restrict__ cond,
                                  const float* __restrict__ K1, const float* __restrict__ cb1,
                                  float* __restrict__ g1) {
    int b  = blockIdx.x >> 4;
    int lt = blockIdx.x & 15;
    int l0 = lt * 16;
    int tid = threadIdx.x;
    __shared__ float sm[DIN][22];
    for (int idx = tid; idx < 22 * DIN; idx += 256) {
        int pl = idx / DIN;
        int i  = idx - pl * DIN;
        int p  = l0 - 3 + pl;
        float v = 0.f;
        if (p >= 0 && p < L_LEN)
            v = (i < D_DIM) ? z[((size_t)b * L_LEN + p) * D_DIM + i]
                            : cond[b * C_DIM + (i - D_DIM)];
        sm[i][pl] = v;
    }
    __syncthreads();
    int oc = tid & 127;
    int lb = (tid >> 7) * 8;
    float bias = cb1[oc];
    float acc[8];
    #pragma unroll
    for (int j = 0; j < 8; ++j) acc[j] = bias;
    for (int i = 0; i < DIN; ++i) {
        float zr[14];
        #pragma unroll
        for (int q = 0; q < 14; ++q) zr[q] = sm[i][lb + q];
        #pragma unroll
        for (int tap = 0; tap < 7; ++tap) {
            float k = K1[(size_t)(tap * DIN + i) * 128 + oc];
            #pragma unroll
            for (int j = 0; j < 8; ++j) acc[j] = fmaf(zr[tap + j], k, acc[j]);
        }
    }
    #pragma unroll
    for (int j = 0; j < 8; ++j) {
        int l = l0 + lb + j;
        if (l < L_LEN) g1[((size_t)b * L_LEN + l) * 128 + oc] = fmaxf(acc[j], 0.f);
    }
}

__global__ void conv2_mono_kernel(const float* __restrict__ g1,
                                  const float* __restrict__ K2, const float* __restrict__ cb2,
                                  float* __restrict__ g2) {
    int b  = blockIdx.x >> 4;
    int lt = blockIdx.x & 15;
    int l0 = lt * 16;
    int tid = threadIdx.x;
    __shared__ float sm[128][20];
    for (int idx = tid; idx < 20 * 128; idx += 256) {
        int pl = idx >> 7;
        int i  = idx & 127;
        int p  = l0 - 2 + pl;
        float v = (p >= 0 && p < L_LEN) ? g1[((size_t)b * L_LEN + p) * 128 + i] : 0.f;
        sm[i][pl] = v;
    }
    __syncthreads();
    int oc = tid & 63;
    int lb = (tid >> 6) * 4;
    float bias = cb2[oc];
    float acc[4];
    #pragma unroll
    for (int j = 0; j < 4; ++j) acc[j] = bias;
    for (int i = 0; i < 128; ++i) {
        float zr[8];
        #pragma unroll
        for (int q = 0; q < 8; ++q) zr[q] = sm[i][lb + q];
        #pragma unroll
        for (int tap = 0; tap < 5; ++tap) {
            float k = K2[(size_t)(tap * 128 + i) * 64 + oc];
            #pragma unroll
            for (int j = 0; j < 4; ++j) acc[j] = fmaf(zr[tap + j], k, acc[j]);
        }
    }
    #pragma unroll
    for (int j = 0; j < 4; ++j) {
        int l = l0 + lb + j;
        if (l < L_LEN) g2[((size_t)b * L_LEN + l) * 64 + oc] = fmaxf(acc[j], 0.f);
    }
}

__global__ void conv3_mono_kernel(const float* __restrict__ g2,
                                  const float* __restrict__ K3, const float* __restrict__ cb3,
                                  float* __restrict__ g3) {
    int b  = blockIdx.x >> 4;
    int lt = blockIdx.x & 15;
    int l0 = lt * 16;
    int tid = threadIdx.x;
    int v  = tid & 15;
    int ll = tid >> 4;
    int l  = l0 + ll;
    if (l >= L_LEN) return;
    float acc = cb3[v];
    #pragma unroll
    for (int tap = 0; tap < 3; ++tap) {
        int p = l + tap - 1;
        if (p < 0 || p >= L_LEN) continue;
        const float* gp = g2 + ((size_t)b * L_LEN + p) * 64;
        #pragma unroll
        for (int i = 0; i < 64; ++i) acc = fmaf(gp[i], K3[(size_t)(tap * 64 + i) * 16 + v], acc);
    }
    g3[((size_t)b * L_LEN + l) * 16 + v] = acc;
}

__global__ __launch_bounds__(256) void main_mono_kernel(
        const float* __restrict__ base, const float* __restrict__ g3,
        const float* __restrict__ P, float* __restrict__ out) {
    int b = blockIdx.x / CB;
    int c = blockIdx.x % CB;
    int t = c * 256 + threadIdx.x;
    __shared__ float Pb[34];
    if (threadIdx.x < 34) Pb[threadIdx.x] = P[b * 40 + threadIdx.x];
    __syncthreads();
    if (t >= T_LEN) return;
    float depth = Pb[0];
    float coef  = Pb[1];
    const float scale = 250.0f / 62400.0f;
    float src = ((float)t + 0.5f) * scale - 0.5f;
    src = fminf(fmaxf(src, 0.0f), 249.0f);
    float fi0 = floorf(src);
    int i0 = (int)fi0;
    int i1 = min(i0 + 1, L_LEN - 1);
    float frac = src - fi0;
    const float4* r0 = (const float4*)(g3 + ((size_t)b * L_LEN + i0) * NV);
    const float4* r1 = (const float4*)(g3 + ((size_t)b * L_LEN + i1) * NV);
    float vg[16];
    #pragma unroll
    for (int q = 0; q < 4; ++q) {
        float4 a = r0[q];
        float4 d = r1[q];
        vg[q * 4 + 0] = fmaf(d.x - a.x, frac, a.x);
        vg[q * 4 + 1] = fmaf(d.y - a.y, frac, a.y);
        vg[q * 4 + 2] = fmaf(d.z - a.z, frac, a.z);
        vg[q * 4 + 3] = fmaf(d.w - a.w, frac, a.w);
    }
    float tsec = (float)t * (1.0f / 48000.0f);
    const float* bs = base + (size_t)b * T_LEN;
    const int shifts[NV] = {-9,-8,-6,-5,-4,-3,-1,0,0,1,3,4,5,6,8,9};
    float gain_sum = 0.f, uni = 0.f;
    #pragma unroll
    for (int v = 0; v < NV; ++v) {
        float x = vg[v];
        float sp = fmaxf(x, 0.f) + __logf(1.0f + __expf(-fabsf(x)));
        float fv = 3.0f + 0.3f * (float)v;
        float ph = fv * tsec;
        ph -= floorf(ph);
        float lfo = __builtin_amdgcn_sinf(ph);
        int tb = t - shifts[v];
        if (tb < 0) tb += T_LEN; else if (tb >= T_LEN) tb -= T_LEN;
        float mod = bs[tb] * fmaf(0.2f * depth, lfo, 1.0f);
        gain_sum = fmaf(sp, Pb[2 + v], gain_sum);
        uni      = fmaf(mod * sp, Pb[2 + NV + v], uni);
    }
    out[(size_t)b * T_LEN + t] = gain_sum * coef * uni;
}

extern "C" void kernel_launch(void* const* d_in, const int* in_sizes, int n_in,
                              void* d_out, int out_size, void* d_ws, size_t ws_size,
                              hipStream_t stream) {
    const float* base = (const float*)d_in[0];
    const float* z    = (const float*)d_in[1];
    const float* cond = (const float*)d_in[2];
    const float* W1 = (const float*)d_in[4];  const float* b1 = (const float*)d_in[5];
    const float* W2 = (const float*)d_in[6];  const float* b2 = (const float*)d_in[7];
    const float* W3 = (const float*)d_in[8];  const float* b3 = (const float*)d_in[9];
    const float* W4 = (const float*)d_in[10]; const float* b4 = (const float*)d_in[11];
    const float* K1 = (const float*)d_in[12]; const float* cb1 = (const float*)d_in[13];
    const float* K2 = (const float*)d_in[14]; const float* cb2 = (const float*)d_in[15];
    const float* K3 = (const float*)d_in[16]; const float* cb3 = (const float*)d_in[17];
    float* out = (float*)d_out;

    int B = in_sizes[0] / T_LEN;   // 16

    float* ws = (float*)d_ws;
    const size_t XBF  = NXB / 2;                  // 348160 floats
    const size_t K1F  = NK1 / 2;                  // 71680
    const size_t K2F  = NK2 / 2;                  // 20480
    const size_t G1BF = (size_t)16 * XR2 * 128 / 2;  // 262144
    const size_t G2   = (size_t)16 * L_LEN * 64;     // 256000
    size_t need = (1024 + XBF + K1F + K2F + G1BF + G2) * sizeof(float);  // ~3.8 MB

    float* P = ws;
    if (ws_size >= need) {
        __hip_bfloat16* Xb  = (__hip_bfloat16*)(ws + 1024);
        __hip_bfloat16* K1t = (__hip_bfloat16*)(ws + 1024 + XBF);
        __hip_bfloat16* K2t = (__hip_bfloat16*)(ws + 1024 + XBF + K1F);
        __hip_bfloat16* g1b = (__hip_bfloat16*)(ws + 1024 + XBF + K1F + K2F);
        float* g2 = ws + 1024 + XBF + K1F + K2F + G1BF;

        int prep_blocks = (NXB + NK1 + NK2 + NPAD + 255) / 256;
        prep_kernel<<<prep_blocks, 256, 0, stream>>>(z, cond, K1, K2, Xb, K1t, K2t, g1b);
        conv1_mfma_mlp_kernel<<<16 + 256, 256, 0, stream>>>(
            (const short*)Xb, (const short*)K1t, cb1, g1b, z, cond,
            W1, b1, W2, b2, W3, b3, W4, b4, P);
        conv2_mfma_kernel<<<256, 256, 0, stream>>>(
            (const short*)g1b, (const short*)K2t, g2);
        conv3_main_kernel<<<B * CB, 256, 0, stream>>>(base, g2, cb2, K3, cb3, P, out);
    } else {
        float* g1 = ws + 1024;
        float* g2 = g1 + (size_t)B * L_LEN * 128;
        float* g3 = g2 + (size_t)B * L_LEN * 64;
        params_kernel<<<B, 256, 0, stream>>>(z, cond, W1, b1, W2, b2, W3, b3, W4, b4, P);
        conv1_mono_kernel<<<B * 16, 256, 0, stream>>>(z, cond, K1, cb1, g1);
        conv2_mono_kernel<<<B * 16, 256, 0, stream>>>(g1, K2, cb2, g2);
        conv3_mono_kernel<<<B * 16, 256, 0, stream>>>(g2, K3, cb3, g3);
        main_mono_kernel<<<B * CB, 256, 0, stream>>>(base, g3, P, out);
    }
}

// Round 13
// 58.176 us; speedup vs baseline: 1.4356x; 1.0119x over previous
//
#include <hip/hip_runtime.h>
#include <hip/hip_bf16.h>
#include <math.h>

#define L_LEN 250
#define D_DIM 128
#define C_DIM 32
#define DIN   160
#define NV    16
#define T_LEN 62400
#define CB    244              // ceil(62400/256)
#define XROWS 272              // conv1 input pad rows: r = l+3
#define XR2   256              // g1b pad rows: r = l+2, l in [-2,253]
#define NXB   (16 * XROWS * 160)   // Xb elements (bf16)
#define NK1   (128 * 1120)         // K1t elements (bf16)
#define NK2   (64 * 640)           // K2t elements (bf16)
#define NPAD  (16 * 6 * 128)       // g1b pad-row elements to zero

typedef short short8 __attribute__((ext_vector_type(8)));
typedef float f32x4  __attribute__((ext_vector_type(4)));

// ------- kernel 0: bf16 padded input + transposed weights + g1b pad-zero ----
__global__ __launch_bounds__(256) void prep_kernel(
        const float* __restrict__ z, const float* __restrict__ cond,
        const float* __restrict__ K1, const float* __restrict__ K2,
        __hip_bfloat16* __restrict__ Xb, __hip_bfloat16* __restrict__ K1t,
        __hip_bfloat16* __restrict__ K2t, __hip_bfloat16* __restrict__ g1b) {
    int idx = blockIdx.x * 256 + threadIdx.x;
    if (idx < NXB) {
        int b   = idx / (XROWS * 160);
        int rem = idx - b * (XROWS * 160);
        int r   = rem / 160;
        int ic  = rem - r * 160;
        int l   = r - 3;
        float v = 0.f;
        if (l >= 0 && l < L_LEN)
            v = (ic < D_DIM) ? z[((size_t)b * L_LEN + l) * D_DIM + ic]
                             : cond[b * C_DIM + (ic - D_DIM)];
        Xb[idx] = __float2bfloat16(v);
    } else if (idx < NXB + NK1) {
        int j  = idx - NXB;
        int oc = j / 1120;
        int k  = j - oc * 1120;
        K1t[j] = __float2bfloat16(K1[(size_t)k * 128 + oc]);
    } else if (idx < NXB + NK1 + NK2) {
        int j  = idx - NXB - NK1;
        int oc = j / 640;
        int k  = j - oc * 640;
        K2t[j] = __float2bfloat16(K2[(size_t)k * 64 + oc]);
    } else if (idx < NXB + NK1 + NK2 + NPAD) {
        int j  = idx - NXB - NK1 - NK2;
        int b  = j / (6 * 128);
        int rem = j - b * (6 * 128);
        int rr = rem >> 7;
        int ic = rem & 127;
        int r  = (rr < 2) ? rr : 250 + rr;   // rows 0,1,252,253,254,255
        g1b[((size_t)b * XR2 + r) * 128 + ic] = __float2bfloat16(0.f);
    }
}

// ------- kernel A: blocks 0..15 = K-parallel MLP ; 16..271 = conv1 MFMA -----
// MLP layers use 8 accumulators + unroll 2 => 16 loads in flight per wait.
// conv1 wave: C[16 l][32 oc], K=1120; epilogue g1b = bf16(relu(acc+cb1)).
// P layout (40): [0]=depth,[1]=coef,[2..17]=mask,[18..33]=pan
__global__ __launch_bounds__(256) void conv1_mfma_mlp_kernel(
        const short* __restrict__ Xb, const short* __restrict__ K1t,
        const float* __restrict__ cb1, __hip_bfloat16* __restrict__ g1b,
        const float* __restrict__ z, const float* __restrict__ cond,
        const float* __restrict__ W1, const float* __restrict__ b1,
        const float* __restrict__ W2, const float* __restrict__ b2,
        const float* __restrict__ W3, const float* __restrict__ b3,
        const float* __restrict__ W4, const float* __restrict__ b4,
        float* __restrict__ P) {
    int tid = threadIdx.x;
    if (blockIdx.x < 16) {
        // ---------- K-parallel MLP (hides under conv1) ----------
        int b = blockIdx.x;
        __shared__ float buf[2176];
        float* xb = buf;
        float* h1 = buf + 160;
        float* h2 = buf + 416;
        float* h3 = buf + 544;
        float* pr = buf + 608;
        float* red = buf + 640;
        float4* sm4 = (float4*)(buf + 1152);
        {
            int c4 = tid & 31, rg = tid >> 5;
            const float4* zp = (const float4*)(z + (size_t)b * L_LEN * D_DIM) + c4;
            float4 acc = make_float4(0.f, 0.f, 0.f, 0.f);
            for (int r = rg; r < L_LEN; r += 8) {
                float4 v = zp[(size_t)r * 32];
                acc.x += v.x; acc.y += v.y; acc.z += v.z; acc.w += v.w;
            }
            sm4[rg * 32 + c4] = acc;
        }
        __syncthreads();
        if (tid < 32) {
            float4 acc = sm4[tid];
            #pragma unroll
            for (int g = 1; g < 8; ++g) {
                float4 v = sm4[g * 32 + tid];
                acc.x += v.x; acc.y += v.y; acc.z += v.z; acc.w += v.w;
            }
            const float inv = 1.0f / (float)L_LEN;
            acc.x *= inv; acc.y *= inv; acc.z *= inv; acc.w *= inv;
            ((float4*)xb)[tid] = acc;
        } else if (tid >= 128 && tid < DIN) {
            xb[tid] = cond[b * C_DIM + (tid - 128)];
        }
        __syncthreads();
        {   // L1: 160 -> 256 ; 8 accs, unroll 2 => 16 loads in flight
            const float* w = W1 + tid;
            float a0 = b1[tid], a1 = 0.f, a2 = 0.f, a3 = 0.f;
            float a4 = 0.f, a5 = 0.f, a6 = 0.f, a7 = 0.f;
            #pragma unroll 2
            for (int i = 0; i < DIN; i += 8) {
                a0 = fmaf(xb[i],     w[(size_t)(i)     * 256], a0);
                a1 = fmaf(xb[i + 1], w[(size_t)(i + 1) * 256], a1);
                a2 = fmaf(xb[i + 2], w[(size_t)(i + 2) * 256], a2);
                a3 = fmaf(xb[i + 3], w[(size_t)(i + 3) * 256], a3);
                a4 = fmaf(xb[i + 4], w[(size_t)(i + 4) * 256], a4);
                a5 = fmaf(xb[i + 5], w[(size_t)(i + 5) * 256], a5);
                a6 = fmaf(xb[i + 6], w[(size_t)(i + 6) * 256], a6);
                a7 = fmaf(xb[i + 7], w[(size_t)(i + 7) * 256], a7);
            }
            h1[tid] = fmaxf(((a0 + a1) + (a2 + a3)) + ((a4 + a5) + (a6 + a7)), 0.f);
        }
        __syncthreads();
        {   // L2: 256 -> 128 ; 2 k-halves of 128 ; 8 accs, unroll 2
            int oc = tid & 127, hh = tid >> 7;
            const float* w = W2 + (size_t)(hh * 128) * 128 + oc;
            const float* x = h1 + hh * 128;
            float a0 = 0.f, a1 = 0.f, a2 = 0.f, a3 = 0.f;
            float a4 = 0.f, a5 = 0.f, a6 = 0.f, a7 = 0.f;
            #pragma unroll 2
            for (int i = 0; i < 128; i += 8) {
                a0 = fmaf(x[i],     w[(size_t)(i)     * 128], a0);
                a1 = fmaf(x[i + 1], w[(size_t)(i + 1) * 128], a1);
                a2 = fmaf(x[i + 2], w[(size_t)(i + 2) * 128], a2);
                a3 = fmaf(x[i + 3], w[(size_t)(i + 3) * 128], a3);
                a4 = fmaf(x[i + 4], w[(size_t)(i + 4) * 128], a4);
                a5 = fmaf(x[i + 5], w[(size_t)(i + 5) * 128], a5);
                a6 = fmaf(x[i + 6], w[(size_t)(i + 6) * 128], a6);
                a7 = fmaf(x[i + 7], w[(size_t)(i + 7) * 128], a7);
            }
            red[tid] = ((a0 + a1) + (a2 + a3)) + ((a4 + a5) + (a6 + a7));
        }
        __syncthreads();
        if (tid < 128) h2[tid] = fmaxf(red[tid] + red[tid + 128] + b2[tid], 0.f);
        __syncthreads();
        {   // L3: 128 -> 64 ; 4 k-groups of 32 ; 8 accs, unroll 2
            int oc = tid & 63, qg = tid >> 6;
            const float* w = W3 + (size_t)(qg * 32) * 64 + oc;
            const float* x = h2 + qg * 32;
            float a0 = 0.f, a1 = 0.f, a2 = 0.f, a3 = 0.f;
            float a4 = 0.f, a5 = 0.f, a6 = 0.f, a7 = 0.f;
            #pragma unroll 2
            for (int i = 0; i < 32; i += 8) {
                a0 = fmaf(x[i],     w[(size_t)(i)     * 64], a0);
                a1 = fmaf(x[i + 1], w[(size_t)(i + 1) * 64], a1);
                a2 = fmaf(x[i + 2], w[(size_t)(i + 2) * 64], a2);
                a3 = fmaf(x[i + 3], w[(size_t)(i + 3) * 64], a3);
                a4 = fmaf(x[i + 4], w[(size_t)(i + 4) * 64], a4);
                a5 = fmaf(x[i + 5], w[(size_t)(i + 5) * 64], a5);
                a6 = fmaf(x[i + 6], w[(size_t)(i + 6) * 64], a6);
                a7 = fmaf(x[i + 7], w[(size_t)(i + 7) * 64], a7);
            }
            red[tid] = ((a0 + a1) + (a2 + a3)) + ((a4 + a5) + (a6 + a7));
        }
        __syncthreads();
        if (tid < 64)
            h3[tid] = fmaxf(red[tid] + red[tid + 64] + red[tid + 128] + red[tid + 192] + b3[tid], 0.f);
        __syncthreads();
        red[tid] = h3[tid >> 2] * W4[(tid >> 2) * 4 + (tid & 3)];
        __syncthreads();
        if (tid < 4) {
            float s = b4[tid];
            for (int k = 0; k < 64; ++k) s += red[k * 4 + tid];
            pr[tid] = s;
        }
        __syncthreads();
        if (tid == 0) {
            float num_voices = 1.0f + 14.0f / (1.0f + __expf(-pr[0]));
            float spread     = 1.0f / (1.0f + __expf(-pr[2]));
            float depth      = 0.5f / (1.0f + __expf(-pr[3]));
            float* Pb = P + b * 40;
            float msum = 0.f;
            for (int v = 0; v < NV; ++v) {
                float m = 1.0f / (1.0f + __expf(-(num_voices - (float)v) * 2.0f));
                msum += m;
                Pb[2 + v] = m;
                float pos = ((float)v - 7.5f) * (1.0f / 16.0f);
                Pb[2 + NV + v] = 1.0f - fabsf(pos) * spread * 0.5f;
            }
            float norm = sqrtf(msum + 1e-6f);
            Pb[0] = depth;
            Pb[1] = 1.0f / (norm + 1e-6f);
        }
        return;
    }
    // ---------------- conv1 MFMA path (verified layout, R11) ----------------
    int blk = blockIdx.x - 16;
    int b   = blk >> 4;
    int lt  = blk & 15;
    int l0  = lt * 16;
    int lane = tid & 63;
    int oc0g = (tid >> 6) * 32;
    int m  = lane & 15;
    int kg = lane >> 4;

    const short* Ab = Xb + ((size_t)(b * XROWS + l0 + m) * 160 + kg * 8);
    const short* Bb = K1t + ((size_t)(oc0g + m) * 1120 + kg * 8);

    f32x4 acc0 = {0.f, 0.f, 0.f, 0.f};
    f32x4 acc1 = {0.f, 0.f, 0.f, 0.f};
    #pragma unroll 1
    for (int tap = 0; tap < 7; ++tap) {
        const short* ap = Ab + tap * 160;
        const short* bp = Bb + tap * 160;
        #pragma unroll
        for (int ks = 0; ks < 5; ++ks) {
            short8 av  = *(const short8*)(ap + ks * 32);
            short8 bv0 = *(const short8*)(bp + ks * 32);
            short8 bv1 = *(const short8*)(bp + 16 * 1120 + ks * 32);
            acc0 = __builtin_amdgcn_mfma_f32_16x16x32_bf16(av, bv0, acc0, 0, 0, 0);
            acc1 = __builtin_amdgcn_mfma_f32_16x16x32_bf16(av, bv1, acc1, 0, 0, 0);
        }
    }
    float bias0 = cb1[oc0g + m];
    float bias1 = cb1[oc0g + m + 16];
    int rbase = l0 + kg * 4;
    #pragma unroll
    for (int j = 0; j < 4; ++j) {
        int lr = rbase + j;
        if (lr < L_LEN) {
            __hip_bfloat16* gp = g1b + ((size_t)(b * XR2) + lr + 2) * 128 + oc0g + m;
            gp[0]  = __float2bfloat16(fmaxf(acc0[j] + bias0, 0.f));
            gp[16] = __float2bfloat16(fmaxf(acc1[j] + bias1, 0.f));
        }
    }
}

// ------- kernel B: conv2 MFMA. 16b x 16lt = 256 blocks; wave = 16l x 16oc ---
__global__ __launch_bounds__(256) void conv2_mfma_kernel(
        const short* __restrict__ g1b, const short* __restrict__ K2t,
        float* __restrict__ g2) {
    int tid = threadIdx.x;
    int b   = blockIdx.x >> 4;
    int lt  = blockIdx.x & 15;
    int l0  = lt * 16;
    int lane = tid & 63;
    int oc0w = (tid >> 6) * 16;
    int m  = lane & 15;
    int kg = lane >> 4;

    const short* Ab = g1b + ((size_t)(b * XR2 + l0 + m) * 128 + kg * 8);
    const short* Bb = K2t + ((size_t)(oc0w + m) * 640 + kg * 8);

    f32x4 acc = {0.f, 0.f, 0.f, 0.f};
    #pragma unroll 1
    for (int tap = 0; tap < 5; ++tap) {
        const short* ap = Ab + tap * 128;
        const short* bp = Bb + tap * 128;
        #pragma unroll
        for (int ks = 0; ks < 4; ++ks) {
            short8 av = *(const short8*)(ap + ks * 32);
            short8 bv = *(const short8*)(bp + ks * 32);
            acc = __builtin_amdgcn_mfma_f32_16x16x32_bf16(av, bv, acc, 0, 0, 0);
        }
    }
    int rbase = l0 + kg * 4;
    #pragma unroll
    for (int j = 0; j < 4; ++j) {
        int l = rbase + j;
        if (l < L_LEN)
            g2[((size_t)b * L_LEN + l) * 64 + oc0w + m] = acc[j];
    }
}

// ------- kernel C: fused conv3 + upsample + softplus + unison mix ----------
// Adds LDS-staged base window: bs[t0-9 .. t0+255+9] -> sbase[274]
__global__ __launch_bounds__(256) void conv3_main_kernel(
        const float* __restrict__ base, const float* __restrict__ g2,
        const float* __restrict__ cb2,
        const float* __restrict__ K3, const float* __restrict__ cb3,
        const float* __restrict__ P, float* __restrict__ out) {
    int b = blockIdx.x / CB;
    int c = blockIdx.x % CB;
    int t0 = c * 256;
    int tid = threadIdx.x;
    const float scale = 250.0f / 62400.0f;

    __shared__ float k3t[16][196];
    __shared__ float sA[6][68];
    __shared__ float g3loc[4][17];
    __shared__ float Pb[34];
    __shared__ float sbase[276];

    float src0 = ((float)t0 + 0.5f) * scale - 0.5f;
    src0 = fminf(fmaxf(src0, 0.0f), 249.0f);
    int L0 = (int)floorf(src0);

    const float* bs = base + (size_t)b * T_LEN;
    if (tid < 34) Pb[tid] = P[b * 40 + tid];
    for (int idx = tid; idx < 274; idx += 256) {
        int tt = t0 - 9 + idx;
        if (tt < 0) tt += T_LEN; else if (tt >= T_LEN) tt -= T_LEN;
        sbase[idx] = bs[tt];
    }
    for (int idx = tid; idx < 3 * 64 * 16; idx += 256) {
        int v  = idx & 15;
        int ti = idx >> 4;
        k3t[v][ti] = K3[ti * 16 + v];
    }
    for (int idx = tid; idx < 6 * 64; idx += 256) {
        int pl = idx >> 6;
        int i  = idx & 63;
        int p  = L0 - 1 + pl;
        float v = 0.f;
        if (p >= 0 && p < L_LEN)
            v = fmaxf(cb2[i] + g2[((size_t)b * L_LEN + p) * 64 + i], 0.f);
        sA[pl][i] = v;
    }
    __syncthreads();

    {   // conv3: 4 rows x 16 v x 4 ic-segments; quad shuffle-reduce
        int seg = tid & 3;
        int v   = (tid >> 2) & 15;
        int r   = tid >> 6;
        float acc = 0.f;
        #pragma unroll
        for (int tap = 0; tap < 3; ++tap) {
            const float* gr = &sA[r + tap][seg * 16];
            const float* kr = &k3t[v][tap * 64 + seg * 16];
            #pragma unroll
            for (int j = 0; j < 4; ++j) {
                float4 g = *(const float4*)&gr[j * 4];
                float4 k = *(const float4*)&kr[j * 4];
                acc = fmaf(g.x, k.x, acc);
                acc = fmaf(g.y, k.y, acc);
                acc = fmaf(g.z, k.z, acc);
                acc = fmaf(g.w, k.w, acc);
            }
        }
        acc += __shfl_xor(acc, 1);
        acc += __shfl_xor(acc, 2);
        if (seg == 0) g3loc[r][v] = acc + cb3[v];
    }
    __syncthreads();

    int t = t0 + tid;
    if (t >= T_LEN) return;
    float depth = Pb[0];
    float coef  = Pb[1];
    float src = ((float)t + 0.5f) * scale - 0.5f;
    src = fminf(fmaxf(src, 0.0f), 249.0f);
    float fi0 = floorf(src);
    int i0 = (int)fi0;
    int i1 = min(i0 + 1, L_LEN - 1);
    float frac = src - fi0;
    int r0 = i0 - L0;
    int r1 = i1 - L0;
    float vg[16];
    #pragma unroll
    for (int v = 0; v < NV; ++v) {
        float a = g3loc[r0][v];
        float d = g3loc[r1][v];
        vg[v] = fmaf(d - a, frac, a);
    }
    float tsec = (float)t * (1.0f / 48000.0f);
    const int shifts[NV] = {-9,-8,-6,-5,-4,-3,-1,0,0,1,3,4,5,6,8,9};
    float gain_sum = 0.f, uni = 0.f;
    #pragma unroll
    for (int v = 0; v < NV; ++v) {
        float x = vg[v];
        float sp = fmaxf(x, 0.f) + __logf(1.0f + __expf(-fabsf(x)));   // softplus
        float fv = 3.0f + 0.3f * (float)v;
        float ph = fv * tsec;
        ph -= floorf(ph);
        float lfo = __builtin_amdgcn_sinf(ph);  // v_sin_f32: revolutions
        float mod = sbase[tid + 9 - shifts[v]] * fmaf(0.2f * depth, lfo, 1.0f);
        gain_sum = fmaf(sp, Pb[2 + v], gain_sum);
        uni      = fmaf(mod * sp, Pb[2 + NV + v], uni);
    }
    out[(size_t)b * T_LEN + t] = gain_sum * coef * uni;
}

// ================= fallback (round-1 monolithic) kernels ====================
__global__ void params_kernel(const float* __restrict__ z, const float* __restrict__ cond,
                              const float* __restrict__ W1, const float* __restrict__ b1,
                              const float* __restrict__ W2, const float* __restrict__ b2,
                              const float* __restrict__ W3, const float* __restrict__ b3,
                              const float* __restrict__ W4, const float* __restrict__ b4,
                              float* __restrict__ P) {
    int b = blockIdx.x;
    int tid = threadIdx.x;
    __shared__ float xb[DIN];
    __shared__ float zp2[128];
    __shared__ float h1[256];
    __shared__ float h2[128];
    __shared__ float h3[64];
    __shared__ float pr[4];
    {
        int i = tid & 127, half = tid >> 7;
        const float* zp = z + (size_t)b * L_LEN * D_DIM + i;
        float s = 0.f;
        for (int l = half; l < L_LEN; l += 2) s += zp[(size_t)l * D_DIM];
        if (half) zp2[i] = s;
        __syncthreads();
        if (!half) xb[i] = (s + zp2[i]) * (1.0f / (float)L_LEN);
        if (tid >= 128 && tid < DIN) xb[tid] = cond[b * C_DIM + (tid - 128)];
    }
    __syncthreads();
    {
        float acc = b1[tid];
        for (int i = 0; i < DIN; ++i) acc = fmaf(xb[i], W1[i * 256 + tid], acc);
        h1[tid] = fmaxf(acc, 0.f);
    }
    __syncthreads();
    if (tid < 128) {
        float acc = b2[tid];
        for (int i = 0; i < 256; ++i) acc = fmaf(h1[i], W2[i * 128 + tid], acc);
        h2[tid] = fmaxf(acc, 0.f);
    }
    __syncthreads();
    if (tid < 64) {
        float acc = b3[tid];
        for (int i = 0; i < 128; ++i) acc = fmaf(h2[i], W3[i * 64 + tid], acc);
        h3[tid] = fmaxf(acc, 0.f);
    }
    __syncthreads();
    if (tid < 4) {
        float acc = b4[tid];
        for (int i = 0; i < 64; ++i) acc = fmaf(h3[i], W4[i * 4 + tid], acc);
        pr[tid] = acc;
    }
    __syncthreads();
    if (tid == 0) {
        float num_voices = 1.0f + 14.0f / (1.0f + __expf(-pr[0]));
        float spread     = 1.0f / (1.0f + __expf(-pr[2]));
        float depth      = 0.5f / (1.0f + __expf(-pr[3]));
        float* Pb = P + b * 40;
        float msum = 0.f;
        for (int v = 0; v < NV; ++v) {
            float m = 1.0f / (1.0f + __expf(-(num_voices - (float)v) * 2.0f));
            msum += m;
            Pb[2 + v] = m;
            float pos = ((float)v - 7.5f) * (1.0f / 16.0f);
            Pb[2 + NV + v] = 1.0f - fabsf(pos) * spread * 0.5f;
        }
        float norm = sqrtf(msum + 1e-6f);
        Pb[0] = depth;
        Pb[1] = 1.0f / (norm + 1e-6f);
    }
}

__global__ void conv1_mono_kernel(const float* __restrict__ z, const float* __restrict__ cond,
                                  const float* __restrict__ K1, const float* __restrict__ cb1,
                                  float* __restrict__ g1) {
    int b  = blockIdx.x >> 4;
    int lt = blockIdx.x & 15;
    int l0 = lt * 16;
    int tid = threadIdx.x;
    __shared__ float sm[DIN][22];
    for (int idx = tid; idx < 22 * DIN; idx += 256) {
        int pl = idx / DIN;
        int i  = idx - pl * DIN;
        int p  = l0 - 3 + pl;
        float v = 0.f;
        if (p >= 0 && p < L_LEN)
            v = (i < D_DIM) ? z[((size_t)b * L_LEN + p) * D_DIM + i]
                            : cond[b * C_DIM + (i - D_DIM)];
        sm[i][pl] = v;
    }
    __syncthreads();
    int oc = tid & 127;
    int lb = (tid >> 7) * 8;
    float bias = cb1[oc];
    float acc[8];
    #pragma unroll
    for (int j = 0; j < 8; ++j) acc[j] = bias;
    for (int i = 0; i < DIN; ++i) {
        float zr[14];
        #pragma unroll
        for (int q = 0; q < 14; ++q) zr[q] = sm[i][lb + q];
        #pragma unroll
        for (int tap = 0; tap < 7; ++tap) {
            float k = K1[(size_t)(tap * DIN + i) * 128 + oc];
            #pragma unroll
            for (int j = 0; j < 8; ++j) acc[j] = fmaf(zr[tap + j], k, acc[j]);
        }
    }
    #pragma unroll
    for (int j = 0; j < 8; ++j) {
        int l = l0 + lb + j;
        if (l < L_LEN) g1[((size_t)b * L_LEN + l) * 128 + oc] = fmaxf(acc[j], 0.f);
    }
}

__global__ void conv2_mono_kernel(const float* __restrict__ g1,
                                  const float* __restrict__ K2, const float* __restrict__ cb2,
                                  float* __restrict__ g2) {
    int b  = blockIdx.x >> 4;
    int lt = blockIdx.x & 15;
    int l0 = lt * 16;
    int tid = threadIdx.x;
    __shared__ float sm[128][20];
    for (int idx = tid; idx < 20 * 128; idx += 256) {
        int pl = idx >> 7;
        int i  = idx & 127;
        int p  = l0 - 2 + pl;
        float v = (p >= 0 && p < L_LEN) ? g1[((size_t)b * L_LEN + p) * 128 + i] : 0.f;
        sm[i][pl] = v;
    }
    __syncthreads();
    int oc = tid & 63;
    int lb = (tid >> 6) * 4;
    float bias = cb2[oc];
    float acc[4];
    #pragma unroll
    for (int j = 0; j < 4; ++j) acc[j] = bias;
    for (int i = 0; i < 128; ++i) {
        float zr[8];
        #pragma unroll
        for (int q = 0; q < 8; ++q) zr[q] = sm[i][lb + q];
        #pragma unroll
        for (int tap = 0; tap < 5; ++tap) {
            float k = K2[(size_t)(tap * 128 + i) * 64 + oc];
            #pragma unroll
            for (int j = 0; j < 4; ++j) acc[j] = fmaf(zr[tap + j], k, acc[j]);
        }
    }
    #pragma unroll
    for (int j = 0; j < 4; ++j) {
        int l = l0 + lb + j;
        if (l < L_LEN) g2[((size_t)b * L_LEN + l) * 64 + oc] = fmaxf(acc[j], 0.f);
    }
}

__global__ void conv3_mono_kernel(const float* __restrict__ g2,
                                  const float* __restrict__ K3, const float* __restrict__ cb3,
                                  float* __restrict__ g3) {
    int b  = blockIdx.x >> 4;
    int lt = blockIdx.x & 15;
    int l0 = lt * 16;
    int tid = threadIdx.x;
    int v  = tid & 15;
    int ll = tid >> 4;
    int l  = l0 + ll;
    if (l >= L_LEN) return;
    float acc = cb3[v];
    #pragma unroll
    for (int tap = 0; tap < 3; ++tap) {
        int p = l + tap - 1;
        if (p < 0 || p >= L_LEN) continue;
        const float* gp = g2 + ((size_t)b * L_LEN + p) * 64;
        #pragma unroll
        for (int i = 0; i < 64; ++i) acc = fmaf(gp[i], K3[(size_t)(tap * 64 + i) * 16 + v], acc);
    }
    g3[((size_t)b * L_LEN + l) * 16 + v] = acc;
}

__global__ __launch_bounds__(256) void main_mono_kernel(
        const float* __restrict__ base, const float* __restrict__ g3,
        const float* __restrict__ P, float* __restrict__ out) {
    int b = blockIdx.x / CB;
    int c = blockIdx.x % CB;
    int t = c * 256 + threadIdx.x;
    __shared__ float Pb[34];
    if (threadIdx.x < 34) Pb[threadIdx.x] = P[b * 40 + threadIdx.x];
    __syncthreads();
    if (t >= T_LEN) return;
    float depth = Pb[0];
    float coef  = Pb[1];
    const float scale = 250.0f / 62400.0f;
    float src = ((float)t + 0.5f) * scale - 0.5f;
    src = fminf(fmaxf(src, 0.0f), 249.0f);
    float fi0 = floorf(src);
    int i0 = (int)fi0;
    int i1 = min(i0 + 1, L_LEN - 1);
    float frac = src - fi0;
    const float4* r0 = (const float4*)(g3 + ((size_t)b * L_LEN + i0) * NV);
    const float4* r1 = (const float4*)(g3 + ((size_t)b * L_LEN + i1) * NV);
    float vg[16];
    #pragma unroll
    for (int q = 0; q < 4; ++q) {
        float4 a = r0[q];
        float4 d = r1[q];
        vg[q * 4 + 0] = fmaf(d.x - a.x, frac, a.x);
        vg[q * 4 + 1] = fmaf(d.y - a.y, frac, a.y);
        vg[q * 4 + 2] = fmaf(d.z - a.z, frac, a.z);
        vg[q * 4 + 3] = fmaf(d.w - a.w, frac, a.w);
    }
    float tsec = (float)t * (1.0f / 48000.0f);
    const float* bs = base + (size_t)b * T_LEN;
    const int shifts[NV] = {-9,-8,-6,-5,-4,-3,-1,0,0,1,3,4,5,6,8,9};
    float gain_sum = 0.f, uni = 0.f;
    #pragma unroll
    for (int v = 0; v < NV; ++v) {
        float x = vg[v];
        float sp = fmaxf(x, 0.f) + __logf(1.0f + __expf(-fabsf(x)));
        float fv = 3.0f + 0.3f * (float)v;
        float ph = fv * tsec;
        ph -= floorf(ph);
        float lfo = __builtin_amdgcn_sinf(ph);
        int tb = t - shifts[v];
        if (tb < 0) tb += T_LEN; else if (tb >= T_LEN) tb -= T_LEN;
        float mod = bs[tb] * fmaf(0.2f * depth, lfo, 1.0f);
        gain_sum = fmaf(sp, Pb[2 + v], gain_sum);
        uni      = fmaf(mod * sp, Pb[2 + NV + v], uni);
    }
    out[(size_t)b * T_LEN + t] = gain_sum * coef * uni;
}

extern "C" void kernel_launch(void* const* d_in, const int* in_sizes, int n_in,
                              void* d_out, int out_size, void* d_ws, size_t ws_size,
                              hipStream_t stream) {
    const float* base = (const float*)d_in[0];
    const float* z    = (const float*)d_in[1];
    const float* cond = (const float*)d_in[2];
    const float* W1 = (const float*)d_in[4];  const float* b1 = (const float*)d_in[5];
    const float* W2 = (const float*)d_in[6];  const float* b2 = (const float*)d_in[7];
    const float* W3 = (const float*)d_in[8];  const float* b3 = (const float*)d_in[9];
    const float* W4 = (const float*)d_in[10]; const float* b4 = (const float*)d_in[11];
    const float* K1 = (const float*)d_in[12]; const float* cb1 = (const float*)d_in[13];
    const float* K2 = (const float*)d_in[14]; const float* cb2 = (const float*)d_in[15];
    const float* K3 = (const float*)d_in[16]; const float* cb3 = (const float*)d_in[17];
    float* out = (float*)d_out;

    int B = in_sizes[0] / T_LEN;   // 16

    float* ws = (float*)d_ws;
    const size_t XBF  = NXB / 2;                  // 348160 floats
    const size_t K1F  = NK1 / 2;                  // 71680
    const size_t K2F  = NK2 / 2;                  // 20480
    const size_t G1BF = (size_t)16 * XR2 * 128 / 2;  // 262144
    const size_t G2   = (size_t)16 * L_LEN * 64;     // 256000
    size_t need = (1024 + XBF + K1F + K2F + G1BF + G2) * sizeof(float);  // ~3.8 MB

    float* P = ws;
    if (ws_size >= need) {
        __hip_bfloat16* Xb  = (__hip_bfloat16*)(ws + 1024);
        __hip_bfloat16* K1t = (__hip_bfloat16*)(ws + 1024 + XBF);
        __hip_bfloat16* K2t = (__hip_bfloat16*)(ws + 1024 + XBF + K1F);
        __hip_bfloat16* g1b = (__hip_bfloat16*)(ws + 1024 + XBF + K1F + K2F);
        float* g2 = ws + 1024 + XBF + K1F + K2F + G1BF;

        int prep_blocks = (NXB + NK1 + NK2 + NPAD + 255) / 256;
        prep_kernel<<<prep_blocks, 256, 0, stream>>>(z, cond, K1, K2, Xb, K1t, K2t, g1b);
        conv1_mfma_mlp_kernel<<<16 + 256, 256, 0, stream>>>(
            (const short*)Xb, (const short*)K1t, cb1, g1b, z, cond,
            W1, b1, W2, b2, W3, b3, W4, b4, P);
        conv2_mfma_kernel<<<256, 256, 0, stream>>>(
            (const short*)g1b, (const short*)K2t, g2);
        conv3_main_kernel<<<B * CB, 256, 0, stream>>>(base, g2, cb2, K3, cb3, P, out);
    } else {
        float* g1 = ws + 1024;
        float* g2 = g1 + (size_t)B * L_LEN * 128;
        float* g3 = g2 + (size_t)B * L_LEN * 64;
        params_kernel<<<B, 256, 0, stream>>>(z, cond, W1, b1, W2, b2, W3, b3, W4, b4, P);
        conv1_mono_kernel<<<B * 16, 256, 0, stream>>>(z, cond, K1, cb1, g1);
        conv2_mono_kernel<<<B * 16, 256, 0, stream>>>(g1, K2, cb2, g2);
        conv3_mono_kernel<<<B * 16, 256, 0, stream>>>(g2, K3, cb3, g3);
        main_mono_kernel<<<B * CB, 256, 0, stream>>>(base, g3, P, out);
    }
}

// Round 14
// 57.743 us; speedup vs baseline: 1.4464x; 1.0075x over previous
//
#include <hip/hip_runtime.h>
#include <hip/hip_bf16.h>
#include <math.h>

#define L_LEN 250
#define D_DIM 128
#define C_DIM 32
#define DIN   160
#define NV    16
#define T_LEN 62400
#define CB    244              // ceil(62400/256)
#define XROWS 272              // Xb pad rows: r = l+3, l in [-3, 268]
#define NXB   (16 * XROWS * 160)   // Xb elements (bf16)
#define NK1   (128 * 1120)         // K1t elements (bf16)
#define NK2   (64 * 640)           // K2t elements (bf16)

typedef short short8 __attribute__((ext_vector_type(8)));
typedef float f32x4  __attribute__((ext_vector_type(4)));

// ------- kernel 0: bf16 padded input + transposed weights -------------------
__global__ __launch_bounds__(256) void prep_kernel(
        const float* __restrict__ z, const float* __restrict__ cond,
        const float* __restrict__ K1, const float* __restrict__ K2,
        __hip_bfloat16* __restrict__ Xb, __hip_bfloat16* __restrict__ K1t,
        __hip_bfloat16* __restrict__ K2t) {
    int idx = blockIdx.x * 256 + threadIdx.x;
    if (idx < NXB) {
        int b   = idx / (XROWS * 160);
        int rem = idx - b * (XROWS * 160);
        int r   = rem / 160;
        int ic  = rem - r * 160;
        int l   = r - 3;
        float v = 0.f;
        if (l >= 0 && l < L_LEN)
            v = (ic < D_DIM) ? z[((size_t)b * L_LEN + l) * D_DIM + ic]
                             : cond[b * C_DIM + (ic - D_DIM)];
        Xb[idx] = __float2bfloat16(v);
    } else if (idx < NXB + NK1) {
        int j  = idx - NXB;
        int oc = j / 1120;
        int k  = j - oc * 1120;
        K1t[j] = __float2bfloat16(K1[(size_t)k * 128 + oc]);
    } else if (idx < NXB + NK1 + NK2) {
        int j  = idx - NXB - NK1;
        int oc = j / 640;
        int k  = j - oc * 640;
        K2t[j] = __float2bfloat16(K2[(size_t)k * 64 + oc]);
    }
}

// ------- kernel A: blocks 0..15 = K-parallel MLP ; 16..271 = conv1+conv2 ----
// conv path: per block (b, lt=16-l tile): conv1 with +/-4-row halo into LDS
// g1loc[24][132] (bf16, relu+bias applied), then conv2 MFMA from LDS -> g2.
// P layout (40): [0]=depth,[1]=coef,[2..17]=mask,[18..33]=pan
__global__ __launch_bounds__(256) void conv12_mlp_kernel(
        const short* __restrict__ Xb, const short* __restrict__ K1t,
        const short* __restrict__ K2t,
        const float* __restrict__ cb1, float* __restrict__ g2,
        const float* __restrict__ z, const float* __restrict__ cond,
        const float* __restrict__ W1, const float* __restrict__ b1,
        const float* __restrict__ W2, const float* __restrict__ b2,
        const float* __restrict__ W3, const float* __restrict__ b3,
        const float* __restrict__ W4, const float* __restrict__ b4,
        float* __restrict__ P) {
    int tid = threadIdx.x;
    __shared__ __hip_bfloat16 g1loc[24][132];   // rows l0-4 .. l0+19, pad 132
    if (blockIdx.x < 16) {
        // ---------- K-parallel MLP (hides under conv work) ----------
        int b = blockIdx.x;
        __shared__ float buf[2176];
        float* xb = buf;
        float* h1 = buf + 160;
        float* h2 = buf + 416;
        float* h3 = buf + 544;
        float* pr = buf + 608;
        float* red = buf + 640;
        float4* sm4 = (float4*)(buf + 1152);
        {
            int c4 = tid & 31, rg = tid >> 5;
            const float4* zp = (const float4*)(z + (size_t)b * L_LEN * D_DIM) + c4;
            float4 acc = make_float4(0.f, 0.f, 0.f, 0.f);
            for (int r = rg; r < L_LEN; r += 8) {
                float4 v = zp[(size_t)r * 32];
                acc.x += v.x; acc.y += v.y; acc.z += v.z; acc.w += v.w;
            }
            sm4[rg * 32 + c4] = acc;
        }
        __syncthreads();
        if (tid < 32) {
            float4 acc = sm4[tid];
            #pragma unroll
            for (int g = 1; g < 8; ++g) {
                float4 v = sm4[g * 32 + tid];
                acc.x += v.x; acc.y += v.y; acc.z += v.z; acc.w += v.w;
            }
            const float inv = 1.0f / (float)L_LEN;
            acc.x *= inv; acc.y *= inv; acc.z *= inv; acc.w *= inv;
            ((float4*)xb)[tid] = acc;
        } else if (tid >= 128 && tid < DIN) {
            xb[tid] = cond[b * C_DIM + (tid - 128)];
        }
        __syncthreads();
        {   // L1: 160 -> 256 ; 8 accs, unroll 2
            const float* w = W1 + tid;
            float a0 = b1[tid], a1 = 0.f, a2 = 0.f, a3 = 0.f;
            float a4 = 0.f, a5 = 0.f, a6 = 0.f, a7 = 0.f;
            #pragma unroll 2
            for (int i = 0; i < DIN; i += 8) {
                a0 = fmaf(xb[i],     w[(size_t)(i)     * 256], a0);
                a1 = fmaf(xb[i + 1], w[(size_t)(i + 1) * 256], a1);
                a2 = fmaf(xb[i + 2], w[(size_t)(i + 2) * 256], a2);
                a3 = fmaf(xb[i + 3], w[(size_t)(i + 3) * 256], a3);
                a4 = fmaf(xb[i + 4], w[(size_t)(i + 4) * 256], a4);
                a5 = fmaf(xb[i + 5], w[(size_t)(i + 5) * 256], a5);
                a6 = fmaf(xb[i + 6], w[(size_t)(i + 6) * 256], a6);
                a7 = fmaf(xb[i + 7], w[(size_t)(i + 7) * 256], a7);
            }
            h1[tid] = fmaxf(((a0 + a1) + (a2 + a3)) + ((a4 + a5) + (a6 + a7)), 0.f);
        }
        __syncthreads();
        {   // L2: 256 -> 128 ; 2 k-halves ; 8 accs
            int oc = tid & 127, hh = tid >> 7;
            const float* w = W2 + (size_t)(hh * 128) * 128 + oc;
            const float* x = h1 + hh * 128;
            float a0 = 0.f, a1 = 0.f, a2 = 0.f, a3 = 0.f;
            float a4 = 0.f, a5 = 0.f, a6 = 0.f, a7 = 0.f;
            #pragma unroll 2
            for (int i = 0; i < 128; i += 8) {
                a0 = fmaf(x[i],     w[(size_t)(i)     * 128], a0);
                a1 = fmaf(x[i + 1], w[(size_t)(i + 1) * 128], a1);
                a2 = fmaf(x[i + 2], w[(size_t)(i + 2) * 128], a2);
                a3 = fmaf(x[i + 3], w[(size_t)(i + 3) * 128], a3);
                a4 = fmaf(x[i + 4], w[(size_t)(i + 4) * 128], a4);
                a5 = fmaf(x[i + 5], w[(size_t)(i + 5) * 128], a5);
                a6 = fmaf(x[i + 6], w[(size_t)(i + 6) * 128], a6);
                a7 = fmaf(x[i + 7], w[(size_t)(i + 7) * 128], a7);
            }
            red[tid] = ((a0 + a1) + (a2 + a3)) + ((a4 + a5) + (a6 + a7));
        }
        __syncthreads();
        if (tid < 128) h2[tid] = fmaxf(red[tid] + red[tid + 128] + b2[tid], 0.f);
        __syncthreads();
        {   // L3: 128 -> 64 ; 4 k-groups ; 8 accs
            int oc = tid & 63, qg = tid >> 6;
            const float* w = W3 + (size_t)(qg * 32) * 64 + oc;
            const float* x = h2 + qg * 32;
            float a0 = 0.f, a1 = 0.f, a2 = 0.f, a3 = 0.f;
            float a4 = 0.f, a5 = 0.f, a6 = 0.f, a7 = 0.f;
            #pragma unroll 2
            for (int i = 0; i < 32; i += 8) {
                a0 = fmaf(x[i],     w[(size_t)(i)     * 64], a0);
                a1 = fmaf(x[i + 1], w[(size_t)(i + 1) * 64], a1);
                a2 = fmaf(x[i + 2], w[(size_t)(i + 2) * 64], a2);
                a3 = fmaf(x[i + 3], w[(size_t)(i + 3) * 64], a3);
                a4 = fmaf(x[i + 4], w[(size_t)(i + 4) * 64], a4);
                a5 = fmaf(x[i + 5], w[(size_t)(i + 5) * 64], a5);
                a6 = fmaf(x[i + 6], w[(size_t)(i + 6) * 64], a6);
                a7 = fmaf(x[i + 7], w[(size_t)(i + 7) * 64], a7);
            }
            red[tid] = ((a0 + a1) + (a2 + a3)) + ((a4 + a5) + (a6 + a7));
        }
        __syncthreads();
        if (tid < 64)
            h3[tid] = fmaxf(red[tid] + red[tid + 64] + red[tid + 128] + red[tid + 192] + b3[tid], 0.f);
        __syncthreads();
        red[tid] = h3[tid >> 2] * W4[(tid >> 2) * 4 + (tid & 3)];
        __syncthreads();
        if (tid < 4) {
            float s = b4[tid];
            for (int k = 0; k < 64; ++k) s += red[k * 4 + tid];
            pr[tid] = s;
        }
        __syncthreads();
        if (tid == 0) {
            float num_voices = 1.0f + 14.0f / (1.0f + __expf(-pr[0]));
            float spread     = 1.0f / (1.0f + __expf(-pr[2]));
            float depth      = 0.5f / (1.0f + __expf(-pr[3]));
            float* Pb = P + b * 40;
            float msum = 0.f;
            for (int v = 0; v < NV; ++v) {
                float m = 1.0f / (1.0f + __expf(-(num_voices - (float)v) * 2.0f));
                msum += m;
                Pb[2 + v] = m;
                float pos = ((float)v - 7.5f) * (1.0f / 16.0f);
                Pb[2 + NV + v] = 1.0f - fabsf(pos) * spread * 0.5f;
            }
            float norm = sqrtf(msum + 1e-6f);
            Pb[0] = depth;
            Pb[1] = 1.0f / (norm + 1e-6f);
        }
        return;
    }
    // ---------------- conv1 (with halo) + conv2, fused ----------------
    int blk = blockIdx.x - 16;
    int b   = blk >> 4;
    int lt  = blk & 15;
    int l0  = lt * 16;
    int lane = tid & 63;
    int w    = tid >> 6;          // wave 0..3
    int m  = lane & 15;
    int kg = lane >> 4;
    int oc0g = w * 32;            // conv1 oc stripe

    // conv1: two M=16 tiles covering output rows l0-4 .. l0+27 (keep 0..23)
    #pragma unroll 1
    for (int t0r = 0; t0r < 2; ++t0r) {
        int lbase = l0 - 4 + t0r * 16;
        f32x4 acc0 = {0.f, 0.f, 0.f, 0.f};
        f32x4 acc1 = {0.f, 0.f, 0.f, 0.f};
        const short* Bb = K1t + ((size_t)(oc0g + m) * 1120 + kg * 8);
        #pragma unroll 1
        for (int tap = 0; tap < 7; ++tap) {
            int r = lbase + m + tap;                 // Xb padded row = l + tap
            r = min(max(r, 0), XROWS - 1);           // clamped rows are zeros
            const short* ap = Xb + ((size_t)(b * XROWS + r) * 160 + kg * 8);
            const short* bp = Bb + tap * 160;
            #pragma unroll
            for (int ks = 0; ks < 5; ++ks) {
                short8 av  = *(const short8*)(ap + ks * 32);
                short8 bv0 = *(const short8*)(bp + ks * 32);
                short8 bv1 = *(const short8*)(bp + 16 * 1120 + ks * 32);
                acc0 = __builtin_amdgcn_mfma_f32_16x16x32_bf16(av, bv0, acc0, 0, 0, 0);
                acc1 = __builtin_amdgcn_mfma_f32_16x16x32_bf16(av, bv1, acc1, 0, 0, 0);
            }
        }
        // store to LDS: row lidx = l - (l0-4), zero outside [0,250)
        float bias0 = cb1[oc0g + m];
        float bias1 = cb1[oc0g + m + 16];
        #pragma unroll
        for (int j = 0; j < 4; ++j) {
            int l    = lbase + kg * 4 + j;
            int lidx = t0r * 16 + kg * 4 + j;
            if (lidx < 24) {
                bool valid = (l >= 0 && l < L_LEN);
                float v0 = valid ? fmaxf(acc0[j] + bias0, 0.f) : 0.f;
                float v1 = valid ? fmaxf(acc1[j] + bias1, 0.f) : 0.f;
                g1loc[lidx][oc0g + m]      = __float2bfloat16(v0);
                g1loc[lidx][oc0g + m + 16] = __float2bfloat16(v1);
            }
        }
    }
    __syncthreads();

    // conv2: wave w -> oc stripe w*16; out rows l0 + kg*4+j; A from g1loc.
    {
        int oc2 = w * 16 + m;                        // B row (oc)
        const short* Bb2 = K2t + ((size_t)oc2 * 640 + kg * 8);
        f32x4 acc = {0.f, 0.f, 0.f, 0.f};
        #pragma unroll 1
        for (int tap = 0; tap < 5; ++tap) {
            // A[m][k]: g1 row (l0+m) - 2 + tap -> local row m + 2 + tap
            const __hip_bfloat16* arow = &g1loc[m + 2 + tap][kg * 8];
            const short* bp = Bb2 + tap * 128;
            #pragma unroll
            for (int ks = 0; ks < 4; ++ks) {
                short8 av = *(const short8*)(arow + ks * 32);
                short8 bv = *(const short8*)(bp + ks * 32);
                acc = __builtin_amdgcn_mfma_f32_16x16x32_bf16(av, bv, acc, 0, 0, 0);
            }
        }
        int rbase = l0 + kg * 4;
        #pragma unroll
        for (int j = 0; j < 4; ++j) {
            int l = rbase + j;
            if (l < L_LEN)
                g2[((size_t)b * L_LEN + l) * 64 + oc2] = acc[j];
        }
    }
}

// ------- kernel C: fused conv3 + upsample + softplus + unison mix ----------
__global__ __launch_bounds__(256) void conv3_main_kernel(
        const float* __restrict__ base, const float* __restrict__ g2,
        const float* __restrict__ cb2,
        const float* __restrict__ K3, const float* __restrict__ cb3,
        const float* __restrict__ P, float* __restrict__ out) {
    int b = blockIdx.x / CB;
    int c = blockIdx.x % CB;
    int t0 = c * 256;
    int tid = threadIdx.x;
    const float scale = 250.0f / 62400.0f;

    __shared__ float k3t[16][196];
    __shared__ float sA[6][68];
    __shared__ float g3loc[4][17];
    __shared__ float Pb[34];
    __shared__ float sbase[276];

    float src0 = ((float)t0 + 0.5f) * scale - 0.5f;
    src0 = fminf(fmaxf(src0, 0.0f), 249.0f);
    int L0 = (int)floorf(src0);

    const float* bs = base + (size_t)b * T_LEN;
    if (tid < 34) Pb[tid] = P[b * 40 + tid];
    for (int idx = tid; idx < 274; idx += 256) {
        int tt = t0 - 9 + idx;
        if (tt < 0) tt += T_LEN; else if (tt >= T_LEN) tt -= T_LEN;
        sbase[idx] = bs[tt];
    }
    for (int idx = tid; idx < 3 * 64 * 16; idx += 256) {
        int v  = idx & 15;
        int ti = idx >> 4;
        k3t[v][ti] = K3[ti * 16 + v];
    }
    for (int idx = tid; idx < 6 * 64; idx += 256) {
        int pl = idx >> 6;
        int i  = idx & 63;
        int p  = L0 - 1 + pl;
        float v = 0.f;
        if (p >= 0 && p < L_LEN)
            v = fmaxf(cb2[i] + g2[((size_t)b * L_LEN + p) * 64 + i], 0.f);
        sA[pl][i] = v;
    }
    __syncthreads();

    {   // conv3: 4 rows x 16 v x 4 ic-segments; quad shuffle-reduce
        int seg = tid & 3;
        int v   = (tid >> 2) & 15;
        int r   = tid >> 6;
        float acc = 0.f;
        #pragma unroll
        for (int tap = 0; tap < 3; ++tap) {
            const float* gr = &sA[r + tap][seg * 16];
            const float* kr = &k3t[v][tap * 64 + seg * 16];
            #pragma unroll
            for (int j = 0; j < 4; ++j) {
                float4 g = *(const float4*)&gr[j * 4];
                float4 k = *(const float4*)&kr[j * 4];
                acc = fmaf(g.x, k.x, acc);
                acc = fmaf(g.y, k.y, acc);
                acc = fmaf(g.z, k.z, acc);
                acc = fmaf(g.w, k.w, acc);
            }
        }
        acc += __shfl_xor(acc, 1);
        acc += __shfl_xor(acc, 2);
        if (seg == 0) g3loc[r][v] = acc + cb3[v];
    }
    __syncthreads();

    int t = t0 + tid;
    if (t >= T_LEN) return;
    float depth = Pb[0];
    float coef  = Pb[1];
    float src = ((float)t + 0.5f) * scale - 0.5f;
    src = fminf(fmaxf(src, 0.0f), 249.0f);
    float fi0 = floorf(src);
    int i0 = (int)fi0;
    int i1 = min(i0 + 1, L_LEN - 1);
    float frac = src - fi0;
    int r0 = i0 - L0;
    int r1 = i1 - L0;
    float vg[16];
    #pragma unroll
    for (int v = 0; v < NV; ++v) {
        float a = g3loc[r0][v];
        float d = g3loc[r1][v];
        vg[v] = fmaf(d - a, frac, a);
    }
    float tsec = (float)t * (1.0f / 48000.0f);
    const int shifts[NV] = {-9,-8,-6,-5,-4,-3,-1,0,0,1,3,4,5,6,8,9};
    float gain_sum = 0.f, uni = 0.f;
    #pragma unroll
    for (int v = 0; v < NV; ++v) {
        float x = vg[v];
        float sp = fmaxf(x, 0.f) + __logf(1.0f + __expf(-fabsf(x)));   // softplus
        float fv = 3.0f + 0.3f * (float)v;
        float ph = fv * tsec;
        ph -= floorf(ph);
        float lfo = __builtin_amdgcn_sinf(ph);  // v_sin_f32: revolutions
        float mod = sbase[tid + 9 - shifts[v]] * fmaf(0.2f * depth, lfo, 1.0f);
        gain_sum = fmaf(sp, Pb[2 + v], gain_sum);
        uni      = fmaf(mod * sp, Pb[2 + NV + v], uni);
    }
    out[(size_t)b * T_LEN + t] = gain_sum * coef * uni;
}

// ================= fallback (round-1 monolithic) kernels ====================
__global__ void params_kernel(const float* __restrict__ z, const float* __restrict__ cond,
                              const float* __restrict__ W1, const float* __restrict__ b1,
                              const float* __restrict__ W2, const float* __restrict__ b2,
                              const float* __restrict__ W3, const float* __restrict__ b3,
                              const float* __restrict__ W4, const float* __restrict__ b4,
                              float* __restrict__ P) {
    int b = blockIdx.x;
    int tid = threadIdx.x;
    __shared__ float xb[DIN];
    __shared__ float zp2[128];
    __shared__ float h1[256];
    __shared__ float h2[128];
    __shared__ float h3[64];
    __shared__ float pr[4];
    {
        int i = tid & 127, half = tid >> 7;
        const float* zp = z + (size_t)b * L_LEN * D_DIM + i;
        float s = 0.f;
        for (int l = half; l < L_LEN; l += 2) s += zp[(size_t)l * D_DIM];
        if (half) zp2[i] = s;
        __syncthreads();
        if (!half) xb[i] = (s + zp2[i]) * (1.0f / (float)L_LEN);
        if (tid >= 128 && tid < DIN) xb[tid] = cond[b * C_DIM + (tid - 128)];
    }
    __syncthreads();
    {
        float acc = b1[tid];
        for (int i = 0; i < DIN; ++i) acc = fmaf(xb[i], W1[i * 256 + tid], acc);
        h1[tid] = fmaxf(acc, 0.f);
    }
    __syncthreads();
    if (tid < 128) {
        float acc = b2[tid];
        for (int i = 0; i < 256; ++i) acc = fmaf(h1[i], W2[i * 128 + tid], acc);
        h2[tid] = fmaxf(acc, 0.f);
    }
    __syncthreads();
    if (tid < 64) {
        float acc = b3[tid];
        for (int i = 0; i < 128; ++i) acc = fmaf(h2[i], W3[i * 64 + tid], acc);
        h3[tid] = fmaxf(acc, 0.f);
    }
    __syncthreads();
    if (tid < 4) {
        float acc = b4[tid];
        for (int i = 0; i < 64; ++i) acc = fmaf(h3[i], W4[i * 4 + tid], acc);
        pr[tid] = acc;
    }
    __syncthreads();
    if (tid == 0) {
        float num_voices = 1.0f + 14.0f / (1.0f + __expf(-pr[0]));
        float spread     = 1.0f / (1.0f + __expf(-pr[2]));
        float depth      = 0.5f / (1.0f + __expf(-pr[3]));
        float* Pb = P + b * 40;
        float msum = 0.f;
        for (int v = 0; v < NV; ++v) {
            float m = 1.0f / (1.0f + __expf(-(num_voices - (float)v) * 2.0f));
            msum += m;
            Pb[2 + v] = m;
            float pos = ((float)v - 7.5f) * (1.0f / 16.0f);
            Pb[2 + NV + v] = 1.0f - fabsf(pos) * spread * 0.5f;
        }
        float norm = sqrtf(msum + 1e-6f);
        Pb[0] = depth;
        Pb[1] = 1.0f / (norm + 1e-6f);
    }
}

__global__ void conv1_mono_kernel(const float* __restrict__ z, const float* __restrict__ cond,
                                  const float* __restrict__ K1, const float* __restrict__ cb1,
                                  float* __restrict__ g1) {
    int b  = blockIdx.x >> 4;
    int lt = blockIdx.x & 15;
    int l0 = lt * 16;
    int tid = threadIdx.x;
    __shared__ float sm[DIN][22];
    for (int idx = tid; idx < 22 * DIN; idx += 256) {
        int pl = idx / DIN;
        int i  = idx - pl * DIN;
        int p  = l0 - 3 + pl;
        float v = 0.f;
        if (p >= 0 && p < L_LEN)
            v = (i < D_DIM) ? z[((size_t)b * L_LEN + p) * D_DIM + i]
                            : cond[b * C_DIM + (i - D_DIM)];
        sm[i][pl] = v;
    }
    __syncthreads();
    int oc = tid & 127;
    int lb = (tid >> 7) * 8;
    float bias = cb1[oc];
    float acc[8];
    #pragma unroll
    for (int j = 0; j < 8; ++j) acc[j] = bias;
    for (int i = 0; i < DIN; ++i) {
        float zr[14];
        #pragma unroll
        for (int q = 0; q < 14; ++q) zr[q] = sm[i][lb + q];
        #pragma unroll
        for (int tap = 0; tap < 7; ++tap) {
            float k = K1[(size_t)(tap * DIN + i) * 128 + oc];
            #pragma unroll
            for (int j = 0; j < 8; ++j) acc[j] = fmaf(zr[tap + j], k, acc[j]);
        }
    }
    #pragma unroll
    for (int j = 0; j < 8; ++j) {
        int l = l0 + lb + j;
        if (l < L_LEN) g1[((size_t)b * L_LEN + l) * 128 + oc] = fmaxf(acc[j], 0.f);
    }
}

__global__ void conv2_mono_kernel(const float* __restrict__ g1,
                                  const float* __restrict__ K2, const float* __restrict__ cb2,
                                  float* __restrict__ g2) {
    int b  = blockIdx.x >> 4;
    int lt = blockIdx.x & 15;
    int l0 = lt * 16;
    int tid = threadIdx.x;
    __shared__ float sm[128][20];
    for (int idx = tid; idx < 20 * 128; idx += 256) {
        int pl = idx >> 7;
        int i  = idx & 127;
        int p  = l0 - 2 + pl;
        float v = (p >= 0 && p < L_LEN) ? g1[((size_t)b * L_LEN + p) * 128 + i] : 0.f;
        sm[i][pl] = v;
    }
    __syncthreads();
    int oc = tid & 63;
    int lb = (tid >> 6) * 4;
    float bias = cb2[oc];
    float acc[4];
    #pragma unroll
    for (int j = 0; j < 4; ++j) acc[j] = bias;
    for (int i = 0; i < 128; ++i) {
        float zr[8];
        #pragma unroll
        for (int q = 0; q < 8; ++q) zr[q] = sm[i][lb + q];
        #pragma unroll
        for (int tap = 0; tap < 5; ++tap) {
            float k = K2[(size_t)(tap * 128 + i) * 64 + oc];
            #pragma unroll
            for (int j = 0; j < 4; ++j) acc[j] = fmaf(zr[tap + j], k, acc[j]);
        }
    }
    #pragma unroll
    for (int j = 0; j < 4; ++j) {
        int l = l0 + lb + j;
        if (l < L_LEN) g2[((size_t)b * L_LEN + l) * 64 + oc] = fmaxf(acc[j], 0.f);
    }
}

__global__ void conv3_mono_kernel(const float* __restrict__ g2,
                                  const float* __restrict__ K3, const float* __restrict__ cb3,
                                  float* __restrict__ g3) {
    int b  = blockIdx.x >> 4;
    int lt = blockIdx.x & 15;
    int l0 = lt * 16;
    int tid = threadIdx.x;
    int v  = tid & 15;
    int ll = tid >> 4;
    int l  = l0 + ll;
    if (l >= L_LEN) return;
    float acc = cb3[v];
    #pragma unroll
    for (int tap = 0; tap < 3; ++tap) {
        int p = l + tap - 1;
        if (p < 0 || p >= L_LEN) continue;
        const float* gp = g2 + ((size_t)b * L_LEN + p) * 64;
        #pragma unroll
        for (int i = 0; i < 64; ++i) acc = fmaf(gp[i], K3[(size_t)(tap * 64 + i) * 16 + v], acc);
    }
    g3[((size_t)b * L_LEN + l) * 16 + v] = acc;
}

__global__ __launch_bounds__(256) void main_mono_kernel(
        const float* __restrict__ base, const float* __restrict__ g3,
        const float* __restrict__ P, float* __restrict__ out) {
    int b = blockIdx.x / CB;
    int c = blockIdx.x % CB;
    int t = c * 256 + threadIdx.x;
    __shared__ float Pb[34];
    if (threadIdx.x < 34) Pb[threadIdx.x] = P[b * 40 + threadIdx.x];
    __syncthreads();
    if (t >= T_LEN) return;
    float depth = Pb[0];
    float coef  = Pb[1];
    const float scale = 250.0f / 62400.0f;
    float src = ((float)t + 0.5f) * scale - 0.5f;
    src = fminf(fmaxf(src, 0.0f), 249.0f);
    float fi0 = floorf(src);
    int i0 = (int)fi0;
    int i1 = min(i0 + 1, L_LEN - 1);
    float frac = src - fi0;
    const float4* r0 = (const float4*)(g3 + ((size_t)b * L_LEN + i0) * NV);
    const float4* r1 = (const float4*)(g3 + ((size_t)b * L_LEN + i1) * NV);
    float vg[16];
    #pragma unroll
    for (int q = 0; q < 4; ++q) {
        float4 a = r0[q];
        float4 d = r1[q];
        vg[q * 4 + 0] = fmaf(d.x - a.x, frac, a.x);
        vg[q * 4 + 1] = fmaf(d.y - a.y, frac, a.y);
        vg[q * 4 + 2] = fmaf(d.z - a.z, frac, a.z);
        vg[q * 4 + 3] = fmaf(d.w - a.w, frac, a.w);
    }
    float tsec = (float)t * (1.0f / 48000.0f);
    const float* bs = base + (size_t)b * T_LEN;
    const int shifts[NV] = {-9,-8,-6,-5,-4,-3,-1,0,0,1,3,4,5,6,8,9};
    float gain_sum = 0.f, uni = 0.f;
    #pragma unroll
    for (int v = 0; v < NV; ++v) {
        float x = vg[v];
        float sp = fmaxf(x, 0.f) + __logf(1.0f + __expf(-fabsf(x)));
        float fv = 3.0f + 0.3f * (float)v;
        float ph = fv * tsec;
        ph -= floorf(ph);
        float lfo = __builtin_amdgcn_sinf(ph);
        int tb = t - shifts[v];
        if (tb < 0) tb += T_LEN; else if (tb >= T_LEN) tb -= T_LEN;
        float mod = bs[tb] * fmaf(0.2f * depth, lfo, 1.0f);
        gain_sum = fmaf(sp, Pb[2 + v], gain_sum);
        uni      = fmaf(mod * sp, Pb[2 + NV + v], uni);
    }
    out[(size_t)b * T_LEN + t] = gain_sum * coef * uni;
}

extern "C" void kernel_launch(void* const* d_in, const int* in_sizes, int n_in,
                              void* d_out, int out_size, void* d_ws, size_t ws_size,
                              hipStream_t stream) {
    const float* base = (const float*)d_in[0];
    const float* z    = (const float*)d_in[1];
    const float* cond = (const float*)d_in[2];
    const float* W1 = (const float*)d_in[4];  const float* b1 = (const float*)d_in[5];
    const float* W2 = (const float*)d_in[6];  const float* b2 = (const float*)d_in[7];
    const float* W3 = (const float*)d_in[8];  const float* b3 = (const float*)d_in[9];
    const float* W4 = (const float*)d_in[10]; const float* b4 = (const float*)d_in[11];
    const float* K1 = (const float*)d_in[12]; const float* cb1 = (const float*)d_in[13];
    const float* K2 = (const float*)d_in[14]; const float* cb2 = (const float*)d_in[15];
    const float* K3 = (const float*)d_in[16]; const float* cb3 = (const float*)d_in[17];
    float* out = (float*)d_out;

    int B = in_sizes[0] / T_LEN;   // 16

    float* ws = (float*)d_ws;
    const size_t XBF = NXB / 2;                  // floats
    const size_t K1F = NK1 / 2;
    const size_t K2F = NK2 / 2;
    const size_t G2  = (size_t)16 * L_LEN * 64;
    size_t need = (1024 + XBF + K1F + K2F + G2) * sizeof(float);   // ~2.8 MB

    float* P = ws;
    if (ws_size >= need) {
        __hip_bfloat16* Xb  = (__hip_bfloat16*)(ws + 1024);
        __hip_bfloat16* K1t = (__hip_bfloat16*)(ws + 1024 + XBF);
        __hip_bfloat16* K2t = (__hip_bfloat16*)(ws + 1024 + XBF + K1F);
        float* g2 = ws + 1024 + XBF + K1F + K2F;

        int prep_blocks = (NXB + NK1 + NK2 + 255) / 256;
        prep_kernel<<<prep_blocks, 256, 0, stream>>>(z, cond, K1, K2, Xb, K1t, K2t);
        conv12_mlp_kernel<<<16 + 256, 256, 0, stream>>>(
            (const short*)Xb, (const short*)K1t, (const short*)K2t,
            cb1, g2, z, cond, W1, b1, W2, b2, W3, b3, W4, b4, P);
        conv3_main_kernel<<<B * CB, 256, 0, stream>>>(base, g2, cb2, K3, cb3, P, out);
    } else {
        float* g1 = ws + 1024;
        float* g2 = g1 + (size_t)B * L_LEN * 128;
        float* g3 = g2 + (size_t)B * L_LEN * 64;
        params_kernel<<<B, 256, 0, stream>>>(z, cond, W1, b1, W2, b2, W3, b3, W4, b4, P);
        conv1_mono_kernel<<<B * 16, 256, 0, stream>>>(z, cond, K1, cb1, g1);
        conv2_mono_kernel<<<B * 16, 256, 0, stream>>>(g1, K2, cb2, g2);
        conv3_mono_kernel<<<B * 16, 256, 0, stream>>>(g2, K3, cb3, g3);
        main_mono_kernel<<<B * CB, 256, 0, stream>>>(base, g3, P, out);
    }
}